// Round 2
// baseline (17019.019 us; speedup 1.0000x reference)
//
#include <hip/hip_runtime.h>
#include <math.h>

// Problem constants
#define BSZ 8
#define LSZ 2048
#define DMV 320
#define DIV 1280
#define NST 16
#define DCV 8
#define DTR 20
#define NBLKV 4
#define MTOT (BSZ*LSZ)   // 16384

// ---------------------------------------------------------------------------
// start_max reduction (x[:,:,2] >= 0, so int-compare atomicMax is valid)
// ---------------------------------------------------------------------------
__global__ void init_sm_kernel(float* sm) {
    if (threadIdx.x == 0) ((int*)sm)[0] = 0;
}

__global__ void reduce_max_kernel(const float* __restrict__ x, float* sm) {
    int idx = blockIdx.x * blockDim.x + threadIdx.x;
    float v = 0.f;
    for (int i = idx; i < MTOT; i += gridDim.x * blockDim.x)
        v = fmaxf(v, x[i * 4 + 2]);
    #pragma unroll
    for (int off = 32; off > 0; off >>= 1)
        v = fmaxf(v, __shfl_xor(v, off, 64));
    if ((threadIdx.x & 63) == 0)
        atomicMax((int*)sm, __float_as_int(v));
}

// ---------------------------------------------------------------------------
// input normalize + fc (K=4)
// ---------------------------------------------------------------------------
__global__ void fc_kernel(const float* __restrict__ x, const float* __restrict__ fw,
                          const float* __restrict__ fb, const float* __restrict__ sm,
                          float* __restrict__ u) {
    int m = blockIdx.y;
    int o = blockIdx.x * 64 + threadIdx.x;
    float inv_sm = 1.0f / sm[0];
    float x0 = x[m * 4 + 0] * (1.0f / 255.0f);
    float x1 = x[m * 4 + 1] * (1.0f / 255.0f);
    float x2 = x[m * 4 + 2] * inv_sm;
    float x3 = x[m * 4 + 3];
    float acc = fb[o];
    acc = fmaf(x0, fw[o * 4 + 0], acc);
    acc = fmaf(x1, fw[o * 4 + 1], acc);
    acc = fmaf(x2, fw[o * 4 + 2], acc);
    acc = fmaf(x3, fw[o * 4 + 3], acc);
    u[(long)m * DMV + o] = acc;
}

// ---------------------------------------------------------------------------
// Generic fp32 GEMM: Y[m,n] = act( sum_k X[m*ldx+k]*W[n*K+k] + bias[n] )
// 64x64 tile, BK=16, 256 threads, 4x4 per-thread microtile.
// ACT: 0=none 1=tanh 2=relu 3=elu
// ---------------------------------------------------------------------------
template<int ACT>
__global__ __launch_bounds__(256) void gemm_kernel(
    const float* __restrict__ X, const float* __restrict__ W,
    const float* __restrict__ bias, float* __restrict__ Y,
    int M, int N, int K, long ldx, long ldy)
{
    __shared__ __align__(16) float Xs[16][68];
    __shared__ __align__(16) float Ws[16][68];
    int tid = threadIdx.x;
    int m0 = blockIdx.y * 64;
    int n0 = blockIdx.x * 64;
    int tn = tid & 15, tm = tid >> 4;

    float acc[4][4] = {};

    int lr  = tid >> 2;        // 0..63 row in tile
    int lk4 = (tid & 3) * 4;   // 0,4,8,12

    for (int k0 = 0; k0 < K; k0 += 16) {
        {
            int m = m0 + lr;
            float4 v = make_float4(0.f, 0.f, 0.f, 0.f);
            if (m < M) {
                if (k0 + lk4 + 3 < K) {
                    v = *(const float4*)(X + (long)m * ldx + k0 + lk4);
                } else {
                    float tmp[4] = {0.f, 0.f, 0.f, 0.f};
                    for (int j = 0; j < 4; j++)
                        if (k0 + lk4 + j < K) tmp[j] = X[(long)m * ldx + k0 + lk4 + j];
                    v = make_float4(tmp[0], tmp[1], tmp[2], tmp[3]);
                }
            }
            Xs[lk4 + 0][lr] = v.x; Xs[lk4 + 1][lr] = v.y;
            Xs[lk4 + 2][lr] = v.z; Xs[lk4 + 3][lr] = v.w;
        }
        {
            int n = n0 + lr;
            float4 v = make_float4(0.f, 0.f, 0.f, 0.f);
            if (n < N) {
                if (k0 + lk4 + 3 < K) {
                    v = *(const float4*)(W + (long)n * K + k0 + lk4);
                } else {
                    float tmp[4] = {0.f, 0.f, 0.f, 0.f};
                    for (int j = 0; j < 4; j++)
                        if (k0 + lk4 + j < K) tmp[j] = W[(long)n * K + k0 + lk4 + j];
                    v = make_float4(tmp[0], tmp[1], tmp[2], tmp[3]);
                }
            }
            Ws[lk4 + 0][lr] = v.x; Ws[lk4 + 1][lr] = v.y;
            Ws[lk4 + 2][lr] = v.z; Ws[lk4 + 3][lr] = v.w;
        }
        __syncthreads();
        #pragma unroll
        for (int k = 0; k < 16; k++) {
            float xr[4], wr[4];
            *(float4*)xr = *(const float4*)&Xs[k][tm * 4];
            *(float4*)wr = *(const float4*)&Ws[k][tn * 4];
            #pragma unroll
            for (int i = 0; i < 4; i++)
                #pragma unroll
                for (int j = 0; j < 4; j++)
                    acc[i][j] = fmaf(xr[i], wr[j], acc[i][j]);
        }
        __syncthreads();
    }

    #pragma unroll
    for (int i = 0; i < 4; i++) {
        int m = m0 + tm * 4 + i;
        if (m >= M) break;
        #pragma unroll
        for (int j = 0; j < 4; j++) {
            int n = n0 + tn * 4 + j;
            if (n >= N) continue;
            float v = acc[i][j];
            if (bias) v += bias[n];
            if (ACT == 1) v = tanhf(v);
            else if (ACT == 2) v = fmaxf(v, 0.f);
            else if (ACT == 3) v = (v > 0.f) ? v : expm1f(v);
            Y[(long)m * ldy + n] = v;
        }
    }
}

// ---------------------------------------------------------------------------
// depthwise causal conv (k=8) + bias + silu
// reads x-half of xz (ld 2560), writes xc (ld 1280). m is chunk-local token.
// ---------------------------------------------------------------------------
__global__ __launch_bounds__(256) void conv_kernel(
    const float* __restrict__ xz, const float* __restrict__ cw,
    const float* __restrict__ cb, float* __restrict__ xc)
{
    int m = blockIdx.y;
    int d = blockIdx.x * 256 + threadIdx.x;
    int l = m & (LSZ - 1);
    float w[8];
    #pragma unroll
    for (int k = 0; k < 8; k++) w[k] = cw[d * 8 + k];
    float acc = cb[d];
    #pragma unroll
    for (int k = 0; k < 8; k++) {
        int li = l - 7 + k;
        if (li >= 0)
            acc = fmaf(xz[(long)(m - 7 + k) * 2560 + d], w[k], acc);
    }
    float s = acc / (1.0f + __expf(-acc));
    xc[(long)m * DIV + d] = s;
}

// ---------------------------------------------------------------------------
// Mamba selective scan with fused dtproj+softplus.
// One thread per (b_local, d); 16 states in registers. dbc rows (52 floats)
// staged in LDS per 64-step tile. y = (scan_y + xc*D)*silu(z) -> x-half of xz.
// ---------------------------------------------------------------------------
__global__ __launch_bounds__(256) void scan_kernel(
    const float* __restrict__ xc, float* xz, const float* __restrict__ dbc,
    const float* __restrict__ dtw, const float* __restrict__ dtb,
    const float* __restrict__ A_log, const float* __restrict__ Dp)
{
    __shared__ float S[64 * 52];
    int lb = blockIdx.y;                       // chunk-local batch
    int d = blockIdx.x * 256 + threadIdx.x;    // 0..1279
    int tid = threadIdx.x;

    float dtwr[DTR];
    #pragma unroll
    for (int j = 0; j < DTR; j++) dtwr[j] = dtw[d * DTR + j];
    float dtb_d = dtb[d];

    float a[NST], h[NST];
    #pragma unroll
    for (int n = 0; n < NST; n++) {
        a[n] = -__expf(A_log[d * NST + n]);
        h[n] = 0.f;
    }
    float Dd = Dp[d];

    for (int l0 = 0; l0 < LSZ; l0 += 64) {
        __syncthreads();
        // 64 contiguous dbc rows = 3328 contiguous floats
        const float* src = dbc + (long)(lb * LSZ + l0) * 52;
        for (int i = tid; i < 64 * 52; i += 256) S[i] = src[i];
        __syncthreads();
        for (int l = 0; l < 64; l++) {
            long m = (long)lb * LSZ + l0 + l;
            const float* row = &S[l * 52];
            float draw = dtb_d;
            #pragma unroll
            for (int j = 0; j < DTR; j++) draw = fmaf(dtwr[j], row[j], draw);
            float delta = (draw > 20.f) ? draw : log1pf(__expf(draw));
            float xv = xc[m * DIV + d];
            float zv = xz[m * 2560 + 1280 + d];
            float db = delta * xv;
            float y = 0.f;
            #pragma unroll
            for (int n = 0; n < NST; n++) {
                float dA = __expf(delta * a[n]);
                h[n] = fmaf(dA, h[n], db * row[20 + n]);
                y = fmaf(h[n], row[36 + n], y);
            }
            y = fmaf(xv, Dd, y);
            float sz = zv / (1.0f + __expf(-zv));
            xz[m * 2560 + d] = y * sz;
        }
    }
}

// ---------------------------------------------------------------------------
// final: out[b0+t] = relu(h3[t] * start_max / (1 + ln(2048)))
// ---------------------------------------------------------------------------
__global__ void final_kernel(const float* __restrict__ h3, const float* __restrict__ sm,
                             float* __restrict__ out, int Bc) {
    int t = threadIdx.x;
    if (t < Bc) {
        float scale = sm[0] / 8.624618986159398f;   // 1 + ln(2048)
        out[t] = fmaxf(h3[t] * scale, 0.f);
    }
}

// ---------------------------------------------------------------------------
extern "C" void kernel_launch(void* const* d_in, const int* in_sizes, int n_in,
                              void* d_out, int out_size, void* d_ws, size_t ws_size,
                              hipStream_t stream) {
    const float* x        = (const float*)d_in[0];
    const float* fc_w     = (const float*)d_in[1];
    const float* fc_b     = (const float*)d_in[2];
    const float* lin_w    = (const float*)d_in[3];
    const float* lin_b    = (const float*)d_in[4];
    const float* inproj_w = (const float*)d_in[5];
    const float* conv_w   = (const float*)d_in[6];
    const float* conv_b   = (const float*)d_in[7];
    const float* xproj_w  = (const float*)d_in[8];
    const float* dtproj_w = (const float*)d_in[9];
    const float* dtproj_b = (const float*)d_in[10];
    const float* A_log    = (const float*)d_in[11];
    const float* Dp       = (const float*)d_in[12];
    const float* outproj_w= (const float*)d_in[13];
    const float* s1_w1    = (const float*)d_in[14];
    const float* s1_b1    = (const float*)d_in[15];
    const float* s1_w2    = (const float*)d_in[16];
    const float* s1_b2    = (const float*)d_in[17];
    const float* s1_w3    = (const float*)d_in[18];
    const float* s1_b3    = (const float*)d_in[19];

    // ---- workspace sizing: pick largest batch-chunk that fits ----
    const long HDR = 8448;                 // sm(16)+h1(4096)+h2(4096)+h3(16)+pad
    const long PER_TOK = 320 + 320 + 2560 + 1280 + 52;   // 4532 floats
    int Bc = 8;
    while (Bc > 1 && (size_t)(HDR + (long)Bc * LSZ * PER_TOK) * 4 > ws_size)
        Bc >>= 1;
    int nchunk = BSZ / Bc;
    long Mc = (long)Bc * LSZ;

    float* ws = (float*)d_ws;
    float* sm  = ws;               // 16
    float* h1  = sm + 16;          // 4096
    float* h2  = h1 + 4096;        // 4096
    float* h3  = h2 + 4096;        // 16
    float* u   = ws + HDR;         // Mc*320
    float* t   = u  + Mc * DMV;    // Mc*320
    float* xz  = t  + Mc * DMV;    // Mc*2560
    float* xc  = xz + Mc * 2560;   // Mc*1280
    float* dbc = xc + Mc * DIV;    // Mc*52

    init_sm_kernel<<<1, 64, 0, stream>>>(sm);
    reduce_max_kernel<<<32, 256, 0, stream>>>(x, sm);

    for (int c = 0; c < nchunk; c++) {
        int b0 = c * Bc;
        fc_kernel<<<dim3(5, (unsigned)Mc), 64, 0, stream>>>(
            x + (long)b0 * LSZ * 4, fc_w, fc_b, sm, u);

        for (int i = 0; i < NBLKV; i++) {
            const float* lw  = lin_w    + (long)i * DMV * DMV;
            const float* lb  = lin_b    + (long)i * DMV;
            const float* ipw = inproj_w + (long)i * 2 * DIV * DMV;
            const float* cw  = conv_w   + (long)i * DIV * DCV;
            const float* cb  = conv_b   + (long)i * DIV;
            const float* xpw = xproj_w  + (long)i * (DTR + 2 * NST) * DIV;
            const float* dpw = dtproj_w + (long)i * DIV * DTR;
            const float* dpb = dtproj_b + (long)i * DIV;
            const float* al  = A_log    + (long)i * DIV * NST;
            const float* dd  = Dp       + (long)i * DIV;
            const float* opw = outproj_w+ (long)i * DMV * DIV;

            // lin + tanh: (Mc x320)@(320x320)^T
            gemm_kernel<1><<<dim3(5, (unsigned)(Mc / 64)), 256, 0, stream>>>(
                u, lw, lb, t, (int)Mc, DMV, DMV, DMV, DMV);
            // inproj: (Mc x320)@(2560x320)^T -> xz
            gemm_kernel<0><<<dim3(40, (unsigned)(Mc / 64)), 256, 0, stream>>>(
                t, ipw, nullptr, xz, (int)Mc, 2 * DIV, DMV, DMV, 2 * DIV);
            // conv + silu
            conv_kernel<<<dim3(5, (unsigned)Mc), 256, 0, stream>>>(xz, cw, cb, xc);
            // xproj: (Mc x1280)@(52x1280)^T -> dbc
            gemm_kernel<0><<<dim3(1, (unsigned)(Mc / 64)), 256, 0, stream>>>(
                xc, xpw, nullptr, dbc, (int)Mc, DTR + 2 * NST, DIV, DIV, DTR + 2 * NST);
            // scan (fused dtproj+softplus); writes y into x-half of xz
            scan_kernel<<<dim3(5, Bc), 256, 0, stream>>>(xc, xz, dbc, dpw, dpb, al, dd);
            // outproj + elu: (Mc x1280)@(320x1280)^T -> u
            gemm_kernel<3><<<dim3(5, (unsigned)(Mc / 64)), 256, 0, stream>>>(
                xz, opw, nullptr, u, (int)Mc, DMV, DIV, 2 * DIV, DMV);
        }

        // head on last token of each batch in chunk
        gemm_kernel<2><<<dim3(8, 1), 256, 0, stream>>>(
            u + (long)(LSZ - 1) * DMV, s1_w1, s1_b1, h1,
            Bc, 512, DMV, (long)LSZ * DMV, 512);
        gemm_kernel<2><<<dim3(8, 1), 256, 0, stream>>>(h1, s1_w2, s1_b2, h2,
            Bc, 512, 512, 512, 512);
        gemm_kernel<0><<<dim3(1, 1), 256, 0, stream>>>(h2, s1_w3, s1_b3, h3,
            Bc, 1, 512, 512, 1);
        final_kernel<<<1, 64, 0, stream>>>(h3, sm, (float*)d_out + b0, Bc);
    }
}

// Round 3
// 6902.955 us; speedup vs baseline: 2.4655x; 2.4655x over previous
//
#include <hip/hip_runtime.h>
#include <math.h>

// Problem constants
#define BSZ 8
#define LSZ 2048
#define DMV 320
#define DIV 1280
#define NST 16
#define DCV 8
#define DTR 20
#define NBLKV 4
#define MTOT (BSZ*LSZ)   // 16384
#define NCHUNK 32
#define CLEN 64          // NCHUNK*CLEN == LSZ

// ---------------------------------------------------------------------------
// start_max reduction (x[:,:,2] >= 0, so int-compare atomicMax is valid)
// ---------------------------------------------------------------------------
__global__ void init_sm_kernel(float* sm) {
    if (threadIdx.x == 0) ((int*)sm)[0] = 0;
}

__global__ void reduce_max_kernel(const float* __restrict__ x, float* sm) {
    int idx = blockIdx.x * blockDim.x + threadIdx.x;
    float v = 0.f;
    for (int i = idx; i < MTOT; i += gridDim.x * blockDim.x)
        v = fmaxf(v, x[i * 4 + 2]);
    #pragma unroll
    for (int off = 32; off > 0; off >>= 1)
        v = fmaxf(v, __shfl_xor(v, off, 64));
    if ((threadIdx.x & 63) == 0)
        atomicMax((int*)sm, __float_as_int(v));
}

// ---------------------------------------------------------------------------
// input normalize + fc (K=4)
// ---------------------------------------------------------------------------
__global__ void fc_kernel(const float* __restrict__ x, const float* __restrict__ fw,
                          const float* __restrict__ fb, const float* __restrict__ sm,
                          float* __restrict__ u) {
    int m = blockIdx.y;
    int o = blockIdx.x * 64 + threadIdx.x;
    float inv_sm = 1.0f / sm[0];
    float x0 = x[m * 4 + 0] * (1.0f / 255.0f);
    float x1 = x[m * 4 + 1] * (1.0f / 255.0f);
    float x2 = x[m * 4 + 2] * inv_sm;
    float x3 = x[m * 4 + 3];
    float acc = fb[o];
    acc = fmaf(x0, fw[o * 4 + 0], acc);
    acc = fmaf(x1, fw[o * 4 + 1], acc);
    acc = fmaf(x2, fw[o * 4 + 2], acc);
    acc = fmaf(x3, fw[o * 4 + 3], acc);
    u[(long)m * DMV + o] = acc;
}

// ---------------------------------------------------------------------------
// 64x64-tile fp32 GEMM (small problems): Y = act(X@W^T + bias)
// ACT: 0=none 1=tanh 2=relu 3=elu
// ---------------------------------------------------------------------------
template<int ACT>
__global__ __launch_bounds__(256) void gemm_kernel(
    const float* __restrict__ X, const float* __restrict__ W,
    const float* __restrict__ bias, float* __restrict__ Y,
    int M, int N, int K, long ldx, long ldy)
{
    __shared__ __align__(16) float Xs[16][68];
    __shared__ __align__(16) float Ws[16][68];
    int tid = threadIdx.x;
    int m0 = blockIdx.y * 64;
    int n0 = blockIdx.x * 64;
    int tn = tid & 15, tm = tid >> 4;

    float acc[4][4] = {};

    int lr  = tid >> 2;
    int lk4 = (tid & 3) * 4;

    for (int k0 = 0; k0 < K; k0 += 16) {
        {
            int m = m0 + lr;
            float4 v = make_float4(0.f, 0.f, 0.f, 0.f);
            if (m < M) {
                if (k0 + lk4 + 3 < K) {
                    v = *(const float4*)(X + (long)m * ldx + k0 + lk4);
                } else {
                    float tmp[4] = {0.f, 0.f, 0.f, 0.f};
                    for (int j = 0; j < 4; j++)
                        if (k0 + lk4 + j < K) tmp[j] = X[(long)m * ldx + k0 + lk4 + j];
                    v = make_float4(tmp[0], tmp[1], tmp[2], tmp[3]);
                }
            }
            Xs[lk4 + 0][lr] = v.x; Xs[lk4 + 1][lr] = v.y;
            Xs[lk4 + 2][lr] = v.z; Xs[lk4 + 3][lr] = v.w;
        }
        {
            int n = n0 + lr;
            float4 v = make_float4(0.f, 0.f, 0.f, 0.f);
            if (n < N) {
                if (k0 + lk4 + 3 < K) {
                    v = *(const float4*)(W + (long)n * K + k0 + lk4);
                } else {
                    float tmp[4] = {0.f, 0.f, 0.f, 0.f};
                    for (int j = 0; j < 4; j++)
                        if (k0 + lk4 + j < K) tmp[j] = W[(long)n * K + k0 + lk4 + j];
                    v = make_float4(tmp[0], tmp[1], tmp[2], tmp[3]);
                }
            }
            Ws[lk4 + 0][lr] = v.x; Ws[lk4 + 1][lr] = v.y;
            Ws[lk4 + 2][lr] = v.z; Ws[lk4 + 3][lr] = v.w;
        }
        __syncthreads();
        #pragma unroll
        for (int k = 0; k < 16; k++) {
            float xr[4], wr[4];
            *(float4*)xr = *(const float4*)&Xs[k][tm * 4];
            *(float4*)wr = *(const float4*)&Ws[k][tn * 4];
            #pragma unroll
            for (int i = 0; i < 4; i++)
                #pragma unroll
                for (int j = 0; j < 4; j++)
                    acc[i][j] = fmaf(xr[i], wr[j], acc[i][j]);
        }
        __syncthreads();
    }

    #pragma unroll
    for (int i = 0; i < 4; i++) {
        int m = m0 + tm * 4 + i;
        if (m >= M) break;
        #pragma unroll
        for (int j = 0; j < 4; j++) {
            int n = n0 + tn * 4 + j;
            if (n >= N) continue;
            float v = acc[i][j];
            if (bias) v += bias[n];
            if (ACT == 1) v = tanhf(v);
            else if (ACT == 2) v = fmaxf(v, 0.f);
            else if (ACT == 3) v = (v > 0.f) ? v : expm1f(v);
            Y[(long)m * ldy + n] = v;
        }
    }
}

// ---------------------------------------------------------------------------
// 128x128-tile fp32 GEMM, BK=8, 8x8 microtile. Requires M%128==0, K%8==0.
// N bounds-checked. ACT: 0=none 1=tanh 3=elu
// ---------------------------------------------------------------------------
template<int ACT>
__global__ __launch_bounds__(256) void gemm128_kernel(
    const float* __restrict__ X, const float* __restrict__ W,
    const float* __restrict__ bias, float* __restrict__ Y,
    int M, int N, int K, long ldx, long ldy)
{
    __shared__ __align__(16) float Xs[8][132];
    __shared__ __align__(16) float Ws[8][132];
    int tid = threadIdx.x;
    int m0 = blockIdx.y * 128;
    int n0 = blockIdx.x * 128;
    int tn = tid & 15, tm = tid >> 4;

    float acc[8][8] = {};

    int lr  = tid >> 1;        // 0..127
    int lk4 = (tid & 1) * 4;   // 0 or 4

    for (int k0 = 0; k0 < K; k0 += 8) {
        {
            int m = m0 + lr;
            float4 v = *(const float4*)(X + (long)m * ldx + k0 + lk4);
            Xs[lk4 + 0][lr] = v.x; Xs[lk4 + 1][lr] = v.y;
            Xs[lk4 + 2][lr] = v.z; Xs[lk4 + 3][lr] = v.w;
        }
        {
            int n = n0 + lr;
            float4 v = make_float4(0.f, 0.f, 0.f, 0.f);
            if (n < N) v = *(const float4*)(W + (long)n * K + k0 + lk4);
            Ws[lk4 + 0][lr] = v.x; Ws[lk4 + 1][lr] = v.y;
            Ws[lk4 + 2][lr] = v.z; Ws[lk4 + 3][lr] = v.w;
        }
        __syncthreads();
        #pragma unroll
        for (int k = 0; k < 8; k++) {
            float xr[8], wr[8];
            *(float4*)&xr[0] = *(const float4*)&Xs[k][tm * 8];
            *(float4*)&xr[4] = *(const float4*)&Xs[k][tm * 8 + 4];
            *(float4*)&wr[0] = *(const float4*)&Ws[k][tn * 8];
            *(float4*)&wr[4] = *(const float4*)&Ws[k][tn * 8 + 4];
            #pragma unroll
            for (int i = 0; i < 8; i++)
                #pragma unroll
                for (int j = 0; j < 8; j++)
                    acc[i][j] = fmaf(xr[i], wr[j], acc[i][j]);
        }
        __syncthreads();
    }

    #pragma unroll
    for (int i = 0; i < 8; i++) {
        int m = m0 + tm * 8 + i;
        #pragma unroll
        for (int j = 0; j < 8; j++) {
            int n = n0 + tn * 8 + j;
            if (n >= N) continue;
            float v = acc[i][j];
            if (bias) v += bias[n];
            if (ACT == 1) v = tanhf(v);
            else if (ACT == 3) v = (v > 0.f) ? v : expm1f(v);
            Y[(long)m * ldy + n] = v;
        }
    }
}

// ---------------------------------------------------------------------------
// depthwise causal conv (k=8) + bias + silu
// ---------------------------------------------------------------------------
__global__ __launch_bounds__(256) void conv_kernel(
    const float* __restrict__ xz, const float* __restrict__ cw,
    const float* __restrict__ cb, float* __restrict__ xc)
{
    int m = blockIdx.y;
    int d = blockIdx.x * 256 + threadIdx.x;
    int l = m & (LSZ - 1);
    float w[8];
    #pragma unroll
    for (int k = 0; k < 8; k++) w[k] = cw[d * 8 + k];
    float acc = cb[d];
    #pragma unroll
    for (int k = 0; k < 8; k++) {
        int li = l - 7 + k;
        if (li >= 0)
            acc = fmaf(xz[(long)(m - 7 + k) * 2560 + d], w[k], acc);
    }
    float s = acc / (1.0f + __expf(-acc));
    xc[(long)m * DIV + d] = s;
}

// ---------------------------------------------------------------------------
// Chunked Mamba scan, phase 1: per-chunk local scan (h0=0).
// Writes y_local (= C.h_local + x*D, NO silu yet) into xz x-half,
// final chunk state to hfin, sum(delta) to sumd.
// grid: (DIV/256, NCHUNK, Bc)
// ---------------------------------------------------------------------------
__global__ __launch_bounds__(256) void scan_local_kernel(
    const float* __restrict__ xc, float* xz, const float* __restrict__ dbc,
    const float* __restrict__ dtw, const float* __restrict__ dtb,
    const float* __restrict__ A_log, const float* __restrict__ Dp,
    float* __restrict__ hfin, float* __restrict__ sumd)
{
    __shared__ float S[CLEN * 52];
    int lb = blockIdx.z;
    int ch = blockIdx.y;
    int d = blockIdx.x * 256 + threadIdx.x;
    int tid = threadIdx.x;

    float dtwr[DTR];
    #pragma unroll
    for (int j = 0; j < DTR; j++) dtwr[j] = dtw[d * DTR + j];
    float dtb_d = dtb[d];

    float a[NST], h[NST];
    #pragma unroll
    for (int n = 0; n < NST; n++) {
        a[n] = -__expf(A_log[d * NST + n]);
        h[n] = 0.f;
    }
    float Dd = Dp[d];

    long tok0 = (long)lb * LSZ + ch * CLEN;
    const float* src = dbc + tok0 * 52;
    for (int i = tid; i < CLEN * 52; i += 256) S[i] = src[i];
    __syncthreads();

    float sd = 0.f;
    for (int l = 0; l < CLEN; l++) {
        long m = tok0 + l;
        const float* row = &S[l * 52];
        float draw = dtb_d;
        #pragma unroll
        for (int j = 0; j < DTR; j++) draw = fmaf(dtwr[j], row[j], draw);
        float delta = (draw > 20.f) ? draw : log1pf(__expf(draw));
        sd += delta;
        float xv = xc[m * DIV + d];
        float db = delta * xv;
        float y = 0.f;
        #pragma unroll
        for (int n = 0; n < NST; n++) {
            float dA = __expf(delta * a[n]);
            h[n] = fmaf(dA, h[n], db * row[20 + n]);
            y = fmaf(h[n], row[36 + n], y);
        }
        y = fmaf(xv, Dd, y);
        xz[m * 2560 + d] = y;   // y_local (silu(z) applied in fix phase)
    }

    long cidx = ((long)lb * NCHUNK + ch) * DIV + d;
    #pragma unroll
    for (int n = 0; n < NST; n++) hfin[cidx * NST + n] = h[n];
    sumd[cidx] = sd;
}

// ---------------------------------------------------------------------------
// Phase 2: sequential prefix over chunks. One thread per (b, d, n).
// Replaces hfin[c] (chunk-final local state) with the state ENTERING chunk c.
// ---------------------------------------------------------------------------
__global__ __launch_bounds__(256) void scan_prefix_kernel(
    float* __restrict__ hfin, const float* __restrict__ sumd,
    const float* __restrict__ A_log, int Bc)
{
    long g = (long)blockIdx.x * 256 + threadIdx.x;
    int n = (int)(g & (NST - 1));
    long t = g >> 4;
    int d = (int)(t % DIV);
    int lb = (int)(t / DIV);
    if (lb >= Bc) return;

    float a = -__expf(A_log[d * NST + n]);
    float s = 0.f;
    for (int c = 0; c < NCHUNK; c++) {
        long cidx = ((long)lb * NCHUNK + c) * DIV + d;
        float hl = hfin[cidx * NST + n];
        float P = __expf(a * sumd[cidx]);
        hfin[cidx * NST + n] = s;
        s = fmaf(P, s, hl);
    }
}

// ---------------------------------------------------------------------------
// Phase 3: add cross-chunk contribution and apply silu(z).
// y = y_local + C . (exp(a*cumdelta) * h_in);  out = y * silu(z)
// grid: (DIV/256, NCHUNK, Bc)
// ---------------------------------------------------------------------------
__global__ __launch_bounds__(256) void scan_fix_kernel(
    float* xz, const float* __restrict__ dbc,
    const float* __restrict__ dtw, const float* __restrict__ dtb,
    const float* __restrict__ A_log, const float* __restrict__ hfin)
{
    __shared__ float S[CLEN * 52];
    int lb = blockIdx.z;
    int ch = blockIdx.y;
    int d = blockIdx.x * 256 + threadIdx.x;
    int tid = threadIdx.x;

    float dtwr[DTR];
    #pragma unroll
    for (int j = 0; j < DTR; j++) dtwr[j] = dtw[d * DTR + j];
    float dtb_d = dtb[d];

    float a[NST], hin[NST];
    #pragma unroll
    for (int n = 0; n < NST; n++) a[n] = -__expf(A_log[d * NST + n]);
    long cidx = ((long)lb * NCHUNK + ch) * DIV + d;
    #pragma unroll
    for (int n = 0; n < NST; n += 4)
        *(float4*)&hin[n] = *(const float4*)&hfin[cidx * NST + n];

    long tok0 = (long)lb * LSZ + ch * CLEN;
    const float* src = dbc + tok0 * 52;
    for (int i = tid; i < CLEN * 52; i += 256) S[i] = src[i];
    __syncthreads();

    float cum = 0.f;
    for (int l = 0; l < CLEN; l++) {
        long m = tok0 + l;
        const float* row = &S[l * 52];
        float draw = dtb_d;
        #pragma unroll
        for (int j = 0; j < DTR; j++) draw = fmaf(dtwr[j], row[j], draw);
        float delta = (draw > 20.f) ? draw : log1pf(__expf(draw));
        cum += delta;
        float fix = 0.f;
        #pragma unroll
        for (int n = 0; n < NST; n++)
            fix = fmaf(__expf(a[n] * cum) * hin[n], row[36 + n], fix);
        float y = xz[m * 2560 + d] + fix;
        float zv = xz[m * 2560 + 1280 + d];
        float sz = zv / (1.0f + __expf(-zv));
        xz[m * 2560 + d] = y * sz;
    }
}

// ---------------------------------------------------------------------------
__global__ void final_kernel(const float* __restrict__ h3, const float* __restrict__ sm,
                             float* __restrict__ out, int Bc) {
    int t = threadIdx.x;
    if (t < Bc) {
        float scale = sm[0] / 8.624618986159398f;   // 1 + ln(2048)
        out[t] = fmaxf(h3[t] * scale, 0.f);
    }
}

// ---------------------------------------------------------------------------
extern "C" void kernel_launch(void* const* d_in, const int* in_sizes, int n_in,
                              void* d_out, int out_size, void* d_ws, size_t ws_size,
                              hipStream_t stream) {
    const float* x        = (const float*)d_in[0];
    const float* fc_w     = (const float*)d_in[1];
    const float* fc_b     = (const float*)d_in[2];
    const float* lin_w    = (const float*)d_in[3];
    const float* lin_b    = (const float*)d_in[4];
    const float* inproj_w = (const float*)d_in[5];
    const float* conv_w   = (const float*)d_in[6];
    const float* conv_b   = (const float*)d_in[7];
    const float* xproj_w  = (const float*)d_in[8];
    const float* dtproj_w = (const float*)d_in[9];
    const float* dtproj_b = (const float*)d_in[10];
    const float* A_log    = (const float*)d_in[11];
    const float* Dp       = (const float*)d_in[12];
    const float* outproj_w= (const float*)d_in[13];
    const float* s1_w1    = (const float*)d_in[14];
    const float* s1_b1    = (const float*)d_in[15];
    const float* s1_w2    = (const float*)d_in[16];
    const float* s1_b2    = (const float*)d_in[17];
    const float* s1_w3    = (const float*)d_in[18];
    const float* s1_b3    = (const float*)d_in[19];

    // ---- workspace sizing: pick largest batch-chunk that fits ----
    const long HDR = 8448;
    const long PER_TOK = 320 + 320 + 2560 + 1280 + 52;   // 4532 floats
    int Bc = 8;
    while (Bc > 1 && (size_t)(HDR + (long)Bc * LSZ * PER_TOK) * 4 > ws_size)
        Bc >>= 1;
    int nchunk_b = BSZ / Bc;
    long Mc = (long)Bc * LSZ;

    float* ws = (float*)d_ws;
    float* sm  = ws;               // 16
    float* h1  = sm + 16;          // 4096
    float* h2  = h1 + 4096;        // 4096
    float* h3  = h2 + 4096;        // 16
    float* u   = ws + HDR;         // Mc*320
    float* t   = u  + Mc * DMV;    // Mc*320
    float* xz  = t  + Mc * DMV;    // Mc*2560
    float* xc  = xz + Mc * 2560;   // Mc*1280
    float* dbc = xc + Mc * DIV;    // Mc*52

    // scan scratch aliases dead buffers:
    //   hfin needs Bc*NCHUNK*DIV*NST = Bc*655360 floats == t's size exactly.
    //   sumd needs Bc*NCHUNK*DIV = Bc*40960 floats <= u's size (u dead in scan).
    float* hfin = t;
    float* sumd = u;

    init_sm_kernel<<<1, 64, 0, stream>>>(sm);
    reduce_max_kernel<<<32, 256, 0, stream>>>(x, sm);

    for (int c = 0; c < nchunk_b; c++) {
        int b0 = c * Bc;
        fc_kernel<<<dim3(5, (unsigned)Mc), 64, 0, stream>>>(
            x + (long)b0 * LSZ * 4, fc_w, fc_b, sm, u);

        for (int i = 0; i < NBLKV; i++) {
            const float* lw  = lin_w    + (long)i * DMV * DMV;
            const float* lb  = lin_b    + (long)i * DMV;
            const float* ipw = inproj_w + (long)i * 2 * DIV * DMV;
            const float* cw  = conv_w   + (long)i * DIV * DCV;
            const float* cb  = conv_b   + (long)i * DIV;
            const float* xpw = xproj_w  + (long)i * (DTR + 2 * NST) * DIV;
            const float* dpw = dtproj_w + (long)i * DIV * DTR;
            const float* dpb = dtproj_b + (long)i * DIV;
            const float* al  = A_log    + (long)i * DIV * NST;
            const float* dd  = Dp       + (long)i * DIV;
            const float* opw = outproj_w+ (long)i * DMV * DIV;

            // lin + tanh: (Mc x320)@(320x320)^T
            gemm128_kernel<1><<<dim3(3, (unsigned)(Mc / 128)), 256, 0, stream>>>(
                u, lw, lb, t, (int)Mc, DMV, DMV, DMV, DMV);
            // inproj: (Mc x320)@(2560x320)^T -> xz
            gemm128_kernel<0><<<dim3(20, (unsigned)(Mc / 128)), 256, 0, stream>>>(
                t, ipw, nullptr, xz, (int)Mc, 2 * DIV, DMV, DMV, 2 * DIV);
            // conv + silu
            conv_kernel<<<dim3(5, (unsigned)Mc), 256, 0, stream>>>(xz, cw, cb, xc);
            // xproj: (Mc x1280)@(52x1280)^T -> dbc
            gemm_kernel<0><<<dim3(1, (unsigned)(Mc / 64)), 256, 0, stream>>>(
                xc, xpw, nullptr, dbc, (int)Mc, DTR + 2 * NST, DIV, DIV, DTR + 2 * NST);
            // chunked scan
            scan_local_kernel<<<dim3(5, NCHUNK, Bc), 256, 0, stream>>>(
                xc, xz, dbc, dpw, dpb, al, dd, hfin, sumd);
            scan_prefix_kernel<<<dim3(Bc * 80), 256, 0, stream>>>(hfin, sumd, al, Bc);
            scan_fix_kernel<<<dim3(5, NCHUNK, Bc), 256, 0, stream>>>(
                xz, dbc, dpw, dpb, al, hfin);
            // outproj + elu: (Mc x1280)@(320x1280)^T -> u
            gemm128_kernel<3><<<dim3(3, (unsigned)(Mc / 128)), 256, 0, stream>>>(
                xz, opw, nullptr, u, (int)Mc, DMV, DIV, 2 * DIV, DMV);
        }

        // head on last token of each batch in chunk
        gemm_kernel<2><<<dim3(8, 1), 256, 0, stream>>>(
            u + (long)(LSZ - 1) * DMV, s1_w1, s1_b1, h1,
            Bc, 512, DMV, (long)LSZ * DMV, 512);
        gemm_kernel<2><<<dim3(8, 1), 256, 0, stream>>>(h1, s1_w2, s1_b2, h2,
            Bc, 512, 512, 512, 512);
        gemm_kernel<0><<<dim3(1, 1), 256, 0, stream>>>(h2, s1_w3, s1_b3, h3,
            Bc, 1, 512, 512, 1);
        final_kernel<<<1, 64, 0, stream>>>(h3, sm, (float*)d_out + b0, Bc);
    }
}

// Round 4
// 3332.340 us; speedup vs baseline: 5.1072x; 2.0715x over previous
//
#include <hip/hip_runtime.h>
#include <math.h>

// Problem constants
#define BSZ 8
#define LSZ 2048
#define DMV 320
#define DIV 1280
#define NST 16
#define DCV 8
#define DTR 20
#define NBLKV 4
#define MTOT (BSZ*LSZ)   // 16384
#define NCHUNK 32
#define CLEN 64          // NCHUNK*CLEN == LSZ

typedef __attribute__((ext_vector_type(8))) short short8;
typedef __attribute__((ext_vector_type(4))) float floatx4;

__device__ inline short f2bf(float f) {
    union { float f; unsigned u; } v; v.f = f;
    unsigned r = v.u + 0x7FFFu + ((v.u >> 16) & 1u);
    return (short)(r >> 16);
}

// ---------------------------------------------------------------------------
// start_max reduction (x[:,:,2] >= 0, so int-compare atomicMax is valid)
// ---------------------------------------------------------------------------
__global__ void init_sm_kernel(float* sm) {
    if (threadIdx.x == 0) ((int*)sm)[0] = 0;
}

__global__ void reduce_max_kernel(const float* __restrict__ x, float* sm) {
    int idx = blockIdx.x * blockDim.x + threadIdx.x;
    float v = 0.f;
    for (int i = idx; i < MTOT; i += gridDim.x * blockDim.x)
        v = fmaxf(v, x[i * 4 + 2]);
    #pragma unroll
    for (int off = 32; off > 0; off >>= 1)
        v = fmaxf(v, __shfl_xor(v, off, 64));
    if ((threadIdx.x & 63) == 0)
        atomicMax((int*)sm, __float_as_int(v));
}

// ---------------------------------------------------------------------------
// input normalize + fc (K=4).  256 threads = 64 outputs x 4 rows.
// grid (DMV/64, Mc/4)
// ---------------------------------------------------------------------------
__global__ __launch_bounds__(256) void fc_kernel(
    const float* __restrict__ x, const float* __restrict__ fw,
    const float* __restrict__ fb, const float* __restrict__ sm,
    float* __restrict__ u) {
    int o = blockIdx.x * 64 + (threadIdx.x & 63);
    long m = (long)blockIdx.y * 4 + (threadIdx.x >> 6);
    float inv_sm = 1.0f / sm[0];
    float x0 = x[m * 4 + 0] * (1.0f / 255.0f);
    float x1 = x[m * 4 + 1] * (1.0f / 255.0f);
    float x2 = x[m * 4 + 2] * inv_sm;
    float x3 = x[m * 4 + 3];
    float acc = fb[o];
    acc = fmaf(x0, fw[o * 4 + 0], acc);
    acc = fmaf(x1, fw[o * 4 + 1], acc);
    acc = fmaf(x2, fw[o * 4 + 2], acc);
    acc = fmaf(x3, fw[o * 4 + 3], acc);
    u[m * DMV + o] = acc;
}

// ---------------------------------------------------------------------------
// bf16 MFMA GEMM: Y[m,n] = act(sum_k X[m,k]*W[n,k] (+bias))
// BM=128, BK=32, BN in {64,128}. 256 threads = 4 waves.
//   BN=128: wave quadrants 64x64 (wm=wave&1, wn=wave>>1), 4x4 frag grid
//   BN=64 : wave rows 32 (wm=wave*32), 2x4 frag grid
// fp32 -> bf16 (RNE) conversion fused into LDS staging.
// Requires M%128==0, K%32==0; N bounds-checked.
// A/B frag: lane holds 8 contig k at row=lane&15, k0=(lane>>4)*8 [m89/m91]
// C/D: row = (lane>>4)*4 + reg, col = lane&15                    [m89/m91]
// ACT: 0=none 1=tanh 3=elu
// ---------------------------------------------------------------------------
template<int ACT, int BN>
__global__ __launch_bounds__(256) void gemm_mfma_kernel(
    const float* __restrict__ X, const float* __restrict__ W,
    const float* __restrict__ bias, float* __restrict__ Y,
    int N, int K, long ldx, long ldy)
{
    constexpr int WMT = (BN == 128) ? 4 : 2;     // 16-row subtiles per wave
    __shared__ short Xs[128 * 40];               // 32 k + 8 pad per row
    __shared__ short Ws[BN * 40];

    int tid = threadIdx.x;
    int wave = tid >> 6, lane = tid & 63;
    int quad = lane >> 4, l15 = lane & 15;
    int wmbase = (BN == 128) ? (wave & 1) * 64 : wave * 32;
    int wnbase = (BN == 128) ? (wave >> 1) * 64 : 0;
    long m0 = (long)blockIdx.y * 128;
    int n0 = blockIdx.x * BN;

    floatx4 acc[WMT][4];
    #pragma unroll
    for (int i = 0; i < WMT; i++)
        #pragma unroll
        for (int j = 0; j < 4; j++)
            acc[i][j] = (floatx4){0.f, 0.f, 0.f, 0.f};

    int sr = tid >> 2;            // 0..63
    int sk = (tid & 3) * 8;       // 0,8,16,24

    for (int k0 = 0; k0 < K; k0 += 32) {
        #pragma unroll
        for (int r0 = 0; r0 < 128; r0 += 64) {
            int r = r0 + sr;
            const float* p = X + (m0 + r) * ldx + k0 + sk;
            float4 v0 = *(const float4*)p;
            float4 v1 = *(const float4*)(p + 4);
            short8 s;
            s[0]=f2bf(v0.x); s[1]=f2bf(v0.y); s[2]=f2bf(v0.z); s[3]=f2bf(v0.w);
            s[4]=f2bf(v1.x); s[5]=f2bf(v1.y); s[6]=f2bf(v1.z); s[7]=f2bf(v1.w);
            *(short8*)&Xs[r * 40 + sk] = s;
        }
        #pragma unroll
        for (int r0 = 0; r0 < BN; r0 += 64) {
            int r = r0 + sr;
            int n = n0 + r;
            float4 v0 = make_float4(0.f,0.f,0.f,0.f), v1 = v0;
            if (n < N) {
                const float* p = W + (long)n * K + k0 + sk;
                v0 = *(const float4*)p;
                v1 = *(const float4*)(p + 4);
            }
            short8 s;
            s[0]=f2bf(v0.x); s[1]=f2bf(v0.y); s[2]=f2bf(v0.z); s[3]=f2bf(v0.w);
            s[4]=f2bf(v1.x); s[5]=f2bf(v1.y); s[6]=f2bf(v1.z); s[7]=f2bf(v1.w);
            *(short8*)&Ws[r * 40 + sk] = s;
        }
        __syncthreads();
        short8 af[WMT], bfr[4];
        #pragma unroll
        for (int i = 0; i < WMT; i++)
            af[i] = *(short8*)&Xs[(wmbase + i * 16 + l15) * 40 + quad * 8];
        #pragma unroll
        for (int j = 0; j < 4; j++)
            bfr[j] = *(short8*)&Ws[(wnbase + j * 16 + l15) * 40 + quad * 8];
        #pragma unroll
        for (int i = 0; i < WMT; i++)
            #pragma unroll
            for (int j = 0; j < 4; j++)
                acc[i][j] = __builtin_amdgcn_mfma_f32_16x16x32_bf16(
                    af[i], bfr[j], acc[i][j], 0, 0, 0);
        __syncthreads();
    }

    #pragma unroll
    for (int i = 0; i < WMT; i++) {
        long mb = m0 + wmbase + i * 16 + quad * 4;
        #pragma unroll
        for (int j = 0; j < 4; j++) {
            int n = n0 + wnbase + j * 16 + l15;
            if (n >= N) continue;
            float bv = bias ? bias[n] : 0.f;
            #pragma unroll
            for (int r = 0; r < 4; r++) {
                float v = acc[i][j][r] + bv;
                if (ACT == 1) v = tanhf(v);
                else if (ACT == 3) v = (v > 0.f) ? v : expm1f(v);
                Y[(mb + r) * ldy + n] = v;
            }
        }
    }
}

// ---------------------------------------------------------------------------
// small fp32 GEMM for the head (M=8): Y = act(X@W^T + bias)
// ACT: 0=none 2=relu
// ---------------------------------------------------------------------------
template<int ACT>
__global__ __launch_bounds__(256) void gemm_kernel(
    const float* __restrict__ X, const float* __restrict__ W,
    const float* __restrict__ bias, float* __restrict__ Y,
    int M, int N, int K, long ldx, long ldy)
{
    __shared__ __align__(16) float Xs[16][68];
    __shared__ __align__(16) float Ws[16][68];
    int tid = threadIdx.x;
    int m0 = blockIdx.y * 64;
    int n0 = blockIdx.x * 64;
    int tn = tid & 15, tm = tid >> 4;

    float acc[4][4] = {};

    int lr  = tid >> 2;
    int lk4 = (tid & 3) * 4;

    for (int k0 = 0; k0 < K; k0 += 16) {
        {
            int m = m0 + lr;
            float4 v = make_float4(0.f, 0.f, 0.f, 0.f);
            if (m < M) {
                if (k0 + lk4 + 3 < K) {
                    v = *(const float4*)(X + (long)m * ldx + k0 + lk4);
                } else {
                    float tmp[4] = {0.f, 0.f, 0.f, 0.f};
                    for (int j = 0; j < 4; j++)
                        if (k0 + lk4 + j < K) tmp[j] = X[(long)m * ldx + k0 + lk4 + j];
                    v = make_float4(tmp[0], tmp[1], tmp[2], tmp[3]);
                }
            }
            Xs[lk4 + 0][lr] = v.x; Xs[lk4 + 1][lr] = v.y;
            Xs[lk4 + 2][lr] = v.z; Xs[lk4 + 3][lr] = v.w;
        }
        {
            int n = n0 + lr;
            float4 v = make_float4(0.f, 0.f, 0.f, 0.f);
            if (n < N) {
                if (k0 + lk4 + 3 < K) {
                    v = *(const float4*)(W + (long)n * K + k0 + lk4);
                } else {
                    float tmp[4] = {0.f, 0.f, 0.f, 0.f};
                    for (int j = 0; j < 4; j++)
                        if (k0 + lk4 + j < K) tmp[j] = W[(long)n * K + k0 + lk4 + j];
                    v = make_float4(tmp[0], tmp[1], tmp[2], tmp[3]);
                }
            }
            Ws[lk4 + 0][lr] = v.x; Ws[lk4 + 1][lr] = v.y;
            Ws[lk4 + 2][lr] = v.z; Ws[lk4 + 3][lr] = v.w;
        }
        __syncthreads();
        #pragma unroll
        for (int k = 0; k < 16; k++) {
            float xr[4], wr[4];
            *(float4*)xr = *(const float4*)&Xs[k][tm * 4];
            *(float4*)wr = *(const float4*)&Ws[k][tn * 4];
            #pragma unroll
            for (int i = 0; i < 4; i++)
                #pragma unroll
                for (int j = 0; j < 4; j++)
                    acc[i][j] = fmaf(xr[i], wr[j], acc[i][j]);
        }
        __syncthreads();
    }

    #pragma unroll
    for (int i = 0; i < 4; i++) {
        int m = m0 + tm * 4 + i;
        if (m >= M) break;
        #pragma unroll
        for (int j = 0; j < 4; j++) {
            int n = n0 + tn * 4 + j;
            if (n >= N) continue;
            float v = acc[i][j];
            if (bias) v += bias[n];
            if (ACT == 2) v = fmaxf(v, 0.f);
            Y[(long)m * ldy + n] = v;
        }
    }
}

// ---------------------------------------------------------------------------
// depthwise causal conv (k=8) + bias + silu, sliding-window registers.
// 32 tokens per thread. grid (DIV/256, LSZ/32, Bc)
// ---------------------------------------------------------------------------
#define TCONV 32
__global__ __launch_bounds__(256) void conv_kernel(
    const float* __restrict__ xz, const float* __restrict__ cw,
    const float* __restrict__ cb, float* __restrict__ xc)
{
    int d = blockIdx.x * 256 + threadIdx.x;
    int lb = blockIdx.z;
    int l0 = blockIdx.y * TCONV;
    long base = (long)lb * LSZ + l0;

    float w[8];
    #pragma unroll
    for (int k = 0; k < 8; k++) w[k] = cw[d * 8 + k];
    float bc = cb[d];

    float win[8];
    #pragma unroll
    for (int i = 0; i < 7; i++) {
        int l = l0 - 7 + i;
        win[i] = (l >= 0) ? xz[(base - 7 + i) * 2560 + d] : 0.f;
    }
    #pragma unroll
    for (int s = 0; s < TCONV; s++) {
        win[7] = xz[(base + s) * 2560 + d];
        float acc = bc;
        #pragma unroll
        for (int k = 0; k < 8; k++) acc = fmaf(win[k], w[k], acc);
        float sv = acc / (1.0f + __expf(-acc));
        xc[(base + s) * DIV + d] = sv;
        #pragma unroll
        for (int k = 0; k < 7; k++) win[k] = win[k + 1];
    }
}

// ---------------------------------------------------------------------------
// Chunked Mamba scan, phase 1: per-chunk local scan (h0=0).
// ---------------------------------------------------------------------------
__global__ __launch_bounds__(256) void scan_local_kernel(
    const float* __restrict__ xc, float* xz, const float* __restrict__ dbc,
    const float* __restrict__ dtw, const float* __restrict__ dtb,
    const float* __restrict__ A_log, const float* __restrict__ Dp,
    float* __restrict__ hfin, float* __restrict__ sumd)
{
    __shared__ float S[CLEN * 52];
    int lb = blockIdx.z;
    int ch = blockIdx.y;
    int d = blockIdx.x * 256 + threadIdx.x;
    int tid = threadIdx.x;

    float dtwr[DTR];
    #pragma unroll
    for (int j = 0; j < DTR; j++) dtwr[j] = dtw[d * DTR + j];
    float dtb_d = dtb[d];

    float a[NST], h[NST];
    #pragma unroll
    for (int n = 0; n < NST; n++) {
        a[n] = -__expf(A_log[d * NST + n]);
        h[n] = 0.f;
    }
    float Dd = Dp[d];

    long tok0 = (long)lb * LSZ + ch * CLEN;
    const float* src = dbc + tok0 * 52;
    for (int i = tid; i < CLEN * 52; i += 256) S[i] = src[i];
    __syncthreads();

    float sd = 0.f;
    for (int l = 0; l < CLEN; l++) {
        long m = tok0 + l;
        const float* row = &S[l * 52];
        float draw = dtb_d;
        #pragma unroll
        for (int j = 0; j < DTR; j++) draw = fmaf(dtwr[j], row[j], draw);
        float delta = (draw > 20.f) ? draw : log1pf(__expf(draw));
        sd += delta;
        float xv = xc[m * DIV + d];
        float db = delta * xv;
        float y = 0.f;
        #pragma unroll
        for (int n = 0; n < NST; n++) {
            float dA = __expf(delta * a[n]);
            h[n] = fmaf(dA, h[n], db * row[20 + n]);
            y = fmaf(h[n], row[36 + n], y);
        }
        y = fmaf(xv, Dd, y);
        xz[m * 2560 + d] = y;   // y_local (silu(z) applied in fix phase)
    }

    long cidx = ((long)lb * NCHUNK + ch) * DIV + d;
    #pragma unroll
    for (int n = 0; n < NST; n++) hfin[cidx * NST + n] = h[n];
    sumd[cidx] = sd;
}

// ---------------------------------------------------------------------------
// Phase 2: sequential prefix over chunks. One thread per (b, d, n).
// ---------------------------------------------------------------------------
__global__ __launch_bounds__(256) void scan_prefix_kernel(
    float* __restrict__ hfin, const float* __restrict__ sumd,
    const float* __restrict__ A_log, int Bc)
{
    long g = (long)blockIdx.x * 256 + threadIdx.x;
    int n = (int)(g & (NST - 1));
    long t = g >> 4;
    int d = (int)(t % DIV);
    int lb = (int)(t / DIV);
    if (lb >= Bc) return;

    float a = -__expf(A_log[d * NST + n]);
    float s = 0.f;
    for (int c = 0; c < NCHUNK; c++) {
        long cidx = ((long)lb * NCHUNK + c) * DIV + d;
        float hl = hfin[cidx * NST + n];
        float P = __expf(a * sumd[cidx]);
        hfin[cidx * NST + n] = s;
        s = fmaf(P, s, hl);
    }
}

// ---------------------------------------------------------------------------
// Phase 3: add cross-chunk contribution and apply silu(z).
// ---------------------------------------------------------------------------
__global__ __launch_bounds__(256) void scan_fix_kernel(
    float* xz, const float* __restrict__ dbc,
    const float* __restrict__ dtw, const float* __restrict__ dtb,
    const float* __restrict__ A_log, const float* __restrict__ hfin)
{
    __shared__ float S[CLEN * 52];
    int lb = blockIdx.z;
    int ch = blockIdx.y;
    int d = blockIdx.x * 256 + threadIdx.x;
    int tid = threadIdx.x;

    float dtwr[DTR];
    #pragma unroll
    for (int j = 0; j < DTR; j++) dtwr[j] = dtw[d * DTR + j];
    float dtb_d = dtb[d];

    float a[NST], hin[NST];
    #pragma unroll
    for (int n = 0; n < NST; n++) a[n] = -__expf(A_log[d * NST + n]);
    long cidx = ((long)lb * NCHUNK + ch) * DIV + d;
    #pragma unroll
    for (int n = 0; n < NST; n += 4)
        *(float4*)&hin[n] = *(const float4*)&hfin[cidx * NST + n];

    long tok0 = (long)lb * LSZ + ch * CLEN;
    const float* src = dbc + tok0 * 52;
    for (int i = tid; i < CLEN * 52; i += 256) S[i] = src[i];
    __syncthreads();

    float cum = 0.f;
    for (int l = 0; l < CLEN; l++) {
        long m = tok0 + l;
        const float* row = &S[l * 52];
        float draw = dtb_d;
        #pragma unroll
        for (int j = 0; j < DTR; j++) draw = fmaf(dtwr[j], row[j], draw);
        float delta = (draw > 20.f) ? draw : log1pf(__expf(draw));
        cum += delta;
        float fix = 0.f;
        #pragma unroll
        for (int n = 0; n < NST; n++)
            fix = fmaf(__expf(a[n] * cum) * hin[n], row[36 + n], fix);
        float y = xz[m * 2560 + d] + fix;
        float zv = xz[m * 2560 + 1280 + d];
        float sz = zv / (1.0f + __expf(-zv));
        xz[m * 2560 + d] = y * sz;
    }
}

// ---------------------------------------------------------------------------
__global__ void final_kernel(const float* __restrict__ h3, const float* __restrict__ sm,
                             float* __restrict__ out, int Bc) {
    int t = threadIdx.x;
    if (t < Bc) {
        float scale = sm[0] / 8.624618986159398f;   // 1 + ln(2048)
        out[t] = fmaxf(h3[t] * scale, 0.f);
    }
}

// ---------------------------------------------------------------------------
extern "C" void kernel_launch(void* const* d_in, const int* in_sizes, int n_in,
                              void* d_out, int out_size, void* d_ws, size_t ws_size,
                              hipStream_t stream) {
    const float* x        = (const float*)d_in[0];
    const float* fc_w     = (const float*)d_in[1];
    const float* fc_b     = (const float*)d_in[2];
    const float* lin_w    = (const float*)d_in[3];
    const float* lin_b    = (const float*)d_in[4];
    const float* inproj_w = (const float*)d_in[5];
    const float* conv_w   = (const float*)d_in[6];
    const float* conv_b   = (const float*)d_in[7];
    const float* xproj_w  = (const float*)d_in[8];
    const float* dtproj_w = (const float*)d_in[9];
    const float* dtproj_b = (const float*)d_in[10];
    const float* A_log    = (const float*)d_in[11];
    const float* Dp       = (const float*)d_in[12];
    const float* outproj_w= (const float*)d_in[13];
    const float* s1_w1    = (const float*)d_in[14];
    const float* s1_b1    = (const float*)d_in[15];
    const float* s1_w2    = (const float*)d_in[16];
    const float* s1_b2    = (const float*)d_in[17];
    const float* s1_w3    = (const float*)d_in[18];
    const float* s1_b3    = (const float*)d_in[19];

    // ---- workspace sizing: pick largest batch-chunk that fits ----
    const long HDR = 8448;
    const long PER_TOK = 320 + 320 + 2560 + 1280 + 52;   // 4532 floats
    int Bc = 8;
    while (Bc > 1 && (size_t)(HDR + (long)Bc * LSZ * PER_TOK) * 4 > ws_size)
        Bc >>= 1;
    int nchunk_b = BSZ / Bc;
    long Mc = (long)Bc * LSZ;

    float* ws = (float*)d_ws;
    float* sm  = ws;               // 16
    float* h1  = sm + 16;          // 4096
    float* h2  = h1 + 4096;        // 4096
    float* h3  = h2 + 4096;        // 16
    float* u   = ws + HDR;         // Mc*320
    float* t   = u  + Mc * DMV;    // Mc*320
    float* xz  = t  + Mc * DMV;    // Mc*2560
    float* xc  = xz + Mc * 2560;   // Mc*1280
    float* dbc = xc + Mc * DIV;    // Mc*52

    // scan scratch aliases dead buffers (t dead after inproj; u dead mid-layer)
    float* hfin = t;
    float* sumd = u;

    init_sm_kernel<<<1, 64, 0, stream>>>(sm);
    reduce_max_kernel<<<32, 256, 0, stream>>>(x, sm);

    for (int c = 0; c < nchunk_b; c++) {
        int b0 = c * Bc;
        fc_kernel<<<dim3(5, (unsigned)(Mc / 4)), 256, 0, stream>>>(
            x + (long)b0 * LSZ * 4, fc_w, fc_b, sm, u);

        for (int i = 0; i < NBLKV; i++) {
            const float* lw  = lin_w    + (long)i * DMV * DMV;
            const float* lb  = lin_b    + (long)i * DMV;
            const float* ipw = inproj_w + (long)i * 2 * DIV * DMV;
            const float* cw  = conv_w   + (long)i * DIV * DCV;
            const float* cb  = conv_b   + (long)i * DIV;
            const float* xpw = xproj_w  + (long)i * (DTR + 2 * NST) * DIV;
            const float* dpw = dtproj_w + (long)i * DIV * DTR;
            const float* dpb = dtproj_b + (long)i * DIV;
            const float* al  = A_log    + (long)i * DIV * NST;
            const float* dd  = Dp       + (long)i * DIV;
            const float* opw = outproj_w+ (long)i * DMV * DIV;

            // lin + tanh: (Mc x320)@(320x320)^T -> t
            gemm_mfma_kernel<1, 64><<<dim3(5, (unsigned)(Mc / 128)), 256, 0, stream>>>(
                u, lw, lb, t, DMV, DMV, DMV, DMV);
            // inproj: (Mc x320)@(2560x320)^T -> xz
            gemm_mfma_kernel<0, 128><<<dim3(20, (unsigned)(Mc / 128)), 256, 0, stream>>>(
                t, ipw, nullptr, xz, 2 * DIV, DMV, DMV, 2 * DIV);
            // conv + silu (sliding window)
            conv_kernel<<<dim3(5, LSZ / TCONV, Bc), 256, 0, stream>>>(xz, cw, cb, xc);
            // xproj: (Mc x1280)@(52x1280)^T -> dbc
            gemm_mfma_kernel<0, 64><<<dim3(1, (unsigned)(Mc / 128)), 256, 0, stream>>>(
                xc, xpw, nullptr, dbc, DTR + 2 * NST, DIV, DIV, DTR + 2 * NST);
            // chunked scan
            scan_local_kernel<<<dim3(5, NCHUNK, Bc), 256, 0, stream>>>(
                xc, xz, dbc, dpw, dpb, al, dd, hfin, sumd);
            scan_prefix_kernel<<<dim3(Bc * 80), 256, 0, stream>>>(hfin, sumd, al, Bc);
            scan_fix_kernel<<<dim3(5, NCHUNK, Bc), 256, 0, stream>>>(
                xz, dbc, dpw, dpb, al, hfin);
            // outproj + elu: (Mc x1280)@(320x1280)^T -> u
            gemm_mfma_kernel<3, 64><<<dim3(5, (unsigned)(Mc / 128)), 256, 0, stream>>>(
                xz, opw, nullptr, u, DMV, DIV, 2 * DIV, DMV);
        }

        // head on last token of each batch in chunk (M=8, fp32)
        gemm_kernel<2><<<dim3(8, 1), 256, 0, stream>>>(
            u + (long)(LSZ - 1) * DMV, s1_w1, s1_b1, h1,
            Bc, 512, DMV, (long)LSZ * DMV, 512);
        gemm_kernel<2><<<dim3(8, 1), 256, 0, stream>>>(h1, s1_w2, s1_b2, h2,
            Bc, 512, 512, 512, 512);
        gemm_kernel<0><<<dim3(1, 1), 256, 0, stream>>>(h2, s1_w3, s1_b3, h3,
            Bc, 1, 512, 512, 1);
        final_kernel<<<1, 64, 0, stream>>>(h3, sm, (float*)d_out + b0, Bc);
    }
}

// Round 5
// 2001.647 us; speedup vs baseline: 8.5025x; 1.6648x over previous
//
#include <hip/hip_runtime.h>
#include <math.h>

// Problem constants
#define BSZ 8
#define LSZ 2048
#define DMV 320
#define DIV 1280
#define NST 16
#define DCV 8
#define DTR 20
#define NBLKV 4
#define MTOT (BSZ*LSZ)   // 16384
#define NCHUNK 32
#define CLEN 64          // NCHUNK*CLEN == LSZ

typedef __attribute__((ext_vector_type(8))) short short8;
typedef __attribute__((ext_vector_type(8))) unsigned short ushort8;
typedef __attribute__((ext_vector_type(4))) float floatx4;

__device__ inline unsigned short f2bf(float f) {
    union { float f; unsigned u; } v; v.f = f;
    unsigned r = v.u + 0x7FFFu + ((v.u >> 16) & 1u);
    return (unsigned short)(r >> 16);
}
__device__ inline float bf2f(unsigned short b) {
    union { unsigned u; float f; } v; v.u = ((unsigned)b) << 16;
    return v.f;
}

// ---------------------------------------------------------------------------
// fp32 -> bf16 weight conversion (grid-stride, n % 4 == 0)
// ---------------------------------------------------------------------------
__global__ __launch_bounds__(256) void convert_kernel(
    const float* __restrict__ src, unsigned short* __restrict__ dst, long n4) {
    long i = (long)blockIdx.x * 256 + threadIdx.x;
    if (i >= n4) return;
    float4 v = *(const float4*)(src + i * 4);
    unsigned short o[4] = {f2bf(v.x), f2bf(v.y), f2bf(v.z), f2bf(v.w)};
    *(unsigned long long*)(dst + i * 4) = *(unsigned long long*)o;
}

// ---------------------------------------------------------------------------
// start_max reduction (x[:,:,2] >= 0, so int-compare atomicMax is valid)
// ---------------------------------------------------------------------------
__global__ void init_sm_kernel(float* sm) {
    if (threadIdx.x == 0) ((int*)sm)[0] = 0;
}

__global__ void reduce_max_kernel(const float* __restrict__ x, float* sm) {
    int idx = blockIdx.x * blockDim.x + threadIdx.x;
    float v = 0.f;
    for (int i = idx; i < MTOT; i += gridDim.x * blockDim.x)
        v = fmaxf(v, x[i * 4 + 2]);
    #pragma unroll
    for (int off = 32; off > 0; off >>= 1)
        v = fmaxf(v, __shfl_xor(v, off, 64));
    if ((threadIdx.x & 63) == 0)
        atomicMax((int*)sm, __float_as_int(v));
}

// ---------------------------------------------------------------------------
// input normalize + fc (K=4) -> bf16 u. 256 threads = 64 outputs x 4 rows.
// ---------------------------------------------------------------------------
__global__ __launch_bounds__(256) void fc_kernel(
    const float* __restrict__ x, const float* __restrict__ fw,
    const float* __restrict__ fb, const float* __restrict__ sm,
    unsigned short* __restrict__ u) {
    int o = blockIdx.x * 64 + (threadIdx.x & 63);
    long m = (long)blockIdx.y * 4 + (threadIdx.x >> 6);
    float inv_sm = 1.0f / sm[0];
    float x0 = x[m * 4 + 0] * (1.0f / 255.0f);
    float x1 = x[m * 4 + 1] * (1.0f / 255.0f);
    float x2 = x[m * 4 + 2] * inv_sm;
    float x3 = x[m * 4 + 3];
    float acc = fb[o];
    acc = fmaf(x0, fw[o * 4 + 0], acc);
    acc = fmaf(x1, fw[o * 4 + 1], acc);
    acc = fmaf(x2, fw[o * 4 + 2], acc);
    acc = fmaf(x3, fw[o * 4 + 3], acc);
    u[m * DMV + o] = f2bf(acc);
}

// ---------------------------------------------------------------------------
// bf16 MFMA GEMM: Y[m,n] = act(sum_k X[m,k]*W[n,k] (+bias))
// X, W already bf16. BK=32, 256 threads = 4 waves.
// BM/BN in {64,128}: wave tiling 64x64 / 32x64 / 32x32.
// A/B frag: lane holds 8 contig k at row=lane&15, k0=(lane>>4)*8 [m89/m91]
// C/D: row = (lane>>4)*4 + reg, col = lane&15                    [m89/m91]
// ACT: 0=none 1=tanh 3=elu.  TOUT: unsigned short (bf16) or float.
// ---------------------------------------------------------------------------
template<int ACT, int BM, int BN, typename TOUT>
__global__ __launch_bounds__(256) void gemm_mfma_kernel(
    const unsigned short* __restrict__ X, const unsigned short* __restrict__ W,
    const float* __restrict__ bias, TOUT* __restrict__ Y,
    int N, int K, long ldx, long ldy)
{
    constexpr int WMT = (BM == 128 && BN == 128) ? 4 : 2;
    constexpr int WNT = (BM == 64 && BN == 64) ? 2 : 4;
    __shared__ unsigned short Xs[BM * 40];   // 32 k + 8 pad per row
    __shared__ unsigned short Ws[BN * 40];

    int tid = threadIdx.x;
    int wave = tid >> 6, lane = tid & 63;
    int quad = lane >> 4, l15 = lane & 15;
    int wmbase, wnbase;
    if (BM == 128 && BN == 128)      { wmbase = (wave & 1) * 64; wnbase = (wave >> 1) * 64; }
    else if (BM == 128 && BN == 64)  { wmbase = wave * 32;       wnbase = 0; }
    else                             { wmbase = (wave & 1) * 32; wnbase = (wave >> 1) * 32; }
    long m0 = (long)blockIdx.y * BM;
    int n0 = blockIdx.x * BN;

    floatx4 acc[WMT][WNT];
    #pragma unroll
    for (int i = 0; i < WMT; i++)
        #pragma unroll
        for (int j = 0; j < WNT; j++)
            acc[i][j] = (floatx4){0.f, 0.f, 0.f, 0.f};

    int sr = tid >> 2;            // 0..63
    int sk = (tid & 3) * 8;       // 0,8,16,24

    for (int k0 = 0; k0 < K; k0 += 32) {
        #pragma unroll
        for (int r0 = 0; r0 < BM; r0 += 64) {
            int r = r0 + sr;
            *(ushort8*)&Xs[r * 40 + sk] =
                *(const ushort8*)(X + (m0 + r) * ldx + k0 + sk);
        }
        #pragma unroll
        for (int r0 = 0; r0 < BN; r0 += 64) {
            int r = r0 + sr;
            int n = n0 + r;
            ushort8 v = (ushort8)(0);
            if (n < N) v = *(const ushort8*)(W + (long)n * K + k0 + sk);
            *(ushort8*)&Ws[r * 40 + sk] = v;
        }
        __syncthreads();
        short8 af[WMT], bfr[WNT];
        #pragma unroll
        for (int i = 0; i < WMT; i++)
            af[i] = *(short8*)&Xs[(wmbase + i * 16 + l15) * 40 + quad * 8];
        #pragma unroll
        for (int j = 0; j < WNT; j++)
            bfr[j] = *(short8*)&Ws[(wnbase + j * 16 + l15) * 40 + quad * 8];
        #pragma unroll
        for (int i = 0; i < WMT; i++)
            #pragma unroll
            for (int j = 0; j < WNT; j++)
                acc[i][j] = __builtin_amdgcn_mfma_f32_16x16x32_bf16(
                    af[i], bfr[j], acc[i][j], 0, 0, 0);
        __syncthreads();
    }

    #pragma unroll
    for (int i = 0; i < WMT; i++) {
        long mb = m0 + wmbase + i * 16 + quad * 4;
        #pragma unroll
        for (int j = 0; j < WNT; j++) {
            int n = n0 + wnbase + j * 16 + l15;
            if (n >= N) continue;
            float bv = bias ? bias[n] : 0.f;
            #pragma unroll
            for (int r = 0; r < 4; r++) {
                float v = acc[i][j][r] + bv;
                if (ACT == 1) v = tanhf(v);
                else if (ACT == 3) v = (v > 0.f) ? v : expm1f(v);
                if constexpr (sizeof(TOUT) == 2)
                    Y[(mb + r) * ldy + n] = f2bf(v);
                else
                    Y[(mb + r) * ldy + n] = v;
            }
        }
    }
}

// ---------------------------------------------------------------------------
// small fp32 GEMM for the head (M=8): Y = act(X@W^T + bias)
// TIN: bf16 (ushort) or float X. ACT: 0=none 2=relu
// ---------------------------------------------------------------------------
template<int ACT, typename TIN>
__global__ __launch_bounds__(256) void gemm_kernel(
    const TIN* __restrict__ X, const float* __restrict__ W,
    const float* __restrict__ bias, float* __restrict__ Y,
    int M, int N, int K, long ldx, long ldy)
{
    __shared__ __align__(16) float Xs[16][68];
    __shared__ __align__(16) float Ws[16][68];
    int tid = threadIdx.x;
    int m0 = blockIdx.y * 64;
    int n0 = blockIdx.x * 64;
    int tn = tid & 15, tm = tid >> 4;

    float acc[4][4] = {};

    int lr  = tid >> 2;
    int lk4 = (tid & 3) * 4;

    for (int k0 = 0; k0 < K; k0 += 16) {
        {
            int m = m0 + lr;
            float tmp[4] = {0.f, 0.f, 0.f, 0.f};
            if (m < M) {
                for (int j = 0; j < 4; j++) {
                    if (k0 + lk4 + j < K) {
                        if constexpr (sizeof(TIN) == 2)
                            tmp[j] = bf2f(X[(long)m * ldx + k0 + lk4 + j]);
                        else
                            tmp[j] = X[(long)m * ldx + k0 + lk4 + j];
                    }
                }
            }
            Xs[lk4 + 0][lr] = tmp[0]; Xs[lk4 + 1][lr] = tmp[1];
            Xs[lk4 + 2][lr] = tmp[2]; Xs[lk4 + 3][lr] = tmp[3];
        }
        {
            int n = n0 + lr;
            float tmp[4] = {0.f, 0.f, 0.f, 0.f};
            if (n < N) {
                for (int j = 0; j < 4; j++)
                    if (k0 + lk4 + j < K) tmp[j] = W[(long)n * K + k0 + lk4 + j];
            }
            Ws[lk4 + 0][lr] = tmp[0]; Ws[lk4 + 1][lr] = tmp[1];
            Ws[lk4 + 2][lr] = tmp[2]; Ws[lk4 + 3][lr] = tmp[3];
        }
        __syncthreads();
        #pragma unroll
        for (int k = 0; k < 16; k++) {
            float xr[4], wr[4];
            *(float4*)xr = *(const float4*)&Xs[k][tm * 4];
            *(float4*)wr = *(const float4*)&Ws[k][tn * 4];
            #pragma unroll
            for (int i = 0; i < 4; i++)
                #pragma unroll
                for (int j = 0; j < 4; j++)
                    acc[i][j] = fmaf(xr[i], wr[j], acc[i][j]);
        }
        __syncthreads();
    }

    #pragma unroll
    for (int i = 0; i < 4; i++) {
        int m = m0 + tm * 4 + i;
        if (m >= M) break;
        #pragma unroll
        for (int j = 0; j < 4; j++) {
            int n = n0 + tn * 4 + j;
            if (n >= N) continue;
            float v = acc[i][j];
            if (bias) v += bias[n];
            if (ACT == 2) v = fmaxf(v, 0.f);
            Y[(long)m * ldy + n] = v;
        }
    }
}

// ---------------------------------------------------------------------------
// depthwise causal conv (k=8) + bias + silu, sliding-window registers, bf16.
// 32 tokens per thread. grid (DIV/256, LSZ/32, Bc)
// ---------------------------------------------------------------------------
#define TCONV 32
__global__ __launch_bounds__(256) void conv_kernel(
    const unsigned short* __restrict__ xz, const float* __restrict__ cw,
    const float* __restrict__ cb, unsigned short* __restrict__ xc)
{
    int d = blockIdx.x * 256 + threadIdx.x;
    int lb = blockIdx.z;
    int l0 = blockIdx.y * TCONV;
    long base = (long)lb * LSZ + l0;

    float w[8];
    #pragma unroll
    for (int k = 0; k < 8; k++) w[k] = cw[d * 8 + k];
    float bc = cb[d];

    float win[8];
    #pragma unroll
    for (int i = 0; i < 7; i++) {
        int l = l0 - 7 + i;
        win[i] = (l >= 0) ? bf2f(xz[(base - 7 + i) * 2560 + d]) : 0.f;
    }
    #pragma unroll
    for (int s = 0; s < TCONV; s++) {
        win[7] = bf2f(xz[(base + s) * 2560 + d]);
        float acc = bc;
        #pragma unroll
        for (int k = 0; k < 8; k++) acc = fmaf(win[k], w[k], acc);
        float sv = acc / (1.0f + __expf(-acc));
        xc[(base + s) * DIV + d] = f2bf(sv);
        #pragma unroll
        for (int k = 0; k < 7; k++) win[k] = win[k + 1];
    }
}

// power ladder: pw[n] = p^(n+1), depth-4
__device__ inline void pow_ladder(float p, float* pw) {
    pw[0] = p;
    pw[1] = pw[0] * pw[0];
    pw[2] = pw[1] * pw[0];
    pw[3] = pw[1] * pw[1];
    pw[4] = pw[3] * pw[0];
    pw[5] = pw[3] * pw[1];
    pw[6] = pw[3] * pw[2];
    pw[7] = pw[3] * pw[3];
    #pragma unroll
    for (int k = 8; k < 16; k++) pw[k] = pw[7] * pw[k - 8];
}

// ---------------------------------------------------------------------------
// Chunked Mamba scan, phase 1: per-chunk local scan (h0=0).
// Exploits a[n] = (n+1)*a[0] (A_log = log(1..16)) -> 1 exp + 15 mul per step,
// with generic-exp fallback if the geometric check fails.
// ---------------------------------------------------------------------------
__global__ __launch_bounds__(256) void scan_local_kernel(
    const unsigned short* __restrict__ xc, unsigned short* xz,
    const float* __restrict__ dbc,
    const float* __restrict__ dtw, const float* __restrict__ dtb,
    const float* __restrict__ A_log, const float* __restrict__ Dp,
    float* __restrict__ hfin, float* __restrict__ sumd)
{
    __shared__ float S[CLEN * 52];
    int lb = blockIdx.z;
    int ch = blockIdx.y;
    int d = blockIdx.x * 256 + threadIdx.x;
    int tid = threadIdx.x;

    float dtwr[DTR];
    #pragma unroll
    for (int j = 0; j < DTR; j++) dtwr[j] = dtw[d * DTR + j];
    float dtb_d = dtb[d];

    float a[NST], h[NST];
    #pragma unroll
    for (int n = 0; n < NST; n++) {
        a[n] = -__expf(A_log[d * NST + n]);
        h[n] = 0.f;
    }
    float a0 = a[0];
    bool geo = true;
    #pragma unroll
    for (int n = 1; n < NST; n++)
        geo = geo && (fabsf(a[n] - (float)(n + 1) * a0) <= 1e-4f * (float)(n + 1));
    float Dd = Dp[d];

    long tok0 = (long)lb * LSZ + ch * CLEN;
    const float* src = dbc + tok0 * 52;
    for (int i = tid; i < CLEN * 52; i += 256) S[i] = src[i];
    __syncthreads();

    float sd = 0.f;
    for (int l = 0; l < CLEN; l++) {
        long m = tok0 + l;
        const float* row = &S[l * 52];
        float draw = dtb_d;
        #pragma unroll
        for (int j = 0; j < DTR; j++) draw = fmaf(dtwr[j], row[j], draw);
        float delta = (draw > 20.f) ? draw : log1pf(__expf(draw));
        sd += delta;
        float xv = bf2f(xc[m * DIV + d]);
        float db = delta * xv;
        float y = 0.f;
        if (geo) {
            float pw[NST];
            pow_ladder(__expf(delta * a0), pw);
            #pragma unroll
            for (int n = 0; n < NST; n++) {
                h[n] = fmaf(pw[n], h[n], db * row[20 + n]);
                y = fmaf(h[n], row[36 + n], y);
            }
        } else {
            #pragma unroll
            for (int n = 0; n < NST; n++) {
                float dA = __expf(delta * a[n]);
                h[n] = fmaf(dA, h[n], db * row[20 + n]);
                y = fmaf(h[n], row[36 + n], y);
            }
        }
        y = fmaf(xv, Dd, y);
        xz[m * 2560 + d] = f2bf(y);   // y_local (silu(z) applied in fix phase)
    }

    long cidx = ((long)lb * NCHUNK + ch) * DIV + d;
    #pragma unroll
    for (int n = 0; n < NST; n++) hfin[cidx * NST + n] = h[n];
    sumd[cidx] = sd;
}

// ---------------------------------------------------------------------------
// Phase 2: sequential prefix over chunks. One thread per (b, d, n).
// ---------------------------------------------------------------------------
__global__ __launch_bounds__(256) void scan_prefix_kernel(
    float* __restrict__ hfin, const float* __restrict__ sumd,
    const float* __restrict__ A_log, int Bc)
{
    long g = (long)blockIdx.x * 256 + threadIdx.x;
    int n = (int)(g & (NST - 1));
    long t = g >> 4;
    int d = (int)(t % DIV);
    int lb = (int)(t / DIV);
    if (lb >= Bc) return;

    float a = -__expf(A_log[d * NST + n]);
    float s = 0.f;
    for (int c = 0; c < NCHUNK; c++) {
        long cidx = ((long)lb * NCHUNK + c) * DIV + d;
        float hl = hfin[cidx * NST + n];
        float P = __expf(a * sumd[cidx]);
        hfin[cidx * NST + n] = s;
        s = fmaf(P, s, hl);
    }
}

// ---------------------------------------------------------------------------
// Phase 3: add cross-chunk contribution (running product) and apply silu(z).
// ---------------------------------------------------------------------------
__global__ __launch_bounds__(256) void scan_fix_kernel(
    unsigned short* xz, const float* __restrict__ dbc,
    const float* __restrict__ dtw, const float* __restrict__ dtb,
    const float* __restrict__ A_log, const float* __restrict__ hfin)
{
    __shared__ float S[CLEN * 52];
    int lb = blockIdx.z;
    int ch = blockIdx.y;
    int d = blockIdx.x * 256 + threadIdx.x;
    int tid = threadIdx.x;

    float dtwr[DTR];
    #pragma unroll
    for (int j = 0; j < DTR; j++) dtwr[j] = dtw[d * DTR + j];
    float dtb_d = dtb[d];

    float a[NST], hr[NST];
    #pragma unroll
    for (int n = 0; n < NST; n++) a[n] = -__expf(A_log[d * NST + n]);
    float a0 = a[0];
    bool geo = true;
    #pragma unroll
    for (int n = 1; n < NST; n++)
        geo = geo && (fabsf(a[n] - (float)(n + 1) * a0) <= 1e-4f * (float)(n + 1));

    long cidx = ((long)lb * NCHUNK + ch) * DIV + d;
    #pragma unroll
    for (int n = 0; n < NST; n += 4)
        *(float4*)&hr[n] = *(const float4*)&hfin[cidx * NST + n];

    long tok0 = (long)lb * LSZ + ch * CLEN;
    const float* src = dbc + tok0 * 52;
    for (int i = tid; i < CLEN * 52; i += 256) S[i] = src[i];
    __syncthreads();

    for (int l = 0; l < CLEN; l++) {
        long m = tok0 + l;
        const float* row = &S[l * 52];
        float draw = dtb_d;
        #pragma unroll
        for (int j = 0; j < DTR; j++) draw = fmaf(dtwr[j], row[j], draw);
        float delta = (draw > 20.f) ? draw : log1pf(__expf(draw));
        float fix = 0.f;
        if (geo) {
            float pw[NST];
            pow_ladder(__expf(delta * a0), pw);
            #pragma unroll
            for (int n = 0; n < NST; n++) {
                hr[n] *= pw[n];
                fix = fmaf(hr[n], row[36 + n], fix);
            }
        } else {
            #pragma unroll
            for (int n = 0; n < NST; n++) {
                hr[n] *= __expf(delta * a[n]);
                fix = fmaf(hr[n], row[36 + n], fix);
            }
        }
        float y = bf2f(xz[m * 2560 + d]) + fix;
        float zv = bf2f(xz[m * 2560 + 1280 + d]);
        float sz = zv / (1.0f + __expf(-zv));
        xz[m * 2560 + d] = f2bf(y * sz);
    }
}

// ---------------------------------------------------------------------------
__global__ void final_kernel(const float* __restrict__ h3, const float* __restrict__ sm,
                             float* __restrict__ out, int Bc) {
    int t = threadIdx.x;
    if (t < Bc) {
        float scale = sm[0] / 8.624618986159398f;   // 1 + ln(2048)
        out[t] = fmaxf(h3[t] * scale, 0.f);
    }
}

// ---------------------------------------------------------------------------
extern "C" void kernel_launch(void* const* d_in, const int* in_sizes, int n_in,
                              void* d_out, int out_size, void* d_ws, size_t ws_size,
                              hipStream_t stream) {
    const float* x        = (const float*)d_in[0];
    const float* fc_w     = (const float*)d_in[1];
    const float* fc_b     = (const float*)d_in[2];
    const float* lin_w    = (const float*)d_in[3];
    const float* lin_b    = (const float*)d_in[4];
    const float* inproj_w = (const float*)d_in[5];
    const float* conv_w   = (const float*)d_in[6];
    const float* conv_b   = (const float*)d_in[7];
    const float* xproj_w  = (const float*)d_in[8];
    const float* dtproj_w = (const float*)d_in[9];
    const float* dtproj_b = (const float*)d_in[10];
    const float* A_log    = (const float*)d_in[11];
    const float* Dp       = (const float*)d_in[12];
    const float* outproj_w= (const float*)d_in[13];
    const float* s1_w1    = (const float*)d_in[14];
    const float* s1_b1    = (const float*)d_in[15];
    const float* s1_w2    = (const float*)d_in[16];
    const float* s1_b2    = (const float*)d_in[17];
    const float* s1_w3    = (const float*)d_in[18];
    const float* s1_b3    = (const float*)d_in[19];

    // bf16 weight sizes (all 4 layers, contiguous)
    const long NLIN = (long)NBLKV * DMV * DMV;        // 409600
    const long NINP = (long)NBLKV * 2 * DIV * DMV;    // 3276800
    const long NXP  = (long)NBLKV * (DTR + 2 * NST) * DIV;  // 266240
    const long NOUT = (long)NBLKV * DMV * DIV;        // 1638400

    // ---- workspace sizing ----
    const long FIXED = 64 + 4096 * 4 + 4096 * 4 + 64 +
                       (NLIN + NINP + NXP + NOUT) * 2 + 256;
    const long PER_BATCH = (long)LSZ * (DMV + DMV + 2 * DIV + DIV) * 2  // bf16 acts
                         + (long)LSZ * 52 * 4                            // dbc
                         + (long)NCHUNK * DIV * NST * 4                  // hfin
                         + (long)NCHUNK * DIV * 4;                       // sumd
    int Bc = 8;
    while (Bc > 1 && (size_t)(FIXED + (long)Bc * PER_BATCH) > ws_size)
        Bc >>= 1;
    int nchunk_b = BSZ / Bc;
    long Mc = (long)Bc * LSZ;

    char* p = (char*)d_ws;
    float* sm = (float*)p;           p += 64;
    float* h1 = (float*)p;           p += 4096 * 4;
    float* h2 = (float*)p;           p += 4096 * 4;
    float* h3 = (float*)p;           p += 64;
    unsigned short* wlin = (unsigned short*)p; p += NLIN * 2;
    unsigned short* winp = (unsigned short*)p; p += NINP * 2;
    unsigned short* wxp  = (unsigned short*)p; p += NXP * 2;
    unsigned short* wout = (unsigned short*)p; p += NOUT * 2;
    unsigned short* u  = (unsigned short*)p;   p += Mc * DMV * 2;
    unsigned short* t  = (unsigned short*)p;   p += Mc * DMV * 2;
    unsigned short* xz = (unsigned short*)p;   p += Mc * 2560 * 2;
    unsigned short* xc = (unsigned short*)p;   p += Mc * DIV * 2;
    float* dbc  = (float*)p;         p += Mc * 52 * 4;
    float* hfin = (float*)p;         p += (long)Bc * NCHUNK * DIV * NST * 4;
    float* sumd = (float*)p;

    // one-time (per launch) weight conversion
    convert_kernel<<<(unsigned)((NLIN / 4 + 255) / 256), 256, 0, stream>>>(lin_w, wlin, NLIN / 4);
    convert_kernel<<<(unsigned)((NINP / 4 + 255) / 256), 256, 0, stream>>>(inproj_w, winp, NINP / 4);
    convert_kernel<<<(unsigned)((NXP / 4 + 255) / 256), 256, 0, stream>>>(xproj_w, wxp, NXP / 4);
    convert_kernel<<<(unsigned)((NOUT / 4 + 255) / 256), 256, 0, stream>>>(outproj_w, wout, NOUT / 4);

    init_sm_kernel<<<1, 64, 0, stream>>>(sm);
    reduce_max_kernel<<<32, 256, 0, stream>>>(x, sm);

    for (int c = 0; c < nchunk_b; c++) {
        int b0 = c * Bc;
        fc_kernel<<<dim3(5, (unsigned)(Mc / 4)), 256, 0, stream>>>(
            x + (long)b0 * LSZ * 4, fc_w, fc_b, sm, u);

        for (int i = 0; i < NBLKV; i++) {
            const float* lb  = lin_b    + (long)i * DMV;
            const float* cw  = conv_w   + (long)i * DIV * DCV;
            const float* cb  = conv_b   + (long)i * DIV;
            const float* dpw = dtproj_w + (long)i * DIV * DTR;
            const float* dpb = dtproj_b + (long)i * DIV;
            const float* al  = A_log    + (long)i * DIV * NST;
            const float* dd  = Dp       + (long)i * DIV;

            // lin + tanh: (Mc x320)@(320x320)^T -> t (bf16)
            gemm_mfma_kernel<1, 128, 64, unsigned short>
                <<<dim3(5, (unsigned)(Mc / 128)), 256, 0, stream>>>(
                u, wlin + (long)i * DMV * DMV, lb, t, DMV, DMV, DMV, DMV);
            // inproj: (Mc x320)@(2560x320)^T -> xz (bf16)
            gemm_mfma_kernel<0, 128, 128, unsigned short>
                <<<dim3(20, (unsigned)(Mc / 128)), 256, 0, stream>>>(
                t, winp + (long)i * 2 * DIV * DMV, nullptr, xz, 2 * DIV, DMV, DMV, 2 * DIV);
            // conv + silu (sliding window, bf16)
            conv_kernel<<<dim3(5, LSZ / TCONV, Bc), 256, 0, stream>>>(xz, cw, cb, xc);
            // xproj: (Mc x1280)@(52x1280)^T -> dbc (fp32)
            gemm_mfma_kernel<0, 64, 64, float>
                <<<dim3(1, (unsigned)(Mc / 64)), 256, 0, stream>>>(
                xc, wxp + (long)i * (DTR + 2 * NST) * DIV, nullptr, dbc,
                DTR + 2 * NST, DIV, DIV, DTR + 2 * NST);
            // chunked scan
            scan_local_kernel<<<dim3(5, NCHUNK, Bc), 256, 0, stream>>>(
                xc, xz, dbc, dpw, dpb, al, dd, hfin, sumd);
            scan_prefix_kernel<<<dim3(Bc * 80), 256, 0, stream>>>(hfin, sumd, al, Bc);
            scan_fix_kernel<<<dim3(5, NCHUNK, Bc), 256, 0, stream>>>(
                xz, dbc, dpw, dpb, al, hfin);
            // outproj + elu: (Mc x1280)@(320x1280)^T -> u (bf16)
            gemm_mfma_kernel<3, 128, 64, unsigned short>
                <<<dim3(5, (unsigned)(Mc / 128)), 256, 0, stream>>>(
                xz, wout + (long)i * DMV * DIV, nullptr, u, DMV, DIV, 2 * DIV, DMV);
        }

        // head on last token of each batch in chunk
        gemm_kernel<2, unsigned short><<<dim3(8, 1), 256, 0, stream>>>(
            u + (long)(LSZ - 1) * DMV, s1_w1, s1_b1, h1,
            Bc, 512, DMV, (long)LSZ * DMV, 512);
        gemm_kernel<2, float><<<dim3(8, 1), 256, 0, stream>>>(h1, s1_w2, s1_b2, h2,
            Bc, 512, 512, 512, 512);
        gemm_kernel<0, float><<<dim3(1, 1), 256, 0, stream>>>(h2, s1_w3, s1_b3, h3,
            Bc, 1, 512, 512, 1);
        final_kernel<<<1, 64, 0, stream>>>(h3, sm, (float*)d_out + b0, Bc);
    }
}

// Round 6
// 1713.846 us; speedup vs baseline: 9.9303x; 1.1679x over previous
//
#include <hip/hip_runtime.h>
#include <math.h>

// Problem constants
#define BSZ 8
#define LSZ 2048
#define DMV 320
#define DIV 1280
#define NST 16
#define DCV 8
#define DTR 20
#define NBLKV 4
#define MTOT (BSZ*LSZ)   // 16384
#define NCHUNK 32
#define CLEN 64          // NCHUNK*CLEN == LSZ
#define DBLD 56          // dbc leading dim (bf16), 16B-aligned rows

typedef __attribute__((ext_vector_type(8))) short short8;
typedef __attribute__((ext_vector_type(8))) unsigned short ushort8;
typedef __attribute__((ext_vector_type(4))) float floatx4;

__device__ inline unsigned short f2bf(float f) {
    union { float f; unsigned u; } v; v.f = f;
    unsigned r = v.u + 0x7FFFu + ((v.u >> 16) & 1u);
    return (unsigned short)(r >> 16);
}
__device__ inline float bf2f(unsigned short b) {
    union { unsigned u; float f; } v; v.u = ((unsigned)b) << 16;
    return v.f;
}

// ---------------------------------------------------------------------------
// fp32 -> bf16 weight conversion (grid-stride, n % 4 == 0)
// ---------------------------------------------------------------------------
__global__ __launch_bounds__(256) void convert_kernel(
    const float* __restrict__ src, unsigned short* __restrict__ dst, long n4) {
    long i = (long)blockIdx.x * 256 + threadIdx.x;
    if (i >= n4) return;
    float4 v = *(const float4*)(src + i * 4);
    unsigned short o[4] = {f2bf(v.x), f2bf(v.y), f2bf(v.z), f2bf(v.w)};
    *(unsigned long long*)(dst + i * 4) = *(unsigned long long*)o;
}

// dtproj_w (1280x20) -> bf16 padded to 1280x32 (zeros in cols 20..31)
__global__ __launch_bounds__(256) void convert_dtw_kernel(
    const float* __restrict__ src, unsigned short* __restrict__ dst) {
    int i = blockIdx.x * 256 + threadIdx.x;   // over 1280*32
    if (i >= DIV * 32) return;
    int d = i >> 5, j = i & 31;
    dst[i] = (j < DTR) ? f2bf(src[d * DTR + j]) : (unsigned short)0;
}

// ---------------------------------------------------------------------------
// start_max reduction (x[:,:,2] >= 0, so int-compare atomicMax is valid)
// ---------------------------------------------------------------------------
__global__ void init_sm_kernel(float* sm) {
    if (threadIdx.x == 0) ((int*)sm)[0] = 0;
}

__global__ void reduce_max_kernel(const float* __restrict__ x, float* sm) {
    int idx = blockIdx.x * blockDim.x + threadIdx.x;
    float v = 0.f;
    for (int i = idx; i < MTOT; i += gridDim.x * blockDim.x)
        v = fmaxf(v, x[i * 4 + 2]);
    #pragma unroll
    for (int off = 32; off > 0; off >>= 1)
        v = fmaxf(v, __shfl_xor(v, off, 64));
    if ((threadIdx.x & 63) == 0)
        atomicMax((int*)sm, __float_as_int(v));
}

// ---------------------------------------------------------------------------
// input normalize + fc (K=4) -> bf16 u
// ---------------------------------------------------------------------------
__global__ __launch_bounds__(256) void fc_kernel(
    const float* __restrict__ x, const float* __restrict__ fw,
    const float* __restrict__ fb, const float* __restrict__ sm,
    unsigned short* __restrict__ u) {
    int o = blockIdx.x * 64 + (threadIdx.x & 63);
    long m = (long)blockIdx.y * 4 + (threadIdx.x >> 6);
    float inv_sm = 1.0f / sm[0];
    float x0 = x[m * 4 + 0] * (1.0f / 255.0f);
    float x1 = x[m * 4 + 1] * (1.0f / 255.0f);
    float x2 = x[m * 4 + 2] * inv_sm;
    float x3 = x[m * 4 + 3];
    float acc = fb[o];
    acc = fmaf(x0, fw[o * 4 + 0], acc);
    acc = fmaf(x1, fw[o * 4 + 1], acc);
    acc = fmaf(x2, fw[o * 4 + 2], acc);
    acc = fmaf(x3, fw[o * 4 + 3], acc);
    u[m * DMV + o] = f2bf(acc);
}

// ---------------------------------------------------------------------------
// bf16 MFMA GEMM: Y[m,n] = act(sum_k X[m,k]*W[n,k] (+bias))
// BK=KB (32 or 64), 256 threads = 4 waves, BM/BN in {64,128}.
// A/B frag: lane holds 8 contig k at row=lane&15, k0=(lane>>4)*8 [m89/m91]
// C/D: row = (lane>>4)*4 + reg, col = lane&15                    [m89/m91]
// ACT: 0=none 1=tanh 3=elu 4=softplus
// ---------------------------------------------------------------------------
template<int ACT, int BM, int BN, int KB, typename TOUT>
__global__ __launch_bounds__(256) void gemm_mfma_kernel(
    const unsigned short* __restrict__ X, const unsigned short* __restrict__ W,
    const float* __restrict__ bias, TOUT* __restrict__ Y,
    int N, int K, long ldx, long ldy)
{
    constexpr int WMT = (BM == 128 && BN == 128) ? 4 : 2;
    constexpr int WNT = (BM == 64 && BN == 64) ? 2 : 4;
    constexpr int LDT = KB + 8;
    __shared__ unsigned short Xs[BM * LDT];
    __shared__ unsigned short Ws[BN * LDT];

    int tid = threadIdx.x;
    int wave = tid >> 6, lane = tid & 63;
    int quad = lane >> 4, l15 = lane & 15;
    int wmbase, wnbase;
    if (BM == 128 && BN == 128)      { wmbase = (wave & 1) * 64; wnbase = (wave >> 1) * 64; }
    else if (BM == 128 && BN == 64)  { wmbase = wave * 32;       wnbase = 0; }
    else                             { wmbase = (wave & 1) * 32; wnbase = (wave >> 1) * 32; }
    long m0 = (long)blockIdx.y * BM;
    int n0 = blockIdx.x * BN;

    floatx4 acc[WMT][WNT];
    #pragma unroll
    for (int i = 0; i < WMT; i++)
        #pragma unroll
        for (int j = 0; j < WNT; j++)
            acc[i][j] = (floatx4){0.f, 0.f, 0.f, 0.f};

    constexpr int CPR = KB / 8;          // 16B chunks per row

    for (int k0 = 0; k0 < K; k0 += KB) {
        #pragma unroll
        for (int idx = 0; idx < BM * CPR / 256; idx++) {
            int g = idx * 256 + tid;
            int r = g / CPR, c = g % CPR;
            *(ushort8*)&Xs[r * LDT + c * 8] =
                *(const ushort8*)(X + (m0 + r) * ldx + k0 + c * 8);
        }
        #pragma unroll
        for (int idx = 0; idx < BN * CPR / 256; idx++) {
            int g = idx * 256 + tid;
            int r = g / CPR, c = g % CPR;
            int n = n0 + r;
            ushort8 v = (ushort8)(0);
            if (n < N) v = *(const ushort8*)(W + (long)n * K + k0 + c * 8);
            *(ushort8*)&Ws[r * LDT + c * 8] = v;
        }
        __syncthreads();
        #pragma unroll
        for (int kk = 0; kk < KB; kk += 32) {
            short8 af[WMT], bfr[WNT];
            #pragma unroll
            for (int i = 0; i < WMT; i++)
                af[i] = *(short8*)&Xs[(wmbase + i * 16 + l15) * LDT + kk + quad * 8];
            #pragma unroll
            for (int j = 0; j < WNT; j++)
                bfr[j] = *(short8*)&Ws[(wnbase + j * 16 + l15) * LDT + kk + quad * 8];
            #pragma unroll
            for (int i = 0; i < WMT; i++)
                #pragma unroll
                for (int j = 0; j < WNT; j++)
                    acc[i][j] = __builtin_amdgcn_mfma_f32_16x16x32_bf16(
                        af[i], bfr[j], acc[i][j], 0, 0, 0);
        }
        __syncthreads();
    }

    #pragma unroll
    for (int i = 0; i < WMT; i++) {
        long mb = m0 + wmbase + i * 16 + quad * 4;
        #pragma unroll
        for (int j = 0; j < WNT; j++) {
            int n = n0 + wnbase + j * 16 + l15;
            if (n >= N) continue;
            float bv = bias ? bias[n] : 0.f;
            #pragma unroll
            for (int r = 0; r < 4; r++) {
                float v = acc[i][j][r] + bv;
                if (ACT == 1) v = tanhf(v);
                else if (ACT == 3) v = (v > 0.f) ? v : expm1f(v);
                else if (ACT == 4) v = (v > 20.f) ? v : log1pf(__expf(v));
                if constexpr (sizeof(TOUT) == 2)
                    Y[(mb + r) * ldy + n] = f2bf(v);
                else
                    Y[(mb + r) * ldy + n] = v;
            }
        }
    }
}

// ---------------------------------------------------------------------------
// small fp32 GEMM for the head (M=8)
// ---------------------------------------------------------------------------
template<int ACT, typename TIN>
__global__ __launch_bounds__(256) void gemm_kernel(
    const TIN* __restrict__ X, const float* __restrict__ W,
    const float* __restrict__ bias, float* __restrict__ Y,
    int M, int N, int K, long ldx, long ldy)
{
    __shared__ __align__(16) float Xs[16][68];
    __shared__ __align__(16) float Ws[16][68];
    int tid = threadIdx.x;
    int m0 = blockIdx.y * 64;
    int n0 = blockIdx.x * 64;
    int tn = tid & 15, tm = tid >> 4;

    float acc[4][4] = {};
    int lr  = tid >> 2;
    int lk4 = (tid & 3) * 4;

    for (int k0 = 0; k0 < K; k0 += 16) {
        {
            int m = m0 + lr;
            float tmp[4] = {0.f, 0.f, 0.f, 0.f};
            if (m < M) {
                for (int j = 0; j < 4; j++) {
                    if (k0 + lk4 + j < K) {
                        if constexpr (sizeof(TIN) == 2)
                            tmp[j] = bf2f(X[(long)m * ldx + k0 + lk4 + j]);
                        else
                            tmp[j] = X[(long)m * ldx + k0 + lk4 + j];
                    }
                }
            }
            Xs[lk4 + 0][lr] = tmp[0]; Xs[lk4 + 1][lr] = tmp[1];
            Xs[lk4 + 2][lr] = tmp[2]; Xs[lk4 + 3][lr] = tmp[3];
        }
        {
            int n = n0 + lr;
            float tmp[4] = {0.f, 0.f, 0.f, 0.f};
            if (n < N) {
                for (int j = 0; j < 4; j++)
                    if (k0 + lk4 + j < K) tmp[j] = W[(long)n * K + k0 + lk4 + j];
            }
            Ws[lk4 + 0][lr] = tmp[0]; Ws[lk4 + 1][lr] = tmp[1];
            Ws[lk4 + 2][lr] = tmp[2]; Ws[lk4 + 3][lr] = tmp[3];
        }
        __syncthreads();
        #pragma unroll
        for (int k = 0; k < 16; k++) {
            float xr[4], wr[4];
            *(float4*)xr = *(const float4*)&Xs[k][tm * 4];
            *(float4*)wr = *(const float4*)&Ws[k][tn * 4];
            #pragma unroll
            for (int i = 0; i < 4; i++)
                #pragma unroll
                for (int j = 0; j < 4; j++)
                    acc[i][j] = fmaf(xr[i], wr[j], acc[i][j]);
        }
        __syncthreads();
    }

    #pragma unroll
    for (int i = 0; i < 4; i++) {
        int m = m0 + tm * 4 + i;
        if (m >= M) break;
        #pragma unroll
        for (int j = 0; j < 4; j++) {
            int n = n0 + tn * 4 + j;
            if (n >= N) continue;
            float v = acc[i][j];
            if (bias) v += bias[n];
            if (ACT == 2) v = fmaxf(v, 0.f);
            Y[(long)m * ldy + n] = v;
        }
    }
}

// ---------------------------------------------------------------------------
// depthwise causal conv (k=8) + bias + silu, sliding-window, bf16
// ---------------------------------------------------------------------------
#define TCONV 32
__global__ __launch_bounds__(256) void conv_kernel(
    const unsigned short* __restrict__ xz, const float* __restrict__ cw,
    const float* __restrict__ cb, unsigned short* __restrict__ xc)
{
    int d = blockIdx.x * 256 + threadIdx.x;
    int lb = blockIdx.z;
    int l0 = blockIdx.y * TCONV;
    long base = (long)lb * LSZ + l0;

    float w[8];
    #pragma unroll
    for (int k = 0; k < 8; k++) w[k] = cw[d * 8 + k];
    float bc = cb[d];

    float win[8];
    #pragma unroll
    for (int i = 0; i < 7; i++) {
        int l = l0 - 7 + i;
        win[i] = (l >= 0) ? bf2f(xz[(base - 7 + i) * 2560 + d]) : 0.f;
    }
    #pragma unroll
    for (int s = 0; s < TCONV; s++) {
        win[7] = bf2f(xz[(base + s) * 2560 + d]);
        float acc = bc;
        #pragma unroll
        for (int k = 0; k < 8; k++) acc = fmaf(win[k], w[k], acc);
        float sv = acc / (1.0f + __expf(-acc));
        xc[(base + s) * DIV + d] = f2bf(sv);
        #pragma unroll
        for (int k = 0; k < 7; k++) win[k] = win[k + 1];
    }
}

// power ladder: pw[n] = p^(n+1)
__device__ inline void pow_ladder(float p, float* pw) {
    pw[0] = p;
    pw[1] = pw[0] * pw[0];
    pw[2] = pw[1] * pw[0];
    pw[3] = pw[1] * pw[1];
    pw[4] = pw[3] * pw[0];
    pw[5] = pw[3] * pw[1];
    pw[6] = pw[3] * pw[2];
    pw[7] = pw[3] * pw[3];
    #pragma unroll
    for (int k = 8; k < 16; k++) pw[k] = pw[7] * pw[k - 8];
}

// ---------------------------------------------------------------------------
// Chunked scan phase 1: per-chunk local scan (h0=0). delta precomputed.
// B/C staged fp32 in LDS. Wave-uniform geo-path selection via __all.
// ---------------------------------------------------------------------------
__global__ __launch_bounds__(256) void scan_local_kernel(
    const unsigned short* __restrict__ xc, unsigned short* xz,
    const unsigned short* __restrict__ dbc, const float* __restrict__ delta,
    const float* __restrict__ A_log, const float* __restrict__ Dp,
    float* __restrict__ hfin, float* __restrict__ sumd)
{
    __shared__ float S[CLEN * 32];
    int lb = blockIdx.z;
    int ch = blockIdx.y;
    int d = blockIdx.x * 256 + threadIdx.x;
    int tid = threadIdx.x;

    float a[NST], h[NST];
    #pragma unroll
    for (int n = 0; n < NST; n++) {
        a[n] = -__expf(A_log[d * NST + n]);
        h[n] = 0.f;
    }
    float a0 = a[0];
    bool geo = true;
    #pragma unroll
    for (int n = 1; n < NST; n++)
        geo = geo && (fabsf(a[n] - (float)(n + 1) * a0) <= 1e-4f * (float)(n + 1));
    float Dd = Dp[d];

    long tok0 = (long)lb * LSZ + ch * CLEN;
    for (int i = tid; i < CLEN * 32; i += 256) {
        int r = i >> 5, c = i & 31;
        S[i] = bf2f(dbc[(tok0 + r) * DBLD + 20 + c]);
    }
    __syncthreads();

    float sd = 0.f;
    if (__all(geo)) {
        for (int l = 0; l < CLEN; l++) {
            long m = tok0 + l;
            const float* row = &S[l * 32];
            float dl = delta[m * DIV + d];
            sd += dl;
            float xv = bf2f(xc[m * DIV + d]);
            float db = dl * xv;
            float pw[NST];
            pow_ladder(__expf(dl * a0), pw);
            float y = 0.f;
            #pragma unroll
            for (int n = 0; n < NST; n++) {
                h[n] = fmaf(pw[n], h[n], db * row[n]);
                y = fmaf(h[n], row[16 + n], y);
            }
            y = fmaf(xv, Dd, y);
            xz[m * 2560 + d] = f2bf(y);
        }
    } else {
        for (int l = 0; l < CLEN; l++) {
            long m = tok0 + l;
            const float* row = &S[l * 32];
            float dl = delta[m * DIV + d];
            sd += dl;
            float xv = bf2f(xc[m * DIV + d]);
            float db = dl * xv;
            float y = 0.f;
            #pragma unroll
            for (int n = 0; n < NST; n++) {
                float dA = __expf(dl * a[n]);
                h[n] = fmaf(dA, h[n], db * row[n]);
                y = fmaf(h[n], row[16 + n], y);
            }
            y = fmaf(xv, Dd, y);
            xz[m * 2560 + d] = f2bf(y);
        }
    }

    long cidx = ((long)lb * NCHUNK + ch) * DIV + d;
    #pragma unroll
    for (int n = 0; n < NST; n++) hfin[cidx * NST + n] = h[n];
    sumd[cidx] = sd;
}

// ---------------------------------------------------------------------------
// Phase 2: sequential prefix over chunks. One thread per (b, d, n).
// ---------------------------------------------------------------------------
__global__ __launch_bounds__(256) void scan_prefix_kernel(
    float* __restrict__ hfin, const float* __restrict__ sumd,
    const float* __restrict__ A_log, int Bc)
{
    long g = (long)blockIdx.x * 256 + threadIdx.x;
    int n = (int)(g & (NST - 1));
    long t = g >> 4;
    int d = (int)(t % DIV);
    int lb = (int)(t / DIV);
    if (lb >= Bc) return;

    float a = -__expf(A_log[d * NST + n]);
    float s = 0.f;
    for (int c = 0; c < NCHUNK; c++) {
        long cidx = ((long)lb * NCHUNK + c) * DIV + d;
        float hl = hfin[cidx * NST + n];
        float P = __expf(a * sumd[cidx]);
        hfin[cidx * NST + n] = s;
        s = fmaf(P, s, hl);
    }
}

// ---------------------------------------------------------------------------
// Phase 3: cross-chunk contribution (running product) + silu(z).
// ---------------------------------------------------------------------------
__global__ __launch_bounds__(256) void scan_fix_kernel(
    unsigned short* xz, const unsigned short* __restrict__ dbc,
    const float* __restrict__ delta,
    const float* __restrict__ A_log, const float* __restrict__ hfin)
{
    __shared__ float S[CLEN * 16];
    int lb = blockIdx.z;
    int ch = blockIdx.y;
    int d = blockIdx.x * 256 + threadIdx.x;
    int tid = threadIdx.x;

    float a[NST], hr[NST];
    #pragma unroll
    for (int n = 0; n < NST; n++) a[n] = -__expf(A_log[d * NST + n]);
    float a0 = a[0];
    bool geo = true;
    #pragma unroll
    for (int n = 1; n < NST; n++)
        geo = geo && (fabsf(a[n] - (float)(n + 1) * a0) <= 1e-4f * (float)(n + 1));

    long cidx = ((long)lb * NCHUNK + ch) * DIV + d;
    #pragma unroll
    for (int n = 0; n < NST; n += 4)
        *(float4*)&hr[n] = *(const float4*)&hfin[cidx * NST + n];

    long tok0 = (long)lb * LSZ + ch * CLEN;
    // stage only C (cols 36..51)
    for (int i = tid; i < CLEN * 16; i += 256) {
        int r = i >> 4, c = i & 15;
        S[i] = bf2f(dbc[(tok0 + r) * DBLD + 36 + c]);
    }
    __syncthreads();

    if (__all(geo)) {
        for (int l = 0; l < CLEN; l++) {
            long m = tok0 + l;
            const float* row = &S[l * 16];
            float dl = delta[m * DIV + d];
            float pw[NST];
            pow_ladder(__expf(dl * a0), pw);
            float fix = 0.f;
            #pragma unroll
            for (int n = 0; n < NST; n++) {
                hr[n] *= pw[n];
                fix = fmaf(hr[n], row[n], fix);
            }
            float y = bf2f(xz[m * 2560 + d]) + fix;
            float zv = bf2f(xz[m * 2560 + 1280 + d]);
            float sz = zv / (1.0f + __expf(-zv));
            xz[m * 2560 + d] = f2bf(y * sz);
        }
    } else {
        for (int l = 0; l < CLEN; l++) {
            long m = tok0 + l;
            const float* row = &S[l * 16];
            float dl = delta[m * DIV + d];
            float fix = 0.f;
            #pragma unroll
            for (int n = 0; n < NST; n++) {
                hr[n] *= __expf(dl * a[n]);
                fix = fmaf(hr[n], row[n], fix);
            }
            float y = bf2f(xz[m * 2560 + d]) + fix;
            float zv = bf2f(xz[m * 2560 + 1280 + d]);
            float sz = zv / (1.0f + __expf(-zv));
            xz[m * 2560 + d] = f2bf(y * sz);
        }
    }
}

// ---------------------------------------------------------------------------
__global__ void final_kernel(const float* __restrict__ h3, const float* __restrict__ sm,
                             float* __restrict__ out, int Bc) {
    int t = threadIdx.x;
    if (t < Bc) {
        float scale = sm[0] / 8.624618986159398f;   // 1 + ln(2048)
        out[t] = fmaxf(h3[t] * scale, 0.f);
    }
}

// ---------------------------------------------------------------------------
extern "C" void kernel_launch(void* const* d_in, const int* in_sizes, int n_in,
                              void* d_out, int out_size, void* d_ws, size_t ws_size,
                              hipStream_t stream) {
    const float* x        = (const float*)d_in[0];
    const float* fc_w     = (const float*)d_in[1];
    const float* fc_b     = (const float*)d_in[2];
    const float* lin_w    = (const float*)d_in[3];
    const float* lin_b    = (const float*)d_in[4];
    const float* inproj_w = (const float*)d_in[5];
    const float* conv_w   = (const float*)d_in[6];
    const float* conv_b   = (const float*)d_in[7];
    const float* xproj_w  = (const float*)d_in[8];
    const float* dtproj_w = (const float*)d_in[9];
    const float* dtproj_b = (const float*)d_in[10];
    const float* A_log    = (const float*)d_in[11];
    const float* Dp       = (const float*)d_in[12];
    const float* outproj_w= (const float*)d_in[13];
    const float* s1_w1    = (const float*)d_in[14];
    const float* s1_b1    = (const float*)d_in[15];
    const float* s1_w2    = (const float*)d_in[16];
    const float* s1_b2    = (const float*)d_in[17];
    const float* s1_w3    = (const float*)d_in[18];
    const float* s1_b3    = (const float*)d_in[19];

    const long NLIN = (long)NBLKV * DMV * DMV;
    const long NINP = (long)NBLKV * 2 * DIV * DMV;
    const long NXP  = (long)NBLKV * (DTR + 2 * NST) * DIV;
    const long NOUT = (long)NBLKV * DMV * DIV;
    const long NDTW = (long)NBLKV * DIV * 32;

    // ---- workspace sizing ----
    const long FIXED = 64 + 4096 * 4 + 4096 * 4 + 64 +
                       (NLIN + NINP + NXP + NOUT + NDTW) * 2 + 256;
    const long PER_BATCH = (long)LSZ * (DMV + DMV + 2 * DIV + DIV) * 2   // bf16 acts
                         + (long)LSZ * DBLD * 2                          // dbc bf16
                         + (long)LSZ * DIV * 4                           // delta fp32
                         + (long)NCHUNK * DIV * NST * 4                  // hfin
                         + (long)NCHUNK * DIV * 4;                       // sumd
    int Bc = 8;
    while (Bc > 1 && (size_t)(FIXED + (long)Bc * PER_BATCH) > ws_size)
        Bc >>= 1;
    int nchunk_b = BSZ / Bc;
    long Mc = (long)Bc * LSZ;

    char* p = (char*)d_ws;
    float* sm = (float*)p;           p += 64;
    float* h1 = (float*)p;           p += 4096 * 4;
    float* h2 = (float*)p;           p += 4096 * 4;
    float* h3 = (float*)p;           p += 64;
    unsigned short* wlin = (unsigned short*)p; p += NLIN * 2;
    unsigned short* winp = (unsigned short*)p; p += NINP * 2;
    unsigned short* wxp  = (unsigned short*)p; p += NXP * 2;
    unsigned short* wout = (unsigned short*)p; p += NOUT * 2;
    unsigned short* wdt  = (unsigned short*)p; p += NDTW * 2;
    unsigned short* u  = (unsigned short*)p;   p += Mc * DMV * 2;
    unsigned short* t  = (unsigned short*)p;   p += Mc * DMV * 2;
    unsigned short* xz = (unsigned short*)p;   p += Mc * 2560 * 2;
    unsigned short* xc = (unsigned short*)p;   p += Mc * DIV * 2;
    unsigned short* dbc = (unsigned short*)p;  p += Mc * DBLD * 2;
    float* delta = (float*)p;        p += Mc * DIV * 4;
    float* hfin = (float*)p;         p += (long)Bc * NCHUNK * DIV * NST * 4;
    float* sumd = (float*)p;

    // one-time (per launch) weight conversion
    convert_kernel<<<(unsigned)((NLIN / 4 + 255) / 256), 256, 0, stream>>>(lin_w, wlin, NLIN / 4);
    convert_kernel<<<(unsigned)((NINP / 4 + 255) / 256), 256, 0, stream>>>(inproj_w, winp, NINP / 4);
    convert_kernel<<<(unsigned)((NXP / 4 + 255) / 256), 256, 0, stream>>>(xproj_w, wxp, NXP / 4);
    convert_kernel<<<(unsigned)((NOUT / 4 + 255) / 256), 256, 0, stream>>>(outproj_w, wout, NOUT / 4);
    for (int i = 0; i < NBLKV; i++)
        convert_dtw_kernel<<<(DIV * 32 + 255) / 256, 256, 0, stream>>>(
            dtproj_w + (long)i * DIV * DTR, wdt + (long)i * DIV * 32);

    init_sm_kernel<<<1, 64, 0, stream>>>(sm);
    reduce_max_kernel<<<32, 256, 0, stream>>>(x, sm);

    for (int c = 0; c < nchunk_b; c++) {
        int b0 = c * Bc;
        fc_kernel<<<dim3(5, (unsigned)(Mc / 4)), 256, 0, stream>>>(
            x + (long)b0 * LSZ * 4, fc_w, fc_b, sm, u);

        for (int i = 0; i < NBLKV; i++) {
            const float* lb  = lin_b    + (long)i * DMV;
            const float* cw  = conv_w   + (long)i * DIV * DCV;
            const float* cb  = conv_b   + (long)i * DIV;
            const float* dpb = dtproj_b + (long)i * DIV;
            const float* al  = A_log    + (long)i * DIV * NST;
            const float* dd  = Dp       + (long)i * DIV;

            // lin + tanh: (Mc x320)@(320x320)^T -> t (bf16)
            gemm_mfma_kernel<1, 128, 64, 64, unsigned short>
                <<<dim3(5, (unsigned)(Mc / 128)), 256, 0, stream>>>(
                u, wlin + (long)i * DMV * DMV, lb, t, DMV, DMV, DMV, DMV);
            // inproj: (Mc x320)@(2560x320)^T -> xz (bf16)
            gemm_mfma_kernel<0, 128, 128, 64, unsigned short>
                <<<dim3(20, (unsigned)(Mc / 128)), 256, 0, stream>>>(
                t, winp + (long)i * 2 * DIV * DMV, nullptr, xz, 2 * DIV, DMV, DMV, 2 * DIV);
            // conv + silu (sliding window, bf16)
            conv_kernel<<<dim3(5, LSZ / TCONV, Bc), 256, 0, stream>>>(xz, cw, cb, xc);
            // xproj: (Mc x1280)@(52x1280)^T -> dbc (bf16, ld 56)
            gemm_mfma_kernel<0, 64, 64, 64, unsigned short>
                <<<dim3(1, (unsigned)(Mc / 64)), 256, 0, stream>>>(
                xc, wxp + (long)i * (DTR + 2 * NST) * DIV, nullptr, dbc,
                DTR + 2 * NST, DIV, DIV, DBLD);
            // delta = softplus(dbc[:, :20] @ dtw^T + b): K padded to 32
            gemm_mfma_kernel<4, 128, 128, 32, float>
                <<<dim3(10, (unsigned)(Mc / 128)), 256, 0, stream>>>(
                dbc, wdt + (long)i * DIV * 32, dpb, delta, DIV, 32, DBLD, DIV);
            // chunked scan
            scan_local_kernel<<<dim3(5, NCHUNK, Bc), 256, 0, stream>>>(
                xc, xz, dbc, delta, al, dd, hfin, sumd);
            scan_prefix_kernel<<<dim3(Bc * 80), 256, 0, stream>>>(hfin, sumd, al, Bc);
            scan_fix_kernel<<<dim3(5, NCHUNK, Bc), 256, 0, stream>>>(
                xz, dbc, delta, al, hfin);
            // outproj + elu: (Mc x1280)@(320x1280)^T -> u (bf16)
            gemm_mfma_kernel<3, 128, 64, 64, unsigned short>
                <<<dim3(5, (unsigned)(Mc / 128)), 256, 0, stream>>>(
                xz, wout + (long)i * DMV * DIV, nullptr, u, DMV, DIV, 2 * DIV, DMV);
        }

        // head on last token of each batch in chunk
        gemm_kernel<2, unsigned short><<<dim3(8, 1), 256, 0, stream>>>(
            u + (long)(LSZ - 1) * DMV, s1_w1, s1_b1, h1,
            Bc, 512, DMV, (long)LSZ * DMV, 512);
        gemm_kernel<2, float><<<dim3(8, 1), 256, 0, stream>>>(h1, s1_w2, s1_b2, h2,
            Bc, 512, 512, 512, 512);
        gemm_kernel<0, float><<<dim3(1, 1), 256, 0, stream>>>(h2, s1_w3, s1_b3, h3,
            Bc, 1, 512, 512, 1);
        final_kernel<<<1, 64, 0, stream>>>(h3, sm, (float*)d_out + b0, Bc);
    }
}

// Round 7
// 1493.254 us; speedup vs baseline: 11.3973x; 1.1477x over previous
//
#include <hip/hip_runtime.h>
#include <math.h>

// Problem constants
#define BSZ 8
#define LSZ 2048
#define DMV 320
#define DIV 1280
#define NST 16
#define DCV 8
#define DTR 20
#define NBLKV 4
#define MTOT (BSZ*LSZ)   // 16384
#define NCHUNK 32
#define CLEN 64          // NCHUNK*CLEN == LSZ
#define DBLD 56          // dbc leading dim (bf16), 16B-aligned rows

typedef __attribute__((ext_vector_type(8))) short short8;
typedef __attribute__((ext_vector_type(8))) unsigned short ushort8;
typedef __attribute__((ext_vector_type(4))) float floatx4;

__device__ inline unsigned short f2bf(float f) {
    union { float f; unsigned u; } v; v.f = f;
    unsigned r = v.u + 0x7FFFu + ((v.u >> 16) & 1u);
    return (unsigned short)(r >> 16);
}
__device__ inline float bf2f(unsigned short b) {
    union { unsigned u; float f; } v; v.u = ((unsigned)b) << 16;
    return v.f;
}

// ---------------------------------------------------------------------------
// fp32 -> bf16 weight conversion (grid-stride, n % 4 == 0)
// ---------------------------------------------------------------------------
__global__ __launch_bounds__(256) void convert_kernel(
    const float* __restrict__ src, unsigned short* __restrict__ dst, long n4) {
    long i = (long)blockIdx.x * 256 + threadIdx.x;
    if (i >= n4) return;
    float4 v = *(const float4*)(src + i * 4);
    unsigned short o[4] = {f2bf(v.x), f2bf(v.y), f2bf(v.z), f2bf(v.w)};
    *(unsigned long long*)(dst + i * 4) = *(unsigned long long*)o;
}

// dtproj_w (1280x20) -> bf16 padded to 1280x32 (zeros in cols 20..31)
__global__ __launch_bounds__(256) void convert_dtw_kernel(
    const float* __restrict__ src, unsigned short* __restrict__ dst) {
    int i = blockIdx.x * 256 + threadIdx.x;   // over 1280*32
    if (i >= DIV * 32) return;
    int d = i >> 5, j = i & 31;
    dst[i] = (j < DTR) ? f2bf(src[d * DTR + j]) : (unsigned short)0;
}

// ---------------------------------------------------------------------------
// start_max reduction (x[:,:,2] >= 0, so int-compare atomicMax is valid)
// ---------------------------------------------------------------------------
__global__ void init_sm_kernel(float* sm) {
    if (threadIdx.x == 0) ((int*)sm)[0] = 0;
}

__global__ void reduce_max_kernel(const float* __restrict__ x, float* sm) {
    int idx = blockIdx.x * blockDim.x + threadIdx.x;
    float v = 0.f;
    for (int i = idx; i < MTOT; i += gridDim.x * blockDim.x)
        v = fmaxf(v, x[i * 4 + 2]);
    #pragma unroll
    for (int off = 32; off > 0; off >>= 1)
        v = fmaxf(v, __shfl_xor(v, off, 64));
    if ((threadIdx.x & 63) == 0)
        atomicMax((int*)sm, __float_as_int(v));
}

// ---------------------------------------------------------------------------
// input normalize + fc (K=4) -> bf16 u
// ---------------------------------------------------------------------------
__global__ __launch_bounds__(256) void fc_kernel(
    const float* __restrict__ x, const float* __restrict__ fw,
    const float* __restrict__ fb, const float* __restrict__ sm,
    unsigned short* __restrict__ u) {
    int o = blockIdx.x * 64 + (threadIdx.x & 63);
    long m = (long)blockIdx.y * 4 + (threadIdx.x >> 6);
    float inv_sm = 1.0f / sm[0];
    float x0 = x[m * 4 + 0] * (1.0f / 255.0f);
    float x1 = x[m * 4 + 1] * (1.0f / 255.0f);
    float x2 = x[m * 4 + 2] * inv_sm;
    float x3 = x[m * 4 + 3];
    float acc = fb[o];
    acc = fmaf(x0, fw[o * 4 + 0], acc);
    acc = fmaf(x1, fw[o * 4 + 1], acc);
    acc = fmaf(x2, fw[o * 4 + 2], acc);
    acc = fmaf(x3, fw[o * 4 + 3], acc);
    u[m * DMV + o] = f2bf(acc);
}

// ---------------------------------------------------------------------------
// bf16 MFMA GEMM: Y[m,n] = act(sum_k X[m,k]*W[n,k] (+bias))
// BK=KB (32 or 64), 256 threads = 4 waves, BM/BN in {64,128}.
// A/B frag: lane holds 8 contig k at row=lane&15, k0=(lane>>4)*8 [m89/m91]
// C/D: row = (lane>>4)*4 + reg, col = lane&15                    [m89/m91]
// ACT: 0=none 1=tanh 3=elu 4=softplus(fast)
// ---------------------------------------------------------------------------
template<int ACT, int BM, int BN, int KB, typename TOUT>
__global__ __launch_bounds__(256) void gemm_mfma_kernel(
    const unsigned short* __restrict__ X, const unsigned short* __restrict__ W,
    const float* __restrict__ bias, TOUT* __restrict__ Y,
    int N, int K, long ldx, long ldy)
{
    constexpr int WMT = (BM == 128 && BN == 128) ? 4 : 2;
    constexpr int WNT = (BM == 64 && BN == 64) ? 2 : 4;
    constexpr int LDT = KB + 8;
    __shared__ unsigned short Xs[BM * LDT];
    __shared__ unsigned short Ws[BN * LDT];

    int tid = threadIdx.x;
    int wave = tid >> 6, lane = tid & 63;
    int quad = lane >> 4, l15 = lane & 15;
    int wmbase, wnbase;
    if (BM == 128 && BN == 128)      { wmbase = (wave & 1) * 64; wnbase = (wave >> 1) * 64; }
    else if (BM == 128 && BN == 64)  { wmbase = wave * 32;       wnbase = 0; }
    else                             { wmbase = (wave & 1) * 32; wnbase = (wave >> 1) * 32; }
    long m0 = (long)blockIdx.y * BM;
    int n0 = blockIdx.x * BN;

    floatx4 acc[WMT][WNT];
    #pragma unroll
    for (int i = 0; i < WMT; i++)
        #pragma unroll
        for (int j = 0; j < WNT; j++)
            acc[i][j] = (floatx4){0.f, 0.f, 0.f, 0.f};

    constexpr int CPR = KB / 8;          // 16B chunks per row

    for (int k0 = 0; k0 < K; k0 += KB) {
        #pragma unroll
        for (int idx = 0; idx < BM * CPR / 256; idx++) {
            int g = idx * 256 + tid;
            int r = g / CPR, c = g % CPR;
            *(ushort8*)&Xs[r * LDT + c * 8] =
                *(const ushort8*)(X + (m0 + r) * ldx + k0 + c * 8);
        }
        #pragma unroll
        for (int idx = 0; idx < BN * CPR / 256; idx++) {
            int g = idx * 256 + tid;
            int r = g / CPR, c = g % CPR;
            int n = n0 + r;
            ushort8 v = (ushort8)(0);
            if (n < N) v = *(const ushort8*)(W + (long)n * K + k0 + c * 8);
            *(ushort8*)&Ws[r * LDT + c * 8] = v;
        }
        __syncthreads();
        #pragma unroll
        for (int kk = 0; kk < KB; kk += 32) {
            short8 af[WMT], bfr[WNT];
            #pragma unroll
            for (int i = 0; i < WMT; i++)
                af[i] = *(short8*)&Xs[(wmbase + i * 16 + l15) * LDT + kk + quad * 8];
            #pragma unroll
            for (int j = 0; j < WNT; j++)
                bfr[j] = *(short8*)&Ws[(wnbase + j * 16 + l15) * LDT + kk + quad * 8];
            #pragma unroll
            for (int i = 0; i < WMT; i++)
                #pragma unroll
                for (int j = 0; j < WNT; j++)
                    acc[i][j] = __builtin_amdgcn_mfma_f32_16x16x32_bf16(
                        af[i], bfr[j], acc[i][j], 0, 0, 0);
        }
        __syncthreads();
    }

    #pragma unroll
    for (int i = 0; i < WMT; i++) {
        long mb = m0 + wmbase + i * 16 + quad * 4;
        #pragma unroll
        for (int j = 0; j < WNT; j++) {
            int n = n0 + wnbase + j * 16 + l15;
            if (n >= N) continue;
            float bv = bias ? bias[n] : 0.f;
            #pragma unroll
            for (int r = 0; r < 4; r++) {
                float v = acc[i][j][r] + bv;
                if (ACT == 1) v = tanhf(v);
                else if (ACT == 3) v = (v > 0.f) ? v : expm1f(v);
                else if (ACT == 4) v = (v > 20.f) ? v : __logf(1.0f + __expf(v));
                if constexpr (sizeof(TOUT) == 2)
                    Y[(mb + r) * ldy + n] = f2bf(v);
                else
                    Y[(mb + r) * ldy + n] = v;
            }
        }
    }
}

// ---------------------------------------------------------------------------
// fused head: h1=relu(u@w1^T+b1), h2=relu(h1@w2^T+b2), h3=h2@w3^T+b3,
// out = relu(h3 * start_max/(1+ln(2048))). One block per batch, 512 threads.
// ---------------------------------------------------------------------------
__global__ __launch_bounds__(512) void head_kernel(
    const unsigned short* __restrict__ u,
    const float* __restrict__ w1, const float* __restrict__ b1,
    const float* __restrict__ w2, const float* __restrict__ b2,
    const float* __restrict__ w3, const float* __restrict__ b3,
    const float* __restrict__ sm, float* __restrict__ out)
{
    __shared__ float h1s[512];
    __shared__ float h2s[512];
    __shared__ float red[8];
    int b = blockIdx.x;
    int n = threadIdx.x;
    const unsigned short* xr = u + ((long)b * LSZ + (LSZ - 1)) * DMV;
    float acc = b1[n];
    for (int k = 0; k < DMV; k++) acc = fmaf(bf2f(xr[k]), w1[n * DMV + k], acc);
    h1s[n] = fmaxf(acc, 0.f);
    __syncthreads();
    acc = b2[n];
    for (int k = 0; k < 512; k++) acc = fmaf(h1s[k], w2[n * 512 + k], acc);
    h2s[n] = fmaxf(acc, 0.f);
    __syncthreads();
    float part = h2s[n] * w3[n];
    #pragma unroll
    for (int off = 32; off > 0; off >>= 1) part += __shfl_xor(part, off, 64);
    if ((n & 63) == 0) red[n >> 6] = part;
    __syncthreads();
    if (n == 0) {
        float s = b3[0];
        #pragma unroll
        for (int w = 0; w < 8; w++) s += red[w];
        float scale = sm[0] / 8.624618986159398f;   // 1 + ln(2048)
        out[b] = fmaxf(s * scale, 0.f);
    }
}

// ---------------------------------------------------------------------------
// depthwise causal conv (k=8) + bias + silu, sliding-window, bf16
// ---------------------------------------------------------------------------
#define TCONV 32
__global__ __launch_bounds__(256) void conv_kernel(
    const unsigned short* __restrict__ xz, const float* __restrict__ cw,
    const float* __restrict__ cb, unsigned short* __restrict__ xc)
{
    int d = blockIdx.x * 256 + threadIdx.x;
    int lb = blockIdx.z;
    int l0 = blockIdx.y * TCONV;
    long base = (long)lb * LSZ + l0;

    float w[8];
    #pragma unroll
    for (int k = 0; k < 8; k++) w[k] = cw[d * 8 + k];
    float bc = cb[d];

    float win[8];
    #pragma unroll
    for (int i = 0; i < 7; i++) {
        int l = l0 - 7 + i;
        win[i] = (l >= 0) ? bf2f(xz[(base - 7 + i) * 2560 + d]) : 0.f;
    }
    #pragma unroll
    for (int s = 0; s < TCONV; s++) {
        win[7] = bf2f(xz[(base + s) * 2560 + d]);
        float acc = bc;
        #pragma unroll
        for (int k = 0; k < 8; k++) acc = fmaf(win[k], w[k], acc);
        float sv = acc / (1.0f + __expf(-acc));
        xc[(base + s) * DIV + d] = f2bf(sv);
        #pragma unroll
        for (int k = 0; k < 7; k++) win[k] = win[k + 1];
    }
}

// power ladder: pw[n] = p^(n+1)
__device__ inline void pow_ladder(float p, float* pw) {
    pw[0] = p;
    pw[1] = pw[0] * pw[0];
    pw[2] = pw[1] * pw[0];
    pw[3] = pw[1] * pw[1];
    pw[4] = pw[3] * pw[0];
    pw[5] = pw[3] * pw[1];
    pw[6] = pw[3] * pw[2];
    pw[7] = pw[3] * pw[3];
    #pragma unroll
    for (int k = 8; k < 16; k++) pw[k] = pw[7] * pw[k - 8];
}

// ---------------------------------------------------------------------------
// Chunked scan phase 1: per-chunk local scan (h0=0). delta precomputed (bf16).
// B/C staged fp32 in LDS. Wave-uniform geo-path selection via __all.
// ---------------------------------------------------------------------------
__global__ __launch_bounds__(256) void scan_local_kernel(
    const unsigned short* __restrict__ xc, unsigned short* xz,
    const unsigned short* __restrict__ dbc, const unsigned short* __restrict__ delta,
    const float* __restrict__ A_log, const float* __restrict__ Dp,
    float* __restrict__ hfin, float* __restrict__ sumd)
{
    __shared__ float S[CLEN * 32];
    int lb = blockIdx.z;
    int ch = blockIdx.y;
    int d = blockIdx.x * 256 + threadIdx.x;
    int tid = threadIdx.x;

    float a[NST], h[NST];
    #pragma unroll
    for (int n = 0; n < NST; n++) {
        a[n] = -__expf(A_log[d * NST + n]);
        h[n] = 0.f;
    }
    float a0 = a[0];
    bool geo = true;
    #pragma unroll
    for (int n = 1; n < NST; n++)
        geo = geo && (fabsf(a[n] - (float)(n + 1) * a0) <= 1e-4f * (float)(n + 1));
    float Dd = Dp[d];

    long tok0 = (long)lb * LSZ + ch * CLEN;
    for (int i = tid; i < CLEN * 32; i += 256) {
        int r = i >> 5, c = i & 31;
        S[i] = bf2f(dbc[(tok0 + r) * DBLD + 20 + c]);
    }
    __syncthreads();

    float sd = 0.f;
    if (__all(geo)) {
        for (int l = 0; l < CLEN; l++) {
            long m = tok0 + l;
            const float* row = &S[l * 32];
            float dl = bf2f(delta[m * DIV + d]);
            sd += dl;
            float xv = bf2f(xc[m * DIV + d]);
            float db = dl * xv;
            float pw[NST];
            pow_ladder(__expf(dl * a0), pw);
            float y = 0.f;
            #pragma unroll
            for (int n = 0; n < NST; n++) {
                h[n] = fmaf(pw[n], h[n], db * row[n]);
                y = fmaf(h[n], row[16 + n], y);
            }
            y = fmaf(xv, Dd, y);
            xz[m * 2560 + d] = f2bf(y);
        }
    } else {
        for (int l = 0; l < CLEN; l++) {
            long m = tok0 + l;
            const float* row = &S[l * 32];
            float dl = bf2f(delta[m * DIV + d]);
            sd += dl;
            float xv = bf2f(xc[m * DIV + d]);
            float db = dl * xv;
            float y = 0.f;
            #pragma unroll
            for (int n = 0; n < NST; n++) {
                float dA = __expf(dl * a[n]);
                h[n] = fmaf(dA, h[n], db * row[n]);
                y = fmaf(h[n], row[16 + n], y);
            }
            y = fmaf(xv, Dd, y);
            xz[m * 2560 + d] = f2bf(y);
        }
    }

    long cidx = ((long)lb * NCHUNK + ch) * DIV + d;
    #pragma unroll
    for (int n = 0; n < NST; n++) hfin[cidx * NST + n] = h[n];
    sumd[cidx] = sd;
}

// ---------------------------------------------------------------------------
// Phase 2: sequential prefix over chunks. One thread per (b, d, n).
// ---------------------------------------------------------------------------
__global__ __launch_bounds__(256) void scan_prefix_kernel(
    float* __restrict__ hfin, const float* __restrict__ sumd,
    const float* __restrict__ A_log, int Bc)
{
    long g = (long)blockIdx.x * 256 + threadIdx.x;
    int n = (int)(g & (NST - 1));
    long t = g >> 4;
    int d = (int)(t % DIV);
    int lb = (int)(t / DIV);
    if (lb >= Bc) return;

    float a = -__expf(A_log[d * NST + n]);
    float s = 0.f;
    for (int c = 0; c < NCHUNK; c++) {
        long cidx = ((long)lb * NCHUNK + c) * DIV + d;
        float hl = hfin[cidx * NST + n];
        float P = __expf(a * sumd[cidx]);
        hfin[cidx * NST + n] = s;
        s = fmaf(P, s, hl);
    }
}

// ---------------------------------------------------------------------------
// Phase 3: cross-chunk contribution (running product) + silu(z).
// ---------------------------------------------------------------------------
__global__ __launch_bounds__(256) void scan_fix_kernel(
    unsigned short* xz, const unsigned short* __restrict__ dbc,
    const unsigned short* __restrict__ delta,
    const float* __restrict__ A_log, const float* __restrict__ hfin)
{
    __shared__ float S[CLEN * 16];
    int lb = blockIdx.z;
    int ch = blockIdx.y;
    int d = blockIdx.x * 256 + threadIdx.x;
    int tid = threadIdx.x;

    float a[NST], hr[NST];
    #pragma unroll
    for (int n = 0; n < NST; n++) a[n] = -__expf(A_log[d * NST + n]);
    float a0 = a[0];
    bool geo = true;
    #pragma unroll
    for (int n = 1; n < NST; n++)
        geo = geo && (fabsf(a[n] - (float)(n + 1) * a0) <= 1e-4f * (float)(n + 1));

    long cidx = ((long)lb * NCHUNK + ch) * DIV + d;
    #pragma unroll
    for (int n = 0; n < NST; n += 4)
        *(float4*)&hr[n] = *(const float4*)&hfin[cidx * NST + n];

    long tok0 = (long)lb * LSZ + ch * CLEN;
    // stage only C (cols 36..51)
    for (int i = tid; i < CLEN * 16; i += 256) {
        int r = i >> 4, c = i & 15;
        S[i] = bf2f(dbc[(tok0 + r) * DBLD + 36 + c]);
    }
    __syncthreads();

    if (__all(geo)) {
        for (int l = 0; l < CLEN; l++) {
            long m = tok0 + l;
            const float* row = &S[l * 16];
            float dl = bf2f(delta[m * DIV + d]);
            float pw[NST];
            pow_ladder(__expf(dl * a0), pw);
            float fix = 0.f;
            #pragma unroll
            for (int n = 0; n < NST; n++) {
                hr[n] *= pw[n];
                fix = fmaf(hr[n], row[n], fix);
            }
            float y = bf2f(xz[m * 2560 + d]) + fix;
            float zv = bf2f(xz[m * 2560 + 1280 + d]);
            float sz = zv / (1.0f + __expf(-zv));
            xz[m * 2560 + d] = f2bf(y * sz);
        }
    } else {
        for (int l = 0; l < CLEN; l++) {
            long m = tok0 + l;
            const float* row = &S[l * 16];
            float dl = bf2f(delta[m * DIV + d]);
            float fix = 0.f;
            #pragma unroll
            for (int n = 0; n < NST; n++) {
                hr[n] *= __expf(dl * a[n]);
                fix = fmaf(hr[n], row[n], fix);
            }
            float y = bf2f(xz[m * 2560 + d]) + fix;
            float zv = bf2f(xz[m * 2560 + 1280 + d]);
            float sz = zv / (1.0f + __expf(-zv));
            xz[m * 2560 + d] = f2bf(y * sz);
        }
    }
}

// ---------------------------------------------------------------------------
extern "C" void kernel_launch(void* const* d_in, const int* in_sizes, int n_in,
                              void* d_out, int out_size, void* d_ws, size_t ws_size,
                              hipStream_t stream) {
    const float* x        = (const float*)d_in[0];
    const float* fc_w     = (const float*)d_in[1];
    const float* fc_b     = (const float*)d_in[2];
    const float* lin_w    = (const float*)d_in[3];
    const float* lin_b    = (const float*)d_in[4];
    const float* inproj_w = (const float*)d_in[5];
    const float* conv_w   = (const float*)d_in[6];
    const float* conv_b   = (const float*)d_in[7];
    const float* xproj_w  = (const float*)d_in[8];
    const float* dtproj_w = (const float*)d_in[9];
    const float* dtproj_b = (const float*)d_in[10];
    const float* A_log    = (const float*)d_in[11];
    const float* Dp       = (const float*)d_in[12];
    const float* outproj_w= (const float*)d_in[13];
    const float* s1_w1    = (const float*)d_in[14];
    const float* s1_b1    = (const float*)d_in[15];
    const float* s1_w2    = (const float*)d_in[16];
    const float* s1_b2    = (const float*)d_in[17];
    const float* s1_w3    = (const float*)d_in[18];
    const float* s1_b3    = (const float*)d_in[19];

    const long NLIN = (long)NBLKV * DMV * DMV;
    const long NINP = (long)NBLKV * 2 * DIV * DMV;
    const long NXP  = (long)NBLKV * (DTR + 2 * NST) * DIV;
    const long NOUT = (long)NBLKV * DMV * DIV;
    const long NDTW = (long)NBLKV * DIV * 32;

    // ---- workspace sizing ----
    const long FIXED = 64 + 4096 * 4 + 4096 * 4 + 64 +
                       (NLIN + NINP + NXP + NOUT + NDTW) * 2 + 256;
    const long PER_BATCH = (long)LSZ * (DMV + DMV + 2 * DIV + DIV) * 2   // bf16 acts
                         + (long)LSZ * DBLD * 2                          // dbc bf16
                         + (long)LSZ * DIV * 2                           // delta bf16
                         + (long)NCHUNK * DIV * NST * 4                  // hfin
                         + (long)NCHUNK * DIV * 4;                       // sumd
    int Bc = 8;
    while (Bc > 1 && (size_t)(FIXED + (long)Bc * PER_BATCH) > ws_size)
        Bc >>= 1;
    int nchunk_b = BSZ / Bc;
    long Mc = (long)Bc * LSZ;

    char* p = (char*)d_ws;
    float* sm = (float*)p;           p += 64;
    p += 4096 * 4;                   // (unused, kept for layout stability)
    p += 4096 * 4;
    p += 64;
    unsigned short* wlin = (unsigned short*)p; p += NLIN * 2;
    unsigned short* winp = (unsigned short*)p; p += NINP * 2;
    unsigned short* wxp  = (unsigned short*)p; p += NXP * 2;
    unsigned short* wout = (unsigned short*)p; p += NOUT * 2;
    unsigned short* wdt  = (unsigned short*)p; p += NDTW * 2;
    unsigned short* u  = (unsigned short*)p;   p += Mc * DMV * 2;
    unsigned short* t  = (unsigned short*)p;   p += Mc * DMV * 2;
    unsigned short* xz = (unsigned short*)p;   p += Mc * 2560 * 2;
    unsigned short* xc = (unsigned short*)p;   p += Mc * DIV * 2;
    unsigned short* dbc = (unsigned short*)p;  p += Mc * DBLD * 2;
    unsigned short* delta = (unsigned short*)p; p += Mc * DIV * 2;
    float* hfin = (float*)p;         p += (long)Bc * NCHUNK * DIV * NST * 4;
    float* sumd = (float*)p;

    // one-time (per launch) weight conversion
    convert_kernel<<<(unsigned)((NLIN / 4 + 255) / 256), 256, 0, stream>>>(lin_w, wlin, NLIN / 4);
    convert_kernel<<<(unsigned)((NINP / 4 + 255) / 256), 256, 0, stream>>>(inproj_w, winp, NINP / 4);
    convert_kernel<<<(unsigned)((NXP / 4 + 255) / 256), 256, 0, stream>>>(xproj_w, wxp, NXP / 4);
    convert_kernel<<<(unsigned)((NOUT / 4 + 255) / 256), 256, 0, stream>>>(outproj_w, wout, NOUT / 4);
    for (int i = 0; i < NBLKV; i++)
        convert_dtw_kernel<<<(DIV * 32 + 255) / 256, 256, 0, stream>>>(
            dtproj_w + (long)i * DIV * DTR, wdt + (long)i * DIV * 32);

    init_sm_kernel<<<1, 64, 0, stream>>>(sm);
    reduce_max_kernel<<<32, 256, 0, stream>>>(x, sm);

    for (int c = 0; c < nchunk_b; c++) {
        int b0 = c * Bc;
        fc_kernel<<<dim3(5, (unsigned)(Mc / 4)), 256, 0, stream>>>(
            x + (long)b0 * LSZ * 4, fc_w, fc_b, sm, u);

        for (int i = 0; i < NBLKV; i++) {
            const float* lb  = lin_b    + (long)i * DMV;
            const float* cw  = conv_w   + (long)i * DIV * DCV;
            const float* cb  = conv_b   + (long)i * DIV;
            const float* dpb = dtproj_b + (long)i * DIV;
            const float* al  = A_log    + (long)i * DIV * NST;
            const float* dd  = Dp       + (long)i * DIV;

            // lin + tanh: (Mc x320)@(320x320)^T -> t (bf16)
            gemm_mfma_kernel<1, 128, 64, 64, unsigned short>
                <<<dim3(5, (unsigned)(Mc / 128)), 256, 0, stream>>>(
                u, wlin + (long)i * DMV * DMV, lb, t, DMV, DMV, DMV, DMV);
            // inproj: (Mc x320)@(2560x320)^T -> xz (bf16)
            gemm_mfma_kernel<0, 128, 128, 64, unsigned short>
                <<<dim3(20, (unsigned)(Mc / 128)), 256, 0, stream>>>(
                t, winp + (long)i * 2 * DIV * DMV, nullptr, xz, 2 * DIV, DMV, DMV, 2 * DIV);
            // conv + silu (sliding window, bf16)
            conv_kernel<<<dim3(5, LSZ / TCONV, Bc), 256, 0, stream>>>(xz, cw, cb, xc);
            // xproj: (Mc x1280)@(52x1280)^T -> dbc (bf16, ld 56)
            gemm_mfma_kernel<0, 64, 64, 64, unsigned short>
                <<<dim3(1, (unsigned)(Mc / 64)), 256, 0, stream>>>(
                xc, wxp + (long)i * (DTR + 2 * NST) * DIV, nullptr, dbc,
                DTR + 2 * NST, DIV, DIV, DBLD);
            // delta = softplus(dbc[:, :20] @ dtw^T + b): K padded to 32, bf16 out
            gemm_mfma_kernel<4, 128, 128, 32, unsigned short>
                <<<dim3(10, (unsigned)(Mc / 128)), 256, 0, stream>>>(
                dbc, wdt + (long)i * DIV * 32, dpb, delta, DIV, 32, DBLD, DIV);
            // chunked scan
            scan_local_kernel<<<dim3(5, NCHUNK, Bc), 256, 0, stream>>>(
                xc, xz, dbc, delta, al, dd, hfin, sumd);
            scan_prefix_kernel<<<dim3(Bc * 80), 256, 0, stream>>>(hfin, sumd, al, Bc);
            scan_fix_kernel<<<dim3(5, NCHUNK, Bc), 256, 0, stream>>>(
                xz, dbc, delta, al, hfin);
            // outproj + elu: (Mc x1280)@(320x1280)^T -> u (bf16)
            gemm_mfma_kernel<3, 128, 64, 64, unsigned short>
                <<<dim3(5, (unsigned)(Mc / 128)), 256, 0, stream>>>(
                xz, wout + (long)i * DMV * DIV, nullptr, u, DMV, DIV, 2 * DIV, DMV);
        }

        // fused head on last token of each batch in chunk
        head_kernel<<<Bc, 512, 0, stream>>>(u, s1_w1, s1_b1, s1_w2, s1_b2,
                                            s1_w3, s1_b3, sm, (float*)d_out + b0);
    }
}

// Round 8
// 1457.272 us; speedup vs baseline: 11.6787x; 1.0247x over previous
//
#include <hip/hip_runtime.h>
#include <math.h>

// Problem constants
#define BSZ 8
#define LSZ 2048
#define DMV 320
#define DIV 1280
#define NST 16
#define DCV 8
#define DTR 20
#define NBLKV 4
#define MTOT (BSZ*LSZ)   // 16384
#define NCHUNK 32
#define CLEN 64          // NCHUNK*CLEN == LSZ
#define DBLD 56          // dbc leading dim (bf16), 16B-aligned rows

typedef __attribute__((ext_vector_type(8))) short short8;
typedef __attribute__((ext_vector_type(8))) unsigned short ushort8;
typedef __attribute__((ext_vector_type(4))) float floatx4;

__device__ inline unsigned short f2bf(float f) {
    union { float f; unsigned u; } v; v.f = f;
    unsigned r = v.u + 0x7FFFu + ((v.u >> 16) & 1u);
    return (unsigned short)(r >> 16);
}
__device__ inline float bf2f(unsigned short b) {
    union { unsigned u; float f; } v; v.u = ((unsigned)b) << 16;
    return v.f;
}

// async 16B global -> LDS (wave-uniform LDS base + lane*16) [m97 pattern]
__device__ __forceinline__ void gload_lds16(unsigned short* l, const unsigned short* g) {
    __builtin_amdgcn_global_load_lds(
        (const __attribute__((address_space(1))) unsigned int*)g,
        (__attribute__((address_space(3))) unsigned int*)l, 16, 0, 0);
}

// ---------------------------------------------------------------------------
// fp32 -> bf16 weight conversion (grid-stride, n % 4 == 0)
// ---------------------------------------------------------------------------
__global__ __launch_bounds__(256) void convert_kernel(
    const float* __restrict__ src, unsigned short* __restrict__ dst, long n4) {
    long i = (long)blockIdx.x * 256 + threadIdx.x;
    if (i >= n4) return;
    float4 v = *(const float4*)(src + i * 4);
    unsigned short o[4] = {f2bf(v.x), f2bf(v.y), f2bf(v.z), f2bf(v.w)};
    *(unsigned long long*)(dst + i * 4) = *(unsigned long long*)o;
}

// dtproj_w (NBLKV x 1280 x 20) -> bf16 padded (NBLKV x 1280 x 32), zero cols 20..31
__global__ __launch_bounds__(256) void convert_dtw_kernel(
    const float* __restrict__ src, unsigned short* __restrict__ dst) {
    int i = blockIdx.x * 256 + threadIdx.x;
    if (i >= NBLKV * DIV * 32) return;
    int l = i / (DIV * 32), rem = i % (DIV * 32);
    int d = rem >> 5, j = rem & 31;
    dst[i] = (j < DTR) ? f2bf(src[((long)l * DIV + d) * DTR + j]) : (unsigned short)0;
}

// xproj_w (NBLKV x 52 x 1280) -> bf16 padded (NBLKV x 64 x 1280), zero rows 52..63
__global__ __launch_bounds__(256) void convert_xp_kernel(
    const float* __restrict__ src, unsigned short* __restrict__ dst) {
    int i = blockIdx.x * 256 + threadIdx.x;
    if (i >= NBLKV * 64 * DIV) return;
    int l = i / (64 * DIV), rem = i % (64 * DIV);
    int n = rem / DIV, k = rem % DIV;
    dst[i] = (n < DTR + 2 * NST) ? f2bf(src[((long)l * (DTR + 2 * NST) + n) * DIV + k])
                                 : (unsigned short)0;
}

// ---------------------------------------------------------------------------
// start_max reduction (x[:,:,2] >= 0, so int-compare atomicMax is valid)
// ---------------------------------------------------------------------------
__global__ void init_sm_kernel(float* sm) {
    if (threadIdx.x == 0) ((int*)sm)[0] = 0;
}

__global__ void reduce_max_kernel(const float* __restrict__ x, float* sm) {
    int idx = blockIdx.x * blockDim.x + threadIdx.x;
    float v = 0.f;
    for (int i = idx; i < MTOT; i += gridDim.x * blockDim.x)
        v = fmaxf(v, x[i * 4 + 2]);
    #pragma unroll
    for (int off = 32; off > 0; off >>= 1)
        v = fmaxf(v, __shfl_xor(v, off, 64));
    if ((threadIdx.x & 63) == 0)
        atomicMax((int*)sm, __float_as_int(v));
}

// ---------------------------------------------------------------------------
// input normalize + fc (K=4) -> bf16 u
// ---------------------------------------------------------------------------
__global__ __launch_bounds__(256) void fc_kernel(
    const float* __restrict__ x, const float* __restrict__ fw,
    const float* __restrict__ fb, const float* __restrict__ sm,
    unsigned short* __restrict__ u) {
    int o = blockIdx.x * 64 + (threadIdx.x & 63);
    long m = (long)blockIdx.y * 4 + (threadIdx.x >> 6);
    float inv_sm = 1.0f / sm[0];
    float x0 = x[m * 4 + 0] * (1.0f / 255.0f);
    float x1 = x[m * 4 + 1] * (1.0f / 255.0f);
    float x2 = x[m * 4 + 2] * inv_sm;
    float x3 = x[m * 4 + 3];
    float acc = fb[o];
    acc = fmaf(x0, fw[o * 4 + 0], acc);
    acc = fmaf(x1, fw[o * 4 + 1], acc);
    acc = fmaf(x2, fw[o * 4 + 2], acc);
    acc = fmaf(x3, fw[o * 4 + 3], acc);
    u[m * DMV + o] = f2bf(acc);
}

// ---------------------------------------------------------------------------
// bf16 MFMA GEMM with async global->LDS staging (m97 structure).
// Y[m,n] = act(sum_k X[m,k]*W[n,k] (+bias)).  BK=KB in {32,64}.
// LDS tiles unpadded row-major [row][KB] (layout forced by global_load_lds:
// slot s=(call*64+lane) holds row s/CPR, 16B-chunk s%CPR).
// W tile must have ALL rows readable: pad weights to BN multiple (xproj).
// A/B frag: lane holds 8 contig k at row=lane&15, k0=(lane>>4)*8 [m89/m91]
// C/D: row = (lane>>4)*4 + reg, col = lane&15                    [m89/m91]
// ACT: 0=none 1=tanh 3=elu 4=softplus(fast)
// ---------------------------------------------------------------------------
template<int ACT, int BM, int BN, int KB, typename TOUT>
__global__ __launch_bounds__(256) void gemm_mfma_kernel(
    const unsigned short* __restrict__ X, const unsigned short* __restrict__ W,
    const float* __restrict__ bias, TOUT* __restrict__ Y,
    int N, int K, long ldx, long ldy)
{
    constexpr int WMT = (BM == 128 && BN == 128) ? 4 : 2;
    constexpr int WNT = (BM == 64 && BN == 64) ? 2 : 4;
    constexpr int CPR = KB / 8;                  // 16B chunks per row
    constexpr int NCX = BM * CPR / 256;          // async calls per wave (X)
    constexpr int NCW = BN * CPR / 256;          // async calls per wave (W)
    __shared__ unsigned short Xs[BM * KB];
    __shared__ unsigned short Ws[BN * KB];

    int tid = threadIdx.x;
    int wave = tid >> 6, lane = tid & 63;
    int quad = lane >> 4, l15 = lane & 15;
    int wmbase, wnbase;
    if (BM == 128 && BN == 128)      { wmbase = (wave & 1) * 64; wnbase = (wave >> 1) * 64; }
    else if (BM == 128 && BN == 64)  { wmbase = wave * 32;       wnbase = 0; }
    else                             { wmbase = (wave & 1) * 32; wnbase = (wave >> 1) * 32; }
    long m0 = (long)blockIdx.y * BM;
    int n0 = blockIdx.x * BN;

    floatx4 acc[WMT][WNT];
    #pragma unroll
    for (int i = 0; i < WMT; i++)
        #pragma unroll
        for (int j = 0; j < WNT; j++)
            acc[i][j] = (floatx4){0.f, 0.f, 0.f, 0.f};

    const unsigned short* Xb = X + m0 * ldx;
    const unsigned short* Wb = W + (long)n0 * K;

    for (int k0 = 0; k0 < K; k0 += KB) {
        #pragma unroll
        for (int j = 0; j < NCX; j++) {
            int s = (wave * NCX + j) * 64 + lane;
            int r = s / CPR, c = s % CPR;
            gload_lds16(&Xs[(wave * NCX + j) * 512],
                        Xb + (long)r * ldx + k0 + c * 8);
        }
        #pragma unroll
        for (int j = 0; j < NCW; j++) {
            int s = (wave * NCW + j) * 64 + lane;
            int r = s / CPR, c = s % CPR;
            gload_lds16(&Ws[(wave * NCW + j) * 512],
                        Wb + (long)r * K + k0 + c * 8);
        }
        __syncthreads();
        #pragma unroll
        for (int kk = 0; kk < KB; kk += 32) {
            short8 af[WMT], bfr[WNT];
            #pragma unroll
            for (int i = 0; i < WMT; i++)
                af[i] = *(short8*)&Xs[(wmbase + i * 16 + l15) * KB + kk + quad * 8];
            #pragma unroll
            for (int j = 0; j < WNT; j++)
                bfr[j] = *(short8*)&Ws[(wnbase + j * 16 + l15) * KB + kk + quad * 8];
            #pragma unroll
            for (int i = 0; i < WMT; i++)
                #pragma unroll
                for (int j = 0; j < WNT; j++)
                    acc[i][j] = __builtin_amdgcn_mfma_f32_16x16x32_bf16(
                        af[i], bfr[j], acc[i][j], 0, 0, 0);
        }
        __syncthreads();
    }

    #pragma unroll
    for (int i = 0; i < WMT; i++) {
        long mb = m0 + wmbase + i * 16 + quad * 4;
        #pragma unroll
        for (int j = 0; j < WNT; j++) {
            int n = n0 + wnbase + j * 16 + l15;
            if (n >= N) continue;
            float bv = bias ? bias[n] : 0.f;
            #pragma unroll
            for (int r = 0; r < 4; r++) {
                float v = acc[i][j][r] + bv;
                if (ACT == 1) v = tanhf(v);
                else if (ACT == 3) v = (v > 0.f) ? v : expm1f(v);
                else if (ACT == 4) v = (v > 20.f) ? v : __logf(1.0f + __expf(v));
                if constexpr (sizeof(TOUT) == 2)
                    Y[(mb + r) * ldy + n] = f2bf(v);
                else
                    Y[(mb + r) * ldy + n] = v;
            }
        }
    }
}

// ---------------------------------------------------------------------------
// fused head, wave-per-output with lane-split K + shuffle reduce.
// One block per batch, 512 threads = 8 waves.
// ---------------------------------------------------------------------------
__global__ __launch_bounds__(512) void head_kernel(
    const unsigned short* __restrict__ u,
    const float* __restrict__ w1, const float* __restrict__ b1,
    const float* __restrict__ w2, const float* __restrict__ b2,
    const float* __restrict__ w3, const float* __restrict__ b3,
    const float* __restrict__ sm, float* __restrict__ out)
{
    __shared__ float xs[DMV];
    __shared__ float h1s[512];
    __shared__ float h2s[512];
    __shared__ float red[8];
    int b = blockIdx.x;
    int tid = threadIdx.x, wave = tid >> 6, lane = tid & 63;
    const unsigned short* xr = u + ((long)b * LSZ + (LSZ - 1)) * DMV;
    if (tid < DMV) xs[tid] = bf2f(xr[tid]);
    __syncthreads();

    #pragma unroll 4
    for (int j = 0; j < 64; j++) {
        int n = wave * 64 + j;
        const float* wr = w1 + (long)n * DMV;
        float part = 0.f;
        #pragma unroll
        for (int k = 0; k < DMV; k += 64) part = fmaf(xs[k + lane], wr[k + lane], part);
        #pragma unroll
        for (int off = 32; off > 0; off >>= 1) part += __shfl_xor(part, off, 64);
        if (lane == 0) h1s[n] = fmaxf(part + b1[n], 0.f);
    }
    __syncthreads();
    #pragma unroll 4
    for (int j = 0; j < 64; j++) {
        int n = wave * 64 + j;
        const float* wr = w2 + (long)n * 512;
        float part = 0.f;
        #pragma unroll
        for (int k = 0; k < 512; k += 64) part = fmaf(h1s[k + lane], wr[k + lane], part);
        #pragma unroll
        for (int off = 32; off > 0; off >>= 1) part += __shfl_xor(part, off, 64);
        if (lane == 0) h2s[n] = fmaxf(part + b2[n], 0.f);
    }
    __syncthreads();
    float part = h2s[tid] * w3[tid];
    #pragma unroll
    for (int off = 32; off > 0; off >>= 1) part += __shfl_xor(part, off, 64);
    if (lane == 0) red[wave] = part;
    __syncthreads();
    if (tid == 0) {
        float s = b3[0];
        #pragma unroll
        for (int w = 0; w < 8; w++) s += red[w];
        float scale = sm[0] / 8.624618986159398f;   // 1 + ln(2048)
        out[b] = fmaxf(s * scale, 0.f);
    }
}

// ---------------------------------------------------------------------------
// depthwise causal conv (k=8) + bias + silu, sliding-window, bf16
// ---------------------------------------------------------------------------
#define TCONV 32
__global__ __launch_bounds__(256) void conv_kernel(
    const unsigned short* __restrict__ xz, const float* __restrict__ cw,
    const float* __restrict__ cb, unsigned short* __restrict__ xc)
{
    int d = blockIdx.x * 256 + threadIdx.x;
    int lb = blockIdx.z;
    int l0 = blockIdx.y * TCONV;
    long base = (long)lb * LSZ + l0;

    float w[8];
    #pragma unroll
    for (int k = 0; k < 8; k++) w[k] = cw[d * 8 + k];
    float bc = cb[d];

    float win[8];
    #pragma unroll
    for (int i = 0; i < 7; i++) {
        int l = l0 - 7 + i;
        win[i] = (l >= 0) ? bf2f(xz[(base - 7 + i) * 2560 + d]) : 0.f;
    }
    #pragma unroll
    for (int s = 0; s < TCONV; s++) {
        win[7] = bf2f(xz[(base + s) * 2560 + d]);
        float acc = bc;
        #pragma unroll
        for (int k = 0; k < 8; k++) acc = fmaf(win[k], w[k], acc);
        float sv = acc / (1.0f + __expf(-acc));
        xc[(base + s) * DIV + d] = f2bf(sv);
        #pragma unroll
        for (int k = 0; k < 7; k++) win[k] = win[k + 1];
    }
}

// power ladder: pw[n] = p^(n+1)
__device__ inline void pow_ladder(float p, float* pw) {
    pw[0] = p;
    pw[1] = pw[0] * pw[0];
    pw[2] = pw[1] * pw[0];
    pw[3] = pw[1] * pw[1];
    pw[4] = pw[3] * pw[0];
    pw[5] = pw[3] * pw[1];
    pw[6] = pw[3] * pw[2];
    pw[7] = pw[3] * pw[3];
    #pragma unroll
    for (int k = 8; k < 16; k++) pw[k] = pw[7] * pw[k - 8];
}

// ---------------------------------------------------------------------------
// Chunked scan phase 1: per-chunk local scan (h0=0). delta precomputed (bf16).
// ---------------------------------------------------------------------------
__global__ __launch_bounds__(256) void scan_local_kernel(
    const unsigned short* __restrict__ xc, unsigned short* xz,
    const unsigned short* __restrict__ dbc, const unsigned short* __restrict__ delta,
    const float* __restrict__ A_log, const float* __restrict__ Dp,
    float* __restrict__ hfin, float* __restrict__ sumd)
{
    __shared__ float S[CLEN * 32];
    int lb = blockIdx.z;
    int ch = blockIdx.y;
    int d = blockIdx.x * 256 + threadIdx.x;
    int tid = threadIdx.x;

    float a[NST], h[NST];
    #pragma unroll
    for (int n = 0; n < NST; n++) {
        a[n] = -__expf(A_log[d * NST + n]);
        h[n] = 0.f;
    }
    float a0 = a[0];
    bool geo = true;
    #pragma unroll
    for (int n = 1; n < NST; n++)
        geo = geo && (fabsf(a[n] - (float)(n + 1) * a0) <= 1e-4f * (float)(n + 1));
    float Dd = Dp[d];

    long tok0 = (long)lb * LSZ + ch * CLEN;
    for (int i = tid; i < CLEN * 32; i += 256) {
        int r = i >> 5, c = i & 31;
        S[i] = bf2f(dbc[(tok0 + r) * DBLD + 20 + c]);
    }
    __syncthreads();

    float sd = 0.f;
    if (__all(geo)) {
        for (int l = 0; l < CLEN; l++) {
            long m = tok0 + l;
            const float* row = &S[l * 32];
            float dl = bf2f(delta[m * DIV + d]);
            sd += dl;
            float xv = bf2f(xc[m * DIV + d]);
            float db = dl * xv;
            float pw[NST];
            pow_ladder(__expf(dl * a0), pw);
            float y = 0.f;
            #pragma unroll
            for (int n = 0; n < NST; n++) {
                h[n] = fmaf(pw[n], h[n], db * row[n]);
                y = fmaf(h[n], row[16 + n], y);
            }
            y = fmaf(xv, Dd, y);
            xz[m * 2560 + d] = f2bf(y);
        }
    } else {
        for (int l = 0; l < CLEN; l++) {
            long m = tok0 + l;
            const float* row = &S[l * 32];
            float dl = bf2f(delta[m * DIV + d]);
            sd += dl;
            float xv = bf2f(xc[m * DIV + d]);
            float db = dl * xv;
            float y = 0.f;
            #pragma unroll
            for (int n = 0; n < NST; n++) {
                float dA = __expf(dl * a[n]);
                h[n] = fmaf(dA, h[n], db * row[n]);
                y = fmaf(h[n], row[16 + n], y);
            }
            y = fmaf(xv, Dd, y);
            xz[m * 2560 + d] = f2bf(y);
        }
    }

    long cidx = ((long)lb * NCHUNK + ch) * DIV + d;
    #pragma unroll
    for (int n = 0; n < NST; n++) hfin[cidx * NST + n] = h[n];
    sumd[cidx] = sd;
}

// ---------------------------------------------------------------------------
// Phase 2: sequential prefix over chunks. One thread per (b, d, n).
// ---------------------------------------------------------------------------
__global__ __launch_bounds__(256) void scan_prefix_kernel(
    float* __restrict__ hfin, const float* __restrict__ sumd,
    const float* __restrict__ A_log, int Bc)
{
    long g = (long)blockIdx.x * 256 + threadIdx.x;
    int n = (int)(g & (NST - 1));
    long t = g >> 4;
    int d = (int)(t % DIV);
    int lb = (int)(t / DIV);
    if (lb >= Bc) return;

    float a = -__expf(A_log[d * NST + n]);
    float s = 0.f;
    for (int c = 0; c < NCHUNK; c++) {
        long cidx = ((long)lb * NCHUNK + c) * DIV + d;
        float hl = hfin[cidx * NST + n];
        float P = __expf(a * sumd[cidx]);
        hfin[cidx * NST + n] = s;
        s = fmaf(P, s, hl);
    }
}

// ---------------------------------------------------------------------------
// Phase 3: cross-chunk contribution (running product) + silu(z).
// ---------------------------------------------------------------------------
__global__ __launch_bounds__(256) void scan_fix_kernel(
    unsigned short* xz, const unsigned short* __restrict__ dbc,
    const unsigned short* __restrict__ delta,
    const float* __restrict__ A_log, const float* __restrict__ hfin)
{
    __shared__ float S[CLEN * 16];
    int lb = blockIdx.z;
    int ch = blockIdx.y;
    int d = blockIdx.x * 256 + threadIdx.x;
    int tid = threadIdx.x;

    float a[NST], hr[NST];
    #pragma unroll
    for (int n = 0; n < NST; n++) a[n] = -__expf(A_log[d * NST + n]);
    float a0 = a[0];
    bool geo = true;
    #pragma unroll
    for (int n = 1; n < NST; n++)
        geo = geo && (fabsf(a[n] - (float)(n + 1) * a0) <= 1e-4f * (float)(n + 1));

    long cidx = ((long)lb * NCHUNK + ch) * DIV + d;
    #pragma unroll
    for (int n = 0; n < NST; n += 4)
        *(float4*)&hr[n] = *(const float4*)&hfin[cidx * NST + n];

    long tok0 = (long)lb * LSZ + ch * CLEN;
    for (int i = tid; i < CLEN * 16; i += 256) {
        int r = i >> 4, c = i & 15;
        S[i] = bf2f(dbc[(tok0 + r) * DBLD + 36 + c]);
    }
    __syncthreads();

    if (__all(geo)) {
        for (int l = 0; l < CLEN; l++) {
            long m = tok0 + l;
            const float* row = &S[l * 16];
            float dl = bf2f(delta[m * DIV + d]);
            float pw[NST];
            pow_ladder(__expf(dl * a0), pw);
            float fix = 0.f;
            #pragma unroll
            for (int n = 0; n < NST; n++) {
                hr[n] *= pw[n];
                fix = fmaf(hr[n], row[n], fix);
            }
            float y = bf2f(xz[m * 2560 + d]) + fix;
            float zv = bf2f(xz[m * 2560 + 1280 + d]);
            float sz = zv / (1.0f + __expf(-zv));
            xz[m * 2560 + d] = f2bf(y * sz);
        }
    } else {
        for (int l = 0; l < CLEN; l++) {
            long m = tok0 + l;
            const float* row = &S[l * 16];
            float dl = bf2f(delta[m * DIV + d]);
            float fix = 0.f;
            #pragma unroll
            for (int n = 0; n < NST; n++) {
                hr[n] *= __expf(dl * a[n]);
                fix = fmaf(hr[n], row[n], fix);
            }
            float y = bf2f(xz[m * 2560 + d]) + fix;
            float zv = bf2f(xz[m * 2560 + 1280 + d]);
            float sz = zv / (1.0f + __expf(-zv));
            xz[m * 2560 + d] = f2bf(y * sz);
        }
    }
}

// ---------------------------------------------------------------------------
extern "C" void kernel_launch(void* const* d_in, const int* in_sizes, int n_in,
                              void* d_out, int out_size, void* d_ws, size_t ws_size,
                              hipStream_t stream) {
    const float* x        = (const float*)d_in[0];
    const float* fc_w     = (const float*)d_in[1];
    const float* fc_b     = (const float*)d_in[2];
    const float* lin_w    = (const float*)d_in[3];
    const float* lin_b    = (const float*)d_in[4];
    const float* inproj_w = (const float*)d_in[5];
    const float* conv_w   = (const float*)d_in[6];
    const float* conv_b   = (const float*)d_in[7];
    const float* xproj_w  = (const float*)d_in[8];
    const float* dtproj_w = (const float*)d_in[9];
    const float* dtproj_b = (const float*)d_in[10];
    const float* A_log    = (const float*)d_in[11];
    const float* Dp       = (const float*)d_in[12];
    const float* outproj_w= (const float*)d_in[13];
    const float* s1_w1    = (const float*)d_in[14];
    const float* s1_b1    = (const float*)d_in[15];
    const float* s1_w2    = (const float*)d_in[16];
    const float* s1_b2    = (const float*)d_in[17];
    const float* s1_w3    = (const float*)d_in[18];
    const float* s1_b3    = (const float*)d_in[19];

    const long NLIN = (long)NBLKV * DMV * DMV;
    const long NINP = (long)NBLKV * 2 * DIV * DMV;
    const long NXPP = (long)NBLKV * 64 * DIV;     // padded xproj (64 rows)
    const long NOUT = (long)NBLKV * DMV * DIV;
    const long NDTW = (long)NBLKV * DIV * 32;

    // ---- workspace sizing ----
    const long FIXED = 256 +
                       (NLIN + NINP + NXPP + NOUT + NDTW) * 2 + 256;
    const long PER_BATCH = (long)LSZ * (DMV + DMV + 2 * DIV + DIV) * 2   // bf16 acts
                         + (long)LSZ * DBLD * 2                          // dbc bf16
                         + (long)LSZ * DIV * 2                           // delta bf16
                         + (long)NCHUNK * DIV * NST * 4                  // hfin
                         + (long)NCHUNK * DIV * 4;                       // sumd
    int Bc = 8;
    while (Bc > 1 && (size_t)(FIXED + (long)Bc * PER_BATCH) > ws_size)
        Bc >>= 1;
    int nchunk_b = BSZ / Bc;
    long Mc = (long)Bc * LSZ;

    char* p = (char*)d_ws;
    float* sm = (float*)p;           p += 256;
    unsigned short* wlin = (unsigned short*)p; p += NLIN * 2;
    unsigned short* winp = (unsigned short*)p; p += NINP * 2;
    unsigned short* wxp  = (unsigned short*)p; p += NXPP * 2;
    unsigned short* wout = (unsigned short*)p; p += NOUT * 2;
    unsigned short* wdt  = (unsigned short*)p; p += NDTW * 2;
    unsigned short* u  = (unsigned short*)p;   p += Mc * DMV * 2;
    unsigned short* t  = (unsigned short*)p;   p += Mc * DMV * 2;
    unsigned short* xz = (unsigned short*)p;   p += Mc * 2560 * 2;
    unsigned short* xc = (unsigned short*)p;   p += Mc * DIV * 2;
    unsigned short* dbc = (unsigned short*)p;  p += Mc * DBLD * 2;
    unsigned short* delta = (unsigned short*)p; p += Mc * DIV * 2;
    float* hfin = (float*)p;         p += (long)Bc * NCHUNK * DIV * NST * 4;
    float* sumd = (float*)p;

    // one-time (per launch) weight conversion
    convert_kernel<<<(unsigned)((NLIN / 4 + 255) / 256), 256, 0, stream>>>(lin_w, wlin, NLIN / 4);
    convert_kernel<<<(unsigned)((NINP / 4 + 255) / 256), 256, 0, stream>>>(inproj_w, winp, NINP / 4);
    convert_kernel<<<(unsigned)((NOUT / 4 + 255) / 256), 256, 0, stream>>>(outproj_w, wout, NOUT / 4);
    convert_xp_kernel<<<(unsigned)((NXPP + 255) / 256), 256, 0, stream>>>(xproj_w, wxp);
    convert_dtw_kernel<<<(unsigned)((NDTW + 255) / 256), 256, 0, stream>>>(dtproj_w, wdt);

    init_sm_kernel<<<1, 64, 0, stream>>>(sm);
    reduce_max_kernel<<<32, 256, 0, stream>>>(x, sm);

    for (int c = 0; c < nchunk_b; c++) {
        int b0 = c * Bc;
        fc_kernel<<<dim3(5, (unsigned)(Mc / 4)), 256, 0, stream>>>(
            x + (long)b0 * LSZ * 4, fc_w, fc_b, sm, u);

        for (int i = 0; i < NBLKV; i++) {
            const float* lb  = lin_b    + (long)i * DMV;
            const float* cw  = conv_w   + (long)i * DIV * DCV;
            const float* cb  = conv_b   + (long)i * DIV;
            const float* dpb = dtproj_b + (long)i * DIV;
            const float* al  = A_log    + (long)i * DIV * NST;
            const float* dd  = Dp       + (long)i * DIV;

            // lin + tanh: (Mc x320)@(320x320)^T -> t (bf16)
            gemm_mfma_kernel<1, 128, 64, 64, unsigned short>
                <<<dim3(5, (unsigned)(Mc / 128)), 256, 0, stream>>>(
                u, wlin + (long)i * DMV * DMV, lb, t, DMV, DMV, DMV, DMV);
            // inproj: (Mc x320)@(2560x320)^T -> xz (bf16)
            gemm_mfma_kernel<0, 128, 128, 64, unsigned short>
                <<<dim3(20, (unsigned)(Mc / 128)), 256, 0, stream>>>(
                t, winp + (long)i * 2 * DIV * DMV, nullptr, xz, 2 * DIV, DMV, DMV, 2 * DIV);
            // conv + silu (sliding window, bf16)
            conv_kernel<<<dim3(5, LSZ / TCONV, Bc), 256, 0, stream>>>(xz, cw, cb, xc);
            // xproj: (Mc x1280)@(64x1280)^T (padded W) -> dbc (bf16, ld 56)
            gemm_mfma_kernel<0, 64, 64, 64, unsigned short>
                <<<dim3(1, (unsigned)(Mc / 64)), 256, 0, stream>>>(
                xc, wxp + (long)i * 64 * DIV, nullptr, dbc,
                DTR + 2 * NST, DIV, DIV, DBLD);
            // delta = softplus(dbc[:, :20] @ dtw^T + b): K padded to 32, bf16 out
            gemm_mfma_kernel<4, 128, 128, 32, unsigned short>
                <<<dim3(10, (unsigned)(Mc / 128)), 256, 0, stream>>>(
                dbc, wdt + (long)i * DIV * 32, dpb, delta, DIV, 32, DBLD, DIV);
            // chunked scan
            scan_local_kernel<<<dim3(5, NCHUNK, Bc), 256, 0, stream>>>(
                xc, xz, dbc, delta, al, dd, hfin, sumd);
            scan_prefix_kernel<<<dim3(Bc * 80), 256, 0, stream>>>(hfin, sumd, al, Bc);
            scan_fix_kernel<<<dim3(5, NCHUNK, Bc), 256, 0, stream>>>(
                xz, dbc, delta, al, hfin);
            // outproj + elu: (Mc x1280)@(320x1280)^T -> u (bf16)
            gemm_mfma_kernel<3, 128, 64, 64, unsigned short>
                <<<dim3(5, (unsigned)(Mc / 128)), 256, 0, stream>>>(
                xz, wout + (long)i * DMV * DIV, nullptr, u, DMV, DIV, 2 * DIV, DMV);
        }

        // fused head on last token of each batch in chunk
        head_kernel<<<Bc, 512, 0, stream>>>(u, s1_w1, s1_b1, s1_w2, s1_b2,
                                            s1_w3, s1_b3, sm, (float*)d_out + b0);
    }
}

// Round 9
// 1380.783 us; speedup vs baseline: 12.3256x; 1.0554x over previous
//
#include <hip/hip_runtime.h>
#include <math.h>

// Problem constants
#define BSZ 8
#define LSZ 2048
#define DMV 320
#define DIV 1280
#define NST 16
#define DCV 8
#define DTR 20
#define NBLKV 4
#define MTOT (BSZ*LSZ)   // 16384
#define NCHUNK 32
#define CLEN 64          // NCHUNK*CLEN == LSZ
#define DBLD 56          // dbc leading dim (bf16), 16B-aligned rows

typedef __attribute__((ext_vector_type(8))) short short8;
typedef __attribute__((ext_vector_type(8))) unsigned short ushort8;
typedef __attribute__((ext_vector_type(4))) float floatx4;

__device__ inline unsigned short f2bf(float f) {
    union { float f; unsigned u; } v; v.f = f;
    unsigned r = v.u + 0x7FFFu + ((v.u >> 16) & 1u);
    return (unsigned short)(r >> 16);
}
__device__ inline float bf2f(unsigned short b) {
    union { unsigned u; float f; } v; v.u = ((unsigned)b) << 16;
    return v.f;
}

// async 16B global -> LDS (wave-uniform LDS base + lane*16) [m97 pattern]
__device__ __forceinline__ void gload_lds16(unsigned short* l, const unsigned short* g) {
    __builtin_amdgcn_global_load_lds(
        (const __attribute__((address_space(1))) unsigned int*)g,
        (__attribute__((address_space(3))) unsigned int*)l, 16, 0, 0);
}

// ---------------------------------------------------------------------------
// fp32 -> bf16 weight conversion (grid-stride, n % 4 == 0)
// ---------------------------------------------------------------------------
__global__ __launch_bounds__(256) void convert_kernel(
    const float* __restrict__ src, unsigned short* __restrict__ dst, long n4) {
    long i = (long)blockIdx.x * 256 + threadIdx.x;
    if (i >= n4) return;
    float4 v = *(const float4*)(src + i * 4);
    unsigned short o[4] = {f2bf(v.x), f2bf(v.y), f2bf(v.z), f2bf(v.w)};
    *(unsigned long long*)(dst + i * 4) = *(unsigned long long*)o;
}

// dtproj_w (NBLKV x 1280 x 20) -> bf16 padded (NBLKV x 1280 x 32), zero cols 20..31
__global__ __launch_bounds__(256) void convert_dtw_kernel(
    const float* __restrict__ src, unsigned short* __restrict__ dst) {
    int i = blockIdx.x * 256 + threadIdx.x;
    if (i >= NBLKV * DIV * 32) return;
    int l = i / (DIV * 32), rem = i % (DIV * 32);
    int d = rem >> 5, j = rem & 31;
    dst[i] = (j < DTR) ? f2bf(src[((long)l * DIV + d) * DTR + j]) : (unsigned short)0;
}

// xproj_w (NBLKV x 52 x 1280) -> bf16 padded (NBLKV x 64 x 1280), zero rows 52..63
__global__ __launch_bounds__(256) void convert_xp_kernel(
    const float* __restrict__ src, unsigned short* __restrict__ dst) {
    int i = blockIdx.x * 256 + threadIdx.x;
    if (i >= NBLKV * 64 * DIV) return;
    int l = i / (64 * DIV), rem = i % (64 * DIV);
    int n = rem / DIV, k = rem % DIV;
    dst[i] = (n < DTR + 2 * NST) ? f2bf(src[((long)l * (DTR + 2 * NST) + n) * DIV + k])
                                 : (unsigned short)0;
}

// head weight (N x K) fp32 -> pair-packed transposed bf16:
// dst[((k>>1)*N + n)*2 + (k&1)]  (thread n loads uint = weights for k, k+1)
__global__ __launch_bounds__(256) void convert_t2_kernel(
    const float* __restrict__ src, unsigned short* __restrict__ dst, int N, int K) {
    int i = blockIdx.x * 256 + threadIdx.x;
    if (i >= N * K) return;
    int n = i / K, k = i % K;
    dst[((k >> 1) * N + n) * 2 + (k & 1)] = f2bf(src[i]);
}

// ---------------------------------------------------------------------------
// start_max reduction (x[:,:,2] >= 0, so int-compare atomicMax is valid)
// ---------------------------------------------------------------------------
__global__ void init_sm_kernel(float* sm) {
    if (threadIdx.x == 0) ((int*)sm)[0] = 0;
}

__global__ void reduce_max_kernel(const float* __restrict__ x, float* sm) {
    int idx = blockIdx.x * blockDim.x + threadIdx.x;
    float v = 0.f;
    for (int i = idx; i < MTOT; i += gridDim.x * blockDim.x)
        v = fmaxf(v, x[i * 4 + 2]);
    #pragma unroll
    for (int off = 32; off > 0; off >>= 1)
        v = fmaxf(v, __shfl_xor(v, off, 64));
    if ((threadIdx.x & 63) == 0)
        atomicMax((int*)sm, __float_as_int(v));
}

// ---------------------------------------------------------------------------
// input normalize + fc (K=4) -> bf16 u
// ---------------------------------------------------------------------------
__global__ __launch_bounds__(256) void fc_kernel(
    const float* __restrict__ x, const float* __restrict__ fw,
    const float* __restrict__ fb, const float* __restrict__ sm,
    unsigned short* __restrict__ u) {
    int o = blockIdx.x * 64 + (threadIdx.x & 63);
    long m = (long)blockIdx.y * 4 + (threadIdx.x >> 6);
    float inv_sm = 1.0f / sm[0];
    float x0 = x[m * 4 + 0] * (1.0f / 255.0f);
    float x1 = x[m * 4 + 1] * (1.0f / 255.0f);
    float x2 = x[m * 4 + 2] * inv_sm;
    float x3 = x[m * 4 + 3];
    float acc = fb[o];
    acc = fmaf(x0, fw[o * 4 + 0], acc);
    acc = fmaf(x1, fw[o * 4 + 1], acc);
    acc = fmaf(x2, fw[o * 4 + 2], acc);
    acc = fmaf(x3, fw[o * 4 + 3], acc);
    u[m * DMV + o] = f2bf(acc);
}

// ---------------------------------------------------------------------------
// bf16 MFMA GEMM with async global->LDS staging (m97 structure).
// ---------------------------------------------------------------------------
template<int ACT, int BM, int BN, int KB, typename TOUT>
__global__ __launch_bounds__(256) void gemm_mfma_kernel(
    const unsigned short* __restrict__ X, const unsigned short* __restrict__ W,
    const float* __restrict__ bias, TOUT* __restrict__ Y,
    int N, int K, long ldx, long ldy)
{
    constexpr int WMT = (BM == 128 && BN == 128) ? 4 : 2;
    constexpr int WNT = (BM == 64 && BN == 64) ? 2 : 4;
    constexpr int CPR = KB / 8;                  // 16B chunks per row
    constexpr int NCX = BM * CPR / 256;          // async calls per wave (X)
    constexpr int NCW = BN * CPR / 256;          // async calls per wave (W)
    __shared__ unsigned short Xs[BM * KB];
    __shared__ unsigned short Ws[BN * KB];

    int tid = threadIdx.x;
    int wave = tid >> 6, lane = tid & 63;
    int quad = lane >> 4, l15 = lane & 15;
    int wmbase, wnbase;
    if (BM == 128 && BN == 128)      { wmbase = (wave & 1) * 64; wnbase = (wave >> 1) * 64; }
    else if (BM == 128 && BN == 64)  { wmbase = wave * 32;       wnbase = 0; }
    else                             { wmbase = (wave & 1) * 32; wnbase = (wave >> 1) * 32; }
    long m0 = (long)blockIdx.y * BM;
    int n0 = blockIdx.x * BN;

    floatx4 acc[WMT][WNT];
    #pragma unroll
    for (int i = 0; i < WMT; i++)
        #pragma unroll
        for (int j = 0; j < WNT; j++)
            acc[i][j] = (floatx4){0.f, 0.f, 0.f, 0.f};

    const unsigned short* Xb = X + m0 * ldx;
    const unsigned short* Wb = W + (long)n0 * K;

    for (int k0 = 0; k0 < K; k0 += KB) {
        #pragma unroll
        for (int j = 0; j < NCX; j++) {
            int s = (wave * NCX + j) * 64 + lane;
            int r = s / CPR, c = s % CPR;
            gload_lds16(&Xs[(wave * NCX + j) * 512],
                        Xb + (long)r * ldx + k0 + c * 8);
        }
        #pragma unroll
        for (int j = 0; j < NCW; j++) {
            int s = (wave * NCW + j) * 64 + lane;
            int r = s / CPR, c = s % CPR;
            gload_lds16(&Ws[(wave * NCW + j) * 512],
                        Wb + (long)r * K + k0 + c * 8);
        }
        __syncthreads();
        #pragma unroll
        for (int kk = 0; kk < KB; kk += 32) {
            short8 af[WMT], bfr[WNT];
            #pragma unroll
            for (int i = 0; i < WMT; i++)
                af[i] = *(short8*)&Xs[(wmbase + i * 16 + l15) * KB + kk + quad * 8];
            #pragma unroll
            for (int j = 0; j < WNT; j++)
                bfr[j] = *(short8*)&Ws[(wnbase + j * 16 + l15) * KB + kk + quad * 8];
            #pragma unroll
            for (int i = 0; i < WMT; i++)
                #pragma unroll
                for (int j = 0; j < WNT; j++)
                    acc[i][j] = __builtin_amdgcn_mfma_f32_16x16x32_bf16(
                        af[i], bfr[j], acc[i][j], 0, 0, 0);
        }
        __syncthreads();
    }

    #pragma unroll
    for (int i = 0; i < WMT; i++) {
        long mb = m0 + wmbase + i * 16 + quad * 4;
        #pragma unroll
        for (int j = 0; j < WNT; j++) {
            int n = n0 + wnbase + j * 16 + l15;
            if (n >= N) continue;
            float bv = bias ? bias[n] : 0.f;
            #pragma unroll
            for (int r = 0; r < 4; r++) {
                float v = acc[i][j][r] + bv;
                if (ACT == 1) v = tanhf(v);
                else if (ACT == 3) v = (v > 0.f) ? v : expm1f(v);
                else if (ACT == 4) v = (v > 20.f) ? v : __logf(1.0f + __expf(v));
                if constexpr (sizeof(TOUT) == 2)
                    Y[(mb + r) * ldy + n] = f2bf(v);
                else
                    Y[(mb + r) * ldy + n] = v;
            }
        }
    }
}

// ---------------------------------------------------------------------------
// fused head, thread-per-output with pair-packed transposed bf16 weights.
// One block per batch, 512 threads. Coalesced independent loads -> pipelined.
// ---------------------------------------------------------------------------
__global__ __launch_bounds__(512) void head_kernel(
    const unsigned short* __restrict__ u,
    const unsigned short* __restrict__ w1t, const float* __restrict__ b1,
    const unsigned short* __restrict__ w2t, const float* __restrict__ b2,
    const float* __restrict__ w3, const float* __restrict__ b3,
    const float* __restrict__ sm, float* __restrict__ out)
{
    __shared__ float xs[DMV];
    __shared__ float h1s[512];
    __shared__ float red[8];
    int b = blockIdx.x;
    int tid = threadIdx.x;
    const unsigned short* xr = u + ((long)b * LSZ + (LSZ - 1)) * DMV;
    if (tid < DMV) xs[tid] = bf2f(xr[tid]);
    __syncthreads();

    float acc = 0.f;
    #pragma unroll 8
    for (int kk = 0; kk < DMV / 2; kk++) {
        unsigned wv = *(const unsigned*)&w1t[((long)kk * 512 + tid) * 2];
        acc = fmaf(xs[2 * kk],     bf2f((unsigned short)(wv & 0xffffu)), acc);
        acc = fmaf(xs[2 * kk + 1], bf2f((unsigned short)(wv >> 16)), acc);
    }
    h1s[tid] = fmaxf(acc + b1[tid], 0.f);
    __syncthreads();

    acc = 0.f;
    #pragma unroll 8
    for (int kk = 0; kk < 256; kk++) {
        unsigned wv = *(const unsigned*)&w2t[((long)kk * 512 + tid) * 2];
        acc = fmaf(h1s[2 * kk],     bf2f((unsigned short)(wv & 0xffffu)), acc);
        acc = fmaf(h1s[2 * kk + 1], bf2f((unsigned short)(wv >> 16)), acc);
    }
    float h2 = fmaxf(acc + b2[tid], 0.f);

    float part = h2 * w3[tid];
    #pragma unroll
    for (int off = 32; off > 0; off >>= 1) part += __shfl_xor(part, off, 64);
    if ((tid & 63) == 0) red[tid >> 6] = part;
    __syncthreads();
    if (tid == 0) {
        float s = b3[0];
        #pragma unroll
        for (int w = 0; w < 8; w++) s += red[w];
        float scale = sm[0] / 8.624618986159398f;   // 1 + ln(2048)
        out[b] = fmaxf(s * scale, 0.f);
    }
}

// ---------------------------------------------------------------------------
// depthwise causal conv (k=8) + bias + silu, sliding-window, bf16
// ---------------------------------------------------------------------------
#define TCONV 32
__global__ __launch_bounds__(256) void conv_kernel(
    const unsigned short* __restrict__ xz, const float* __restrict__ cw,
    const float* __restrict__ cb, unsigned short* __restrict__ xc)
{
    int d = blockIdx.x * 256 + threadIdx.x;
    int lb = blockIdx.z;
    int l0 = blockIdx.y * TCONV;
    long base = (long)lb * LSZ + l0;

    float w[8];
    #pragma unroll
    for (int k = 0; k < 8; k++) w[k] = cw[d * 8 + k];
    float bc = cb[d];

    float win[8];
    #pragma unroll
    for (int i = 0; i < 7; i++) {
        int l = l0 - 7 + i;
        win[i] = (l >= 0) ? bf2f(xz[(base - 7 + i) * 2560 + d]) : 0.f;
    }
    #pragma unroll
    for (int s = 0; s < TCONV; s++) {
        win[7] = bf2f(xz[(base + s) * 2560 + d]);
        float acc = bc;
        #pragma unroll
        for (int k = 0; k < 8; k++) acc = fmaf(win[k], w[k], acc);
        float sv = acc / (1.0f + __expf(-acc));
        xc[(base + s) * DIV + d] = f2bf(sv);
        #pragma unroll
        for (int k = 0; k < 7; k++) win[k] = win[k + 1];
    }
}

// power ladder: pw[n] = p^(n+1)
__device__ inline void pow_ladder(float p, float* pw) {
    pw[0] = p;
    pw[1] = pw[0] * pw[0];
    pw[2] = pw[1] * pw[0];
    pw[3] = pw[1] * pw[1];
    pw[4] = pw[3] * pw[0];
    pw[5] = pw[3] * pw[1];
    pw[6] = pw[3] * pw[2];
    pw[7] = pw[3] * pw[3];
    #pragma unroll
    for (int k = 8; k < 16; k++) pw[k] = pw[7] * pw[k - 8];
}

// ---------------------------------------------------------------------------
// Chunked scan phase 1: per-chunk local scan (h0=0). delta precomputed (bf16).
// ---------------------------------------------------------------------------
__global__ __launch_bounds__(256) void scan_local_kernel(
    const unsigned short* __restrict__ xc, unsigned short* xz,
    const unsigned short* __restrict__ dbc, const unsigned short* __restrict__ delta,
    const float* __restrict__ A_log, const float* __restrict__ Dp,
    float* __restrict__ hfin, float* __restrict__ sumd)
{
    __shared__ float S[CLEN * 32];
    int lb = blockIdx.z;
    int ch = blockIdx.y;
    int d = blockIdx.x * 256 + threadIdx.x;
    int tid = threadIdx.x;

    float a[NST], h[NST];
    #pragma unroll
    for (int n = 0; n < NST; n++) {
        a[n] = -__expf(A_log[d * NST + n]);
        h[n] = 0.f;
    }
    float a0 = a[0];
    bool geo = true;
    #pragma unroll
    for (int n = 1; n < NST; n++)
        geo = geo && (fabsf(a[n] - (float)(n + 1) * a0) <= 1e-4f * (float)(n + 1));
    float Dd = Dp[d];

    long tok0 = (long)lb * LSZ + ch * CLEN;
    for (int i = tid; i < CLEN * 32; i += 256) {
        int r = i >> 5, c = i & 31;
        S[i] = bf2f(dbc[(tok0 + r) * DBLD + 20 + c]);
    }
    __syncthreads();

    float sd = 0.f;
    if (__all(geo)) {
        for (int l = 0; l < CLEN; l++) {
            long m = tok0 + l;
            const float* row = &S[l * 32];
            float dl = bf2f(delta[m * DIV + d]);
            sd += dl;
            float xv = bf2f(xc[m * DIV + d]);
            float db = dl * xv;
            float pw[NST];
            pow_ladder(__expf(dl * a0), pw);
            float y = 0.f;
            #pragma unroll
            for (int n = 0; n < NST; n++) {
                h[n] = fmaf(pw[n], h[n], db * row[n]);
                y = fmaf(h[n], row[16 + n], y);
            }
            y = fmaf(xv, Dd, y);
            xz[m * 2560 + d] = f2bf(y);
        }
    } else {
        for (int l = 0; l < CLEN; l++) {
            long m = tok0 + l;
            const float* row = &S[l * 32];
            float dl = bf2f(delta[m * DIV + d]);
            sd += dl;
            float xv = bf2f(xc[m * DIV + d]);
            float db = dl * xv;
            float y = 0.f;
            #pragma unroll
            for (int n = 0; n < NST; n++) {
                float dA = __expf(dl * a[n]);
                h[n] = fmaf(dA, h[n], db * row[n]);
                y = fmaf(h[n], row[16 + n], y);
            }
            y = fmaf(xv, Dd, y);
            xz[m * 2560 + d] = f2bf(y);
        }
    }

    long cidx = ((long)lb * NCHUNK + ch) * DIV + d;
    #pragma unroll
    for (int n = 0; n < NST; n++) hfin[cidx * NST + n] = h[n];
    sumd[cidx] = sd;
}

// ---------------------------------------------------------------------------
// Phase 2: sequential prefix over chunks. One thread per (b, d, n).
// ---------------------------------------------------------------------------
__global__ __launch_bounds__(256) void scan_prefix_kernel(
    float* __restrict__ hfin, const float* __restrict__ sumd,
    const float* __restrict__ A_log, int Bc)
{
    long g = (long)blockIdx.x * 256 + threadIdx.x;
    int n = (int)(g & (NST - 1));
    long t = g >> 4;
    int d = (int)(t % DIV);
    int lb = (int)(t / DIV);
    if (lb >= Bc) return;

    float a = -__expf(A_log[d * NST + n]);
    float s = 0.f;
    for (int c = 0; c < NCHUNK; c++) {
        long cidx = ((long)lb * NCHUNK + c) * DIV + d;
        float hl = hfin[cidx * NST + n];
        float P = __expf(a * sumd[cidx]);
        hfin[cidx * NST + n] = s;
        s = fmaf(P, s, hl);
    }
}

// ---------------------------------------------------------------------------
// Phase 3: cross-chunk contribution (running product) + silu(z).
// ---------------------------------------------------------------------------
__global__ __launch_bounds__(256) void scan_fix_kernel(
    unsigned short* xz, const unsigned short* __restrict__ dbc,
    const unsigned short* __restrict__ delta,
    const float* __restrict__ A_log, const float* __restrict__ hfin)
{
    __shared__ float S[CLEN * 16];
    int lb = blockIdx.z;
    int ch = blockIdx.y;
    int d = blockIdx.x * 256 + threadIdx.x;
    int tid = threadIdx.x;

    float a[NST], hr[NST];
    #pragma unroll
    for (int n = 0; n < NST; n++) a[n] = -__expf(A_log[d * NST + n]);
    float a0 = a[0];
    bool geo = true;
    #pragma unroll
    for (int n = 1; n < NST; n++)
        geo = geo && (fabsf(a[n] - (float)(n + 1) * a0) <= 1e-4f * (float)(n + 1));

    long cidx = ((long)lb * NCHUNK + ch) * DIV + d;
    #pragma unroll
    for (int n = 0; n < NST; n += 4)
        *(float4*)&hr[n] = *(const float4*)&hfin[cidx * NST + n];

    long tok0 = (long)lb * LSZ + ch * CLEN;
    for (int i = tid; i < CLEN * 16; i += 256) {
        int r = i >> 4, c = i & 15;
        S[i] = bf2f(dbc[(tok0 + r) * DBLD + 36 + c]);
    }
    __syncthreads();

    if (__all(geo)) {
        for (int l = 0; l < CLEN; l++) {
            long m = tok0 + l;
            const float* row = &S[l * 16];
            float dl = bf2f(delta[m * DIV + d]);
            float pw[NST];
            pow_ladder(__expf(dl * a0), pw);
            float fix = 0.f;
            #pragma unroll
            for (int n = 0; n < NST; n++) {
                hr[n] *= pw[n];
                fix = fmaf(hr[n], row[n], fix);
            }
            float y = bf2f(xz[m * 2560 + d]) + fix;
            float zv = bf2f(xz[m * 2560 + 1280 + d]);
            float sz = zv / (1.0f + __expf(-zv));
            xz[m * 2560 + d] = f2bf(y * sz);
        }
    } else {
        for (int l = 0; l < CLEN; l++) {
            long m = tok0 + l;
            const float* row = &S[l * 16];
            float dl = bf2f(delta[m * DIV + d]);
            float fix = 0.f;
            #pragma unroll
            for (int n = 0; n < NST; n++) {
                hr[n] *= __expf(dl * a[n]);
                fix = fmaf(hr[n], row[n], fix);
            }
            float y = bf2f(xz[m * 2560 + d]) + fix;
            float zv = bf2f(xz[m * 2560 + 1280 + d]);
            float sz = zv / (1.0f + __expf(-zv));
            xz[m * 2560 + d] = f2bf(y * sz);
        }
    }
}

// ---------------------------------------------------------------------------
extern "C" void kernel_launch(void* const* d_in, const int* in_sizes, int n_in,
                              void* d_out, int out_size, void* d_ws, size_t ws_size,
                              hipStream_t stream) {
    const float* x        = (const float*)d_in[0];
    const float* fc_w     = (const float*)d_in[1];
    const float* fc_b     = (const float*)d_in[2];
    const float* lin_w    = (const float*)d_in[3];
    const float* lin_b    = (const float*)d_in[4];
    const float* inproj_w = (const float*)d_in[5];
    const float* conv_w   = (const float*)d_in[6];
    const float* conv_b   = (const float*)d_in[7];
    const float* xproj_w  = (const float*)d_in[8];
    const float* dtproj_w = (const float*)d_in[9];
    const float* dtproj_b = (const float*)d_in[10];
    const float* A_log    = (const float*)d_in[11];
    const float* Dp       = (const float*)d_in[12];
    const float* outproj_w= (const float*)d_in[13];
    const float* s1_w1    = (const float*)d_in[14];
    const float* s1_b1    = (const float*)d_in[15];
    const float* s1_w2    = (const float*)d_in[16];
    const float* s1_b2    = (const float*)d_in[17];
    const float* s1_w3    = (const float*)d_in[18];
    const float* s1_b3    = (const float*)d_in[19];

    const long NLIN = (long)NBLKV * DMV * DMV;
    const long NINP = (long)NBLKV * 2 * DIV * DMV;
    const long NXPP = (long)NBLKV * 64 * DIV;     // padded xproj (64 rows)
    const long NOUT = (long)NBLKV * DMV * DIV;
    const long NDTW = (long)NBLKV * DIV * 32;
    const long NHW1 = (long)512 * DMV;            // head w1 transposed
    const long NHW2 = (long)512 * 512;            // head w2 transposed

    // ---- workspace sizing ----
    const long FIXED = 256 +
                       (NLIN + NINP + NXPP + NOUT + NDTW + NHW1 + NHW2) * 2 + 256;
    const long PER_BATCH = (long)LSZ * (DMV + DMV + 2 * DIV + DIV) * 2   // bf16 acts
                         + (long)LSZ * DBLD * 2                          // dbc bf16
                         + (long)LSZ * DIV * 2                           // delta bf16
                         + (long)NCHUNK * DIV * NST * 4                  // hfin
                         + (long)NCHUNK * DIV * 4;                       // sumd
    int Bc = 8;
    while (Bc > 1 && (size_t)(FIXED + (long)Bc * PER_BATCH) > ws_size)
        Bc >>= 1;
    int nchunk_b = BSZ / Bc;
    long Mc = (long)Bc * LSZ;

    char* p = (char*)d_ws;
    float* sm = (float*)p;           p += 256;
    unsigned short* wlin = (unsigned short*)p; p += NLIN * 2;
    unsigned short* winp = (unsigned short*)p; p += NINP * 2;
    unsigned short* wxp  = (unsigned short*)p; p += NXPP * 2;
    unsigned short* wout = (unsigned short*)p; p += NOUT * 2;
    unsigned short* wdt  = (unsigned short*)p; p += NDTW * 2;
    unsigned short* w1t  = (unsigned short*)p; p += NHW1 * 2;
    unsigned short* w2t  = (unsigned short*)p; p += NHW2 * 2;
    unsigned short* u  = (unsigned short*)p;   p += Mc * DMV * 2;
    unsigned short* t  = (unsigned short*)p;   p += Mc * DMV * 2;
    unsigned short* xz = (unsigned short*)p;   p += Mc * 2560 * 2;
    unsigned short* xc = (unsigned short*)p;   p += Mc * DIV * 2;
    unsigned short* dbc = (unsigned short*)p;  p += Mc * DBLD * 2;
    unsigned short* delta = (unsigned short*)p; p += Mc * DIV * 2;
    float* hfin = (float*)p;         p += (long)Bc * NCHUNK * DIV * NST * 4;
    float* sumd = (float*)p;

    // one-time (per launch) weight conversion
    convert_kernel<<<(unsigned)((NLIN / 4 + 255) / 256), 256, 0, stream>>>(lin_w, wlin, NLIN / 4);
    convert_kernel<<<(unsigned)((NINP / 4 + 255) / 256), 256, 0, stream>>>(inproj_w, winp, NINP / 4);
    convert_kernel<<<(unsigned)((NOUT / 4 + 255) / 256), 256, 0, stream>>>(outproj_w, wout, NOUT / 4);
    convert_xp_kernel<<<(unsigned)((NXPP + 255) / 256), 256, 0, stream>>>(xproj_w, wxp);
    convert_dtw_kernel<<<(unsigned)((NDTW + 255) / 256), 256, 0, stream>>>(dtproj_w, wdt);
    convert_t2_kernel<<<(unsigned)((NHW1 + 255) / 256), 256, 0, stream>>>(s1_w1, w1t, 512, DMV);
    convert_t2_kernel<<<(unsigned)((NHW2 + 255) / 256), 256, 0, stream>>>(s1_w2, w2t, 512, 512);

    init_sm_kernel<<<1, 64, 0, stream>>>(sm);
    reduce_max_kernel<<<32, 256, 0, stream>>>(x, sm);

    for (int c = 0; c < nchunk_b; c++) {
        int b0 = c * Bc;
        fc_kernel<<<dim3(5, (unsigned)(Mc / 4)), 256, 0, stream>>>(
            x + (long)b0 * LSZ * 4, fc_w, fc_b, sm, u);

        for (int i = 0; i < NBLKV; i++) {
            const float* lb  = lin_b    + (long)i * DMV;
            const float* cw  = conv_w   + (long)i * DIV * DCV;
            const float* cb  = conv_b   + (long)i * DIV;
            const float* dpb = dtproj_b + (long)i * DIV;
            const float* al  = A_log    + (long)i * DIV * NST;
            const float* dd  = Dp       + (long)i * DIV;

            // lin + tanh: (Mc x320)@(320x320)^T -> t (bf16)
            gemm_mfma_kernel<1, 128, 64, 64, unsigned short>
                <<<dim3(5, (unsigned)(Mc / 128)), 256, 0, stream>>>(
                u, wlin + (long)i * DMV * DMV, lb, t, DMV, DMV, DMV, DMV);
            // inproj: (Mc x320)@(2560x320)^T -> xz (bf16)
            gemm_mfma_kernel<0, 128, 128, 64, unsigned short>
                <<<dim3(20, (unsigned)(Mc / 128)), 256, 0, stream>>>(
                t, winp + (long)i * 2 * DIV * DMV, nullptr, xz, 2 * DIV, DMV, DMV, 2 * DIV);
            // conv + silu (sliding window, bf16)
            conv_kernel<<<dim3(5, LSZ / TCONV, Bc), 256, 0, stream>>>(xz, cw, cb, xc);
            // xproj: (Mc x1280)@(64x1280)^T (padded W) -> dbc (bf16, ld 56)
            gemm_mfma_kernel<0, 64, 64, 64, unsigned short>
                <<<dim3(1, (unsigned)(Mc / 64)), 256, 0, stream>>>(
                xc, wxp + (long)i * 64 * DIV, nullptr, dbc,
                DTR + 2 * NST, DIV, DIV, DBLD);
            // delta = softplus(dbc[:, :20] @ dtw^T + b): K padded to 32, bf16 out
            gemm_mfma_kernel<4, 128, 128, 32, unsigned short>
                <<<dim3(10, (unsigned)(Mc / 128)), 256, 0, stream>>>(
                dbc, wdt + (long)i * DIV * 32, dpb, delta, DIV, 32, DBLD, DIV);
            // chunked scan
            scan_local_kernel<<<dim3(5, NCHUNK, Bc), 256, 0, stream>>>(
                xc, xz, dbc, delta, al, dd, hfin, sumd);
            scan_prefix_kernel<<<dim3(Bc * 80), 256, 0, stream>>>(hfin, sumd, al, Bc);
            scan_fix_kernel<<<dim3(5, NCHUNK, Bc), 256, 0, stream>>>(
                xz, dbc, delta, al, hfin);
            // outproj + elu: (Mc x1280)@(320x1280)^T -> u (bf16)
            gemm_mfma_kernel<3, 128, 64, 64, unsigned short>
                <<<dim3(5, (unsigned)(Mc / 128)), 256, 0, stream>>>(
                xz, wout + (long)i * DMV * DIV, nullptr, u, DMV, DIV, 2 * DIV, DMV);
        }

        // fused head on last token of each batch in chunk
        head_kernel<<<Bc, 512, 0, stream>>>(u, w1t, s1_b1, w2t, s1_b2,
                                            s1_w3, s1_b3, sm, (float*)d_out + b0);
    }
}

// Round 10
// 1274.914 us; speedup vs baseline: 13.3492x; 1.0830x over previous
//
#include <hip/hip_runtime.h>
#include <math.h>

// Problem constants
#define BSZ 8
#define LSZ 2048
#define DMV 320
#define DIV 1280
#define NST 16
#define DCV 8
#define DTR 20
#define NBLKV 4
#define MTOT (BSZ*LSZ)   // 16384
#define NCHUNK 32
#define CLEN 64          // NCHUNK*CLEN == LSZ
#define DBLD 56          // dbc leading dim (bf16), 16B-aligned rows

typedef __attribute__((ext_vector_type(8))) short short8;
typedef __attribute__((ext_vector_type(8))) unsigned short ushort8;
typedef __attribute__((ext_vector_type(4))) float floatx4;

__device__ inline unsigned short f2bf(float f) {
    union { float f; unsigned u; } v; v.f = f;
    unsigned r = v.u + 0x7FFFu + ((v.u >> 16) & 1u);
    return (unsigned short)(r >> 16);
}
__device__ inline float bf2f(unsigned short b) {
    union { unsigned u; float f; } v; v.u = ((unsigned)b) << 16;
    return v.f;
}

// async 16B global -> LDS (wave-uniform LDS base + lane*16) [m97 pattern]
__device__ __forceinline__ void gload_lds16(unsigned short* l, const unsigned short* g) {
    __builtin_amdgcn_global_load_lds(
        (const __attribute__((address_space(1))) unsigned int*)g,
        (__attribute__((address_space(3))) unsigned int*)l, 16, 0, 0);
}

// ---------------------------------------------------------------------------
// fp32 -> bf16 weight conversion (grid-stride, n % 4 == 0)
// ---------------------------------------------------------------------------
__global__ __launch_bounds__(256) void convert_kernel(
    const float* __restrict__ src, unsigned short* __restrict__ dst, long n4) {
    long i = (long)blockIdx.x * 256 + threadIdx.x;
    if (i >= n4) return;
    float4 v = *(const float4*)(src + i * 4);
    unsigned short o[4] = {f2bf(v.x), f2bf(v.y), f2bf(v.z), f2bf(v.w)};
    *(unsigned long long*)(dst + i * 4) = *(unsigned long long*)o;
}

// dtproj_w (NBLKV x 1280 x 20) -> bf16 padded (NBLKV x 1280 x 32), zero cols 20..31
__global__ __launch_bounds__(256) void convert_dtw_kernel(
    const float* __restrict__ src, unsigned short* __restrict__ dst) {
    int i = blockIdx.x * 256 + threadIdx.x;
    if (i >= NBLKV * DIV * 32) return;
    int l = i / (DIV * 32), rem = i % (DIV * 32);
    int d = rem >> 5, j = rem & 31;
    dst[i] = (j < DTR) ? f2bf(src[((long)l * DIV + d) * DTR + j]) : (unsigned short)0;
}

// xproj_w (NBLKV x 52 x 1280) -> bf16 padded (NBLKV x 64 x 1280), zero rows 52..63
__global__ __launch_bounds__(256) void convert_xp_kernel(
    const float* __restrict__ src, unsigned short* __restrict__ dst) {
    int i = blockIdx.x * 256 + threadIdx.x;
    if (i >= NBLKV * 64 * DIV) return;
    int l = i / (64 * DIV), rem = i % (64 * DIV);
    int n = rem / DIV, k = rem % DIV;
    dst[i] = (n < DTR + 2 * NST) ? f2bf(src[((long)l * (DTR + 2 * NST) + n) * DIV + k])
                                 : (unsigned short)0;
}

// head weight (N x K) fp32 -> pair-packed transposed bf16:
// dst[((k>>1)*N + n)*2 + (k&1)]  (thread n loads uint = weights for k, k+1)
__global__ __launch_bounds__(256) void convert_t2_kernel(
    const float* __restrict__ src, unsigned short* __restrict__ dst, int N, int K) {
    int i = blockIdx.x * 256 + threadIdx.x;
    if (i >= N * K) return;
    int n = i / K, k = i % K;
    dst[((k >> 1) * N + n) * 2 + (k & 1)] = f2bf(src[i]);
}

// ---------------------------------------------------------------------------
// start_max reduction (x[:,:,2] >= 0, so int-compare atomicMax is valid)
// ---------------------------------------------------------------------------
__global__ void init_sm_kernel(float* sm) {
    if (threadIdx.x == 0) ((int*)sm)[0] = 0;
}

__global__ void reduce_max_kernel(const float* __restrict__ x, float* sm) {
    int idx = blockIdx.x * blockDim.x + threadIdx.x;
    float v = 0.f;
    for (int i = idx; i < MTOT; i += gridDim.x * blockDim.x)
        v = fmaxf(v, x[i * 4 + 2]);
    #pragma unroll
    for (int off = 32; off > 0; off >>= 1)
        v = fmaxf(v, __shfl_xor(v, off, 64));
    if ((threadIdx.x & 63) == 0)
        atomicMax((int*)sm, __float_as_int(v));
}

// ---------------------------------------------------------------------------
// input normalize + fc (K=4) -> bf16 u
// ---------------------------------------------------------------------------
__global__ __launch_bounds__(256) void fc_kernel(
    const float* __restrict__ x, const float* __restrict__ fw,
    const float* __restrict__ fb, const float* __restrict__ sm,
    unsigned short* __restrict__ u) {
    int o = blockIdx.x * 64 + (threadIdx.x & 63);
    long m = (long)blockIdx.y * 4 + (threadIdx.x >> 6);
    float inv_sm = 1.0f / sm[0];
    float x0 = x[m * 4 + 0] * (1.0f / 255.0f);
    float x1 = x[m * 4 + 1] * (1.0f / 255.0f);
    float x2 = x[m * 4 + 2] * inv_sm;
    float x3 = x[m * 4 + 3];
    float acc = fb[o];
    acc = fmaf(x0, fw[o * 4 + 0], acc);
    acc = fmaf(x1, fw[o * 4 + 1], acc);
    acc = fmaf(x2, fw[o * 4 + 2], acc);
    acc = fmaf(x3, fw[o * 4 + 3], acc);
    u[m * DMV + o] = f2bf(acc);
}

// ---------------------------------------------------------------------------
// bf16 MFMA GEMM with async global->LDS staging (m97 structure) and
// XOR chunk swizzle: LDS slot (r, c) holds global chunk c ^ (r & (CPR-1)),
// readers use cp = cl ^ (R & (CPR-1)) -> every bank hit exactly 8x per
// ds_read_b128 wave (conflict-free minimum).
// ---------------------------------------------------------------------------
template<int ACT, int BM, int BN, int KB, typename TOUT>
__global__ __launch_bounds__(256) void gemm_mfma_kernel(
    const unsigned short* __restrict__ X, const unsigned short* __restrict__ W,
    const float* __restrict__ bias, TOUT* __restrict__ Y,
    int N, int K, long ldx, long ldy)
{
    constexpr int WMT = (BM == 128 && BN == 128) ? 4 : 2;
    constexpr int WNT = (BM == 64 && BN == 64) ? 2 : 4;
    constexpr int CPR = KB / 8;                  // 16B chunks per row
    constexpr int CMSK = CPR - 1;
    constexpr int NCX = BM * CPR / 256;          // async calls per wave (X)
    constexpr int NCW = BN * CPR / 256;          // async calls per wave (W)
    __shared__ unsigned short Xs[BM * KB];
    __shared__ unsigned short Ws[BN * KB];

    int tid = threadIdx.x;
    int wave = tid >> 6, lane = tid & 63;
    int quad = lane >> 4, l15 = lane & 15;
    int wmbase, wnbase;
    if (BM == 128 && BN == 128)      { wmbase = (wave & 1) * 64; wnbase = (wave >> 1) * 64; }
    else if (BM == 128 && BN == 64)  { wmbase = wave * 32;       wnbase = 0; }
    else                             { wmbase = (wave & 1) * 32; wnbase = (wave >> 1) * 32; }
    long m0 = (long)blockIdx.y * BM;
    int n0 = blockIdx.x * BN;

    floatx4 acc[WMT][WNT];
    #pragma unroll
    for (int i = 0; i < WMT; i++)
        #pragma unroll
        for (int j = 0; j < WNT; j++)
            acc[i][j] = (floatx4){0.f, 0.f, 0.f, 0.f};

    const unsigned short* Xb = X + m0 * ldx;
    const unsigned short* Wb = W + (long)n0 * K;

    for (int k0 = 0; k0 < K; k0 += KB) {
        #pragma unroll
        for (int j = 0; j < NCX; j++) {
            int s = (wave * NCX + j) * 64 + lane;
            int r = s / CPR, c = s % CPR;
            int cg = c ^ (r & CMSK);
            gload_lds16(&Xs[(wave * NCX + j) * 512],
                        Xb + (long)r * ldx + k0 + cg * 8);
        }
        #pragma unroll
        for (int j = 0; j < NCW; j++) {
            int s = (wave * NCW + j) * 64 + lane;
            int r = s / CPR, c = s % CPR;
            int cg = c ^ (r & CMSK);
            gload_lds16(&Ws[(wave * NCW + j) * 512],
                        Wb + (long)r * K + k0 + cg * 8);
        }
        __syncthreads();
        #pragma unroll
        for (int kk = 0; kk < KB; kk += 32) {
            short8 af[WMT], bfr[WNT];
            #pragma unroll
            for (int i = 0; i < WMT; i++) {
                int R = wmbase + i * 16 + l15;
                int cp = (kk / 8 + quad) ^ (R & CMSK);
                af[i] = *(short8*)&Xs[R * KB + cp * 8];
            }
            #pragma unroll
            for (int j = 0; j < WNT; j++) {
                int R = wnbase + j * 16 + l15;
                int cp = (kk / 8 + quad) ^ (R & CMSK);
                bfr[j] = *(short8*)&Ws[R * KB + cp * 8];
            }
            #pragma unroll
            for (int i = 0; i < WMT; i++)
                #pragma unroll
                for (int j = 0; j < WNT; j++)
                    acc[i][j] = __builtin_amdgcn_mfma_f32_16x16x32_bf16(
                        af[i], bfr[j], acc[i][j], 0, 0, 0);
        }
        __syncthreads();
    }

    #pragma unroll
    for (int i = 0; i < WMT; i++) {
        long mb = m0 + wmbase + i * 16 + quad * 4;
        #pragma unroll
        for (int j = 0; j < WNT; j++) {
            int n = n0 + wnbase + j * 16 + l15;
            if (n >= N) continue;
            float bv = bias ? bias[n] : 0.f;
            #pragma unroll
            for (int r = 0; r < 4; r++) {
                float v = acc[i][j][r] + bv;
                if (ACT == 1) v = tanhf(v);
                else if (ACT == 3) v = (v > 0.f) ? v : expm1f(v);
                else if (ACT == 4) v = (v > 20.f) ? v : __logf(1.0f + __expf(v));
                if constexpr (sizeof(TOUT) == 2)
                    Y[(mb + r) * ldy + n] = f2bf(v);
                else
                    Y[(mb + r) * ldy + n] = v;
            }
        }
    }
}

// ---------------------------------------------------------------------------
// fused head, thread-per-output with pair-packed transposed bf16 weights.
// ---------------------------------------------------------------------------
__global__ __launch_bounds__(512) void head_kernel(
    const unsigned short* __restrict__ u,
    const unsigned short* __restrict__ w1t, const float* __restrict__ b1,
    const unsigned short* __restrict__ w2t, const float* __restrict__ b2,
    const float* __restrict__ w3, const float* __restrict__ b3,
    const float* __restrict__ sm, float* __restrict__ out)
{
    __shared__ float xs[DMV];
    __shared__ float h1s[512];
    __shared__ float red[8];
    int b = blockIdx.x;
    int tid = threadIdx.x;
    const unsigned short* xr = u + ((long)b * LSZ + (LSZ - 1)) * DMV;
    if (tid < DMV) xs[tid] = bf2f(xr[tid]);
    __syncthreads();

    float acc = 0.f;
    #pragma unroll 8
    for (int kk = 0; kk < DMV / 2; kk++) {
        unsigned wv = *(const unsigned*)&w1t[((long)kk * 512 + tid) * 2];
        acc = fmaf(xs[2 * kk],     bf2f((unsigned short)(wv & 0xffffu)), acc);
        acc = fmaf(xs[2 * kk + 1], bf2f((unsigned short)(wv >> 16)), acc);
    }
    h1s[tid] = fmaxf(acc + b1[tid], 0.f);
    __syncthreads();

    acc = 0.f;
    #pragma unroll 8
    for (int kk = 0; kk < 256; kk++) {
        unsigned wv = *(const unsigned*)&w2t[((long)kk * 512 + tid) * 2];
        acc = fmaf(h1s[2 * kk],     bf2f((unsigned short)(wv & 0xffffu)), acc);
        acc = fmaf(h1s[2 * kk + 1], bf2f((unsigned short)(wv >> 16)), acc);
    }
    float h2 = fmaxf(acc + b2[tid], 0.f);

    float part = h2 * w3[tid];
    #pragma unroll
    for (int off = 32; off > 0; off >>= 1) part += __shfl_xor(part, off, 64);
    if ((tid & 63) == 0) red[tid >> 6] = part;
    __syncthreads();
    if (tid == 0) {
        float s = b3[0];
        #pragma unroll
        for (int w = 0; w < 8; w++) s += red[w];
        float scale = sm[0] / 8.624618986159398f;   // 1 + ln(2048)
        out[b] = fmaxf(s * scale, 0.f);
    }
}

// ---------------------------------------------------------------------------
// depthwise causal conv (k=8) + bias + silu, sliding-window, bf16
// ---------------------------------------------------------------------------
#define TCONV 32
__global__ __launch_bounds__(256) void conv_kernel(
    const unsigned short* __restrict__ xz, const float* __restrict__ cw,
    const float* __restrict__ cb, unsigned short* __restrict__ xc)
{
    int d = blockIdx.x * 256 + threadIdx.x;
    int lb = blockIdx.z;
    int l0 = blockIdx.y * TCONV;
    long base = (long)lb * LSZ + l0;

    float w[8];
    #pragma unroll
    for (int k = 0; k < 8; k++) w[k] = cw[d * 8 + k];
    float bc = cb[d];

    float win[8];
    #pragma unroll
    for (int i = 0; i < 7; i++) {
        int l = l0 - 7 + i;
        win[i] = (l >= 0) ? bf2f(xz[(base - 7 + i) * 2560 + d]) : 0.f;
    }
    #pragma unroll
    for (int s = 0; s < TCONV; s++) {
        win[7] = bf2f(xz[(base + s) * 2560 + d]);
        float acc = bc;
        #pragma unroll
        for (int k = 0; k < 8; k++) acc = fmaf(win[k], w[k], acc);
        float sv = acc / (1.0f + __expf(-acc));
        xc[(base + s) * DIV + d] = f2bf(sv);
        #pragma unroll
        for (int k = 0; k < 7; k++) win[k] = win[k + 1];
    }
}

// power ladder: pw[n] = p^(n+1)
__device__ inline void pow_ladder(float p, float* pw) {
    pw[0] = p;
    pw[1] = pw[0] * pw[0];
    pw[2] = pw[1] * pw[0];
    pw[3] = pw[1] * pw[1];
    pw[4] = pw[3] * pw[0];
    pw[5] = pw[3] * pw[1];
    pw[6] = pw[3] * pw[2];
    pw[7] = pw[3] * pw[3];
    #pragma unroll
    for (int k = 8; k < 16; k++) pw[k] = pw[7] * pw[k - 8];
}

// ---------------------------------------------------------------------------
// Chunked scan phase 1: per-chunk local scan (h0=0). delta precomputed (bf16).
// Overwrites delta[m] with the inclusive within-chunk prefix sum (cum) for
// the parallel fix phase.
// ---------------------------------------------------------------------------
__global__ __launch_bounds__(256) void scan_local_kernel(
    const unsigned short* __restrict__ xc, unsigned short* xz,
    const unsigned short* __restrict__ dbc, unsigned short* delta,
    const float* __restrict__ A_log, const float* __restrict__ Dp,
    float* __restrict__ hfin, float* __restrict__ sumd)
{
    __shared__ float S[CLEN * 32];
    int lb = blockIdx.z;
    int ch = blockIdx.y;
    int d = blockIdx.x * 256 + threadIdx.x;
    int tid = threadIdx.x;

    float a[NST], h[NST];
    #pragma unroll
    for (int n = 0; n < NST; n++) {
        a[n] = -__expf(A_log[d * NST + n]);
        h[n] = 0.f;
    }
    float a0 = a[0];
    bool geo = true;
    #pragma unroll
    for (int n = 1; n < NST; n++)
        geo = geo && (fabsf(a[n] - (float)(n + 1) * a0) <= 1e-4f * (float)(n + 1));
    float Dd = Dp[d];

    long tok0 = (long)lb * LSZ + ch * CLEN;
    for (int i = tid; i < CLEN * 32; i += 256) {
        int r = i >> 5, c = i & 31;
        S[i] = bf2f(dbc[(tok0 + r) * DBLD + 20 + c]);
    }
    __syncthreads();

    float sd = 0.f;
    if (__all(geo)) {
        for (int l = 0; l < CLEN; l++) {
            long m = tok0 + l;
            const float* row = &S[l * 32];
            float dl = bf2f(delta[m * DIV + d]);
            sd += dl;
            delta[m * DIV + d] = f2bf(sd);      // cum for fix phase
            float xv = bf2f(xc[m * DIV + d]);
            float db = dl * xv;
            float pw[NST];
            pow_ladder(__expf(dl * a0), pw);
            float y = 0.f;
            #pragma unroll
            for (int n = 0; n < NST; n++) {
                h[n] = fmaf(pw[n], h[n], db * row[n]);
                y = fmaf(h[n], row[16 + n], y);
            }
            y = fmaf(xv, Dd, y);
            xz[m * 2560 + d] = f2bf(y);
        }
    } else {
        for (int l = 0; l < CLEN; l++) {
            long m = tok0 + l;
            const float* row = &S[l * 32];
            float dl = bf2f(delta[m * DIV + d]);
            sd += dl;
            delta[m * DIV + d] = f2bf(sd);
            float xv = bf2f(xc[m * DIV + d]);
            float db = dl * xv;
            float y = 0.f;
            #pragma unroll
            for (int n = 0; n < NST; n++) {
                float dA = __expf(dl * a[n]);
                h[n] = fmaf(dA, h[n], db * row[n]);
                y = fmaf(h[n], row[16 + n], y);
            }
            y = fmaf(xv, Dd, y);
            xz[m * 2560 + d] = f2bf(y);
        }
    }

    long cidx = ((long)lb * NCHUNK + ch) * DIV + d;
    #pragma unroll
    for (int n = 0; n < NST; n++) hfin[cidx * NST + n] = h[n];
    sumd[cidx] = sd;
}

// ---------------------------------------------------------------------------
// Phase 2: sequential prefix over chunks. One thread per (b, d, n).
// ---------------------------------------------------------------------------
__global__ __launch_bounds__(256) void scan_prefix_kernel(
    float* __restrict__ hfin, const float* __restrict__ sumd,
    const float* __restrict__ A_log, int Bc)
{
    long g = (long)blockIdx.x * 256 + threadIdx.x;
    int n = (int)(g & (NST - 1));
    long t = g >> 4;
    int d = (int)(t % DIV);
    int lb = (int)(t / DIV);
    if (lb >= Bc) return;

    float a = -__expf(A_log[d * NST + n]);
    float s = 0.f;
    for (int c = 0; c < NCHUNK; c++) {
        long cidx = ((long)lb * NCHUNK + c) * DIV + d;
        float hl = hfin[cidx * NST + n];
        float P = __expf(a * sumd[cidx]);
        hfin[cidx * NST + n] = s;
        s = fmaf(P, s, hl);
    }
}

// ---------------------------------------------------------------------------
// Phase 3 (parallel over tokens): y = y_local + C . (hin * exp(a*cum)),
// out = y * silu(z). cum read from the repurposed delta buffer.
// ---------------------------------------------------------------------------
__global__ __launch_bounds__(256) void scan_fix_kernel(
    unsigned short* xz, const unsigned short* __restrict__ dbc,
    const unsigned short* __restrict__ cum,
    const float* __restrict__ A_log, const float* __restrict__ hfin)
{
    __shared__ float S[CLEN * 16];
    int lb = blockIdx.z;
    int ch = blockIdx.y;
    int d = blockIdx.x * 256 + threadIdx.x;
    int tid = threadIdx.x;

    float a[NST], hin[NST];
    #pragma unroll
    for (int n = 0; n < NST; n++) a[n] = -__expf(A_log[d * NST + n]);
    float a0 = a[0];
    bool geo = true;
    #pragma unroll
    for (int n = 1; n < NST; n++)
        geo = geo && (fabsf(a[n] - (float)(n + 1) * a0) <= 1e-4f * (float)(n + 1));

    long cidx = ((long)lb * NCHUNK + ch) * DIV + d;
    #pragma unroll
    for (int n = 0; n < NST; n += 4)
        *(float4*)&hin[n] = *(const float4*)&hfin[cidx * NST + n];

    long tok0 = (long)lb * LSZ + ch * CLEN;
    for (int i = tid; i < CLEN * 16; i += 256) {
        int r = i >> 4, c = i & 15;
        S[i] = bf2f(dbc[(tok0 + r) * DBLD + 36 + c]);
    }
    __syncthreads();

    if (__all(geo)) {
        for (int l = 0; l < CLEN; l++) {
            long m = tok0 + l;
            const float* row = &S[l * 16];
            float cm = bf2f(cum[m * DIV + d]);
            float pw[NST];
            pow_ladder(__expf(cm * a0), pw);
            float fix = 0.f;
            #pragma unroll
            for (int n = 0; n < NST; n++)
                fix = fmaf(hin[n] * pw[n], row[n], fix);
            float y = bf2f(xz[m * 2560 + d]) + fix;
            float zv = bf2f(xz[m * 2560 + 1280 + d]);
            float sz = zv / (1.0f + __expf(-zv));
            xz[m * 2560 + d] = f2bf(y * sz);
        }
    } else {
        for (int l = 0; l < CLEN; l++) {
            long m = tok0 + l;
            const float* row = &S[l * 16];
            float cm = bf2f(cum[m * DIV + d]);
            float fix = 0.f;
            #pragma unroll
            for (int n = 0; n < NST; n++)
                fix = fmaf(hin[n] * __expf(cm * a[n]), row[n], fix);
            float y = bf2f(xz[m * 2560 + d]) + fix;
            float zv = bf2f(xz[m * 2560 + 1280 + d]);
            float sz = zv / (1.0f + __expf(-zv));
            xz[m * 2560 + d] = f2bf(y * sz);
        }
    }
}

// ---------------------------------------------------------------------------
extern "C" void kernel_launch(void* const* d_in, const int* in_sizes, int n_in,
                              void* d_out, int out_size, void* d_ws, size_t ws_size,
                              hipStream_t stream) {
    const float* x        = (const float*)d_in[0];
    const float* fc_w     = (const float*)d_in[1];
    const float* fc_b     = (const float*)d_in[2];
    const float* lin_w    = (const float*)d_in[3];
    const float* lin_b    = (const float*)d_in[4];
    const float* inproj_w = (const float*)d_in[5];
    const float* conv_w   = (const float*)d_in[6];
    const float* conv_b   = (const float*)d_in[7];
    const float* xproj_w  = (const float*)d_in[8];
    const float* dtproj_w = (const float*)d_in[9];
    const float* dtproj_b = (const float*)d_in[10];
    const float* A_log    = (const float*)d_in[11];
    const float* Dp       = (const float*)d_in[12];
    const float* outproj_w= (const float*)d_in[13];
    const float* s1_w1    = (const float*)d_in[14];
    const float* s1_b1    = (const float*)d_in[15];
    const float* s1_w2    = (const float*)d_in[16];
    const float* s1_b2    = (const float*)d_in[17];
    const float* s1_w3    = (const float*)d_in[18];
    const float* s1_b3    = (const float*)d_in[19];

    const long NLIN = (long)NBLKV * DMV * DMV;
    const long NINP = (long)NBLKV * 2 * DIV * DMV;
    const long NXPP = (long)NBLKV * 64 * DIV;     // padded xproj (64 rows)
    const long NOUT = (long)NBLKV * DMV * DIV;
    const long NDTW = (long)NBLKV * DIV * 32;
    const long NHW1 = (long)512 * DMV;            // head w1 transposed
    const long NHW2 = (long)512 * 512;            // head w2 transposed

    // ---- workspace sizing ----
    const long FIXED = 256 +
                       (NLIN + NINP + NXPP + NOUT + NDTW + NHW1 + NHW2) * 2 + 256;
    const long PER_BATCH = (long)LSZ * (DMV + DMV + 2 * DIV + DIV) * 2   // bf16 acts
                         + (long)LSZ * DBLD * 2                          // dbc bf16
                         + (long)LSZ * DIV * 2                           // delta/cum bf16
                         + (long)NCHUNK * DIV * NST * 4                  // hfin
                         + (long)NCHUNK * DIV * 4;                       // sumd
    int Bc = 8;
    while (Bc > 1 && (size_t)(FIXED + (long)Bc * PER_BATCH) > ws_size)
        Bc >>= 1;
    int nchunk_b = BSZ / Bc;
    long Mc = (long)Bc * LSZ;

    char* p = (char*)d_ws;
    float* sm = (float*)p;           p += 256;
    unsigned short* wlin = (unsigned short*)p; p += NLIN * 2;
    unsigned short* winp = (unsigned short*)p; p += NINP * 2;
    unsigned short* wxp  = (unsigned short*)p; p += NXPP * 2;
    unsigned short* wout = (unsigned short*)p; p += NOUT * 2;
    unsigned short* wdt  = (unsigned short*)p; p += NDTW * 2;
    unsigned short* w1t  = (unsigned short*)p; p += NHW1 * 2;
    unsigned short* w2t  = (unsigned short*)p; p += NHW2 * 2;
    unsigned short* u  = (unsigned short*)p;   p += Mc * DMV * 2;
    unsigned short* t  = (unsigned short*)p;   p += Mc * DMV * 2;
    unsigned short* xz = (unsigned short*)p;   p += Mc * 2560 * 2;
    unsigned short* xc = (unsigned short*)p;   p += Mc * DIV * 2;
    unsigned short* dbc = (unsigned short*)p;  p += Mc * DBLD * 2;
    unsigned short* delta = (unsigned short*)p; p += Mc * DIV * 2;
    float* hfin = (float*)p;         p += (long)Bc * NCHUNK * DIV * NST * 4;
    float* sumd = (float*)p;

    // one-time (per launch) weight conversion
    convert_kernel<<<(unsigned)((NLIN / 4 + 255) / 256), 256, 0, stream>>>(lin_w, wlin, NLIN / 4);
    convert_kernel<<<(unsigned)((NINP / 4 + 255) / 256), 256, 0, stream>>>(inproj_w, winp, NINP / 4);
    convert_kernel<<<(unsigned)((NOUT / 4 + 255) / 256), 256, 0, stream>>>(outproj_w, wout, NOUT / 4);
    convert_xp_kernel<<<(unsigned)((NXPP + 255) / 256), 256, 0, stream>>>(xproj_w, wxp);
    convert_dtw_kernel<<<(unsigned)((NDTW + 255) / 256), 256, 0, stream>>>(dtproj_w, wdt);
    convert_t2_kernel<<<(unsigned)((NHW1 + 255) / 256), 256, 0, stream>>>(s1_w1, w1t, 512, DMV);
    convert_t2_kernel<<<(unsigned)((NHW2 + 255) / 256), 256, 0, stream>>>(s1_w2, w2t, 512, 512);

    init_sm_kernel<<<1, 64, 0, stream>>>(sm);
    reduce_max_kernel<<<32, 256, 0, stream>>>(x, sm);

    for (int c = 0; c < nchunk_b; c++) {
        int b0 = c * Bc;
        fc_kernel<<<dim3(5, (unsigned)(Mc / 4)), 256, 0, stream>>>(
            x + (long)b0 * LSZ * 4, fc_w, fc_b, sm, u);

        for (int i = 0; i < NBLKV; i++) {
            const float* lb  = lin_b    + (long)i * DMV;
            const float* cw  = conv_w   + (long)i * DIV * DCV;
            const float* cb  = conv_b   + (long)i * DIV;
            const float* dpb = dtproj_b + (long)i * DIV;
            const float* al  = A_log    + (long)i * DIV * NST;
            const float* dd  = Dp       + (long)i * DIV;

            // lin + tanh: (Mc x320)@(320x320)^T -> t (bf16)
            gemm_mfma_kernel<1, 128, 64, 64, unsigned short>
                <<<dim3(5, (unsigned)(Mc / 128)), 256, 0, stream>>>(
                u, wlin + (long)i * DMV * DMV, lb, t, DMV, DMV, DMV, DMV);
            // inproj: (Mc x320)@(2560x320)^T -> xz (bf16)
            gemm_mfma_kernel<0, 128, 128, 64, unsigned short>
                <<<dim3(20, (unsigned)(Mc / 128)), 256, 0, stream>>>(
                t, winp + (long)i * 2 * DIV * DMV, nullptr, xz, 2 * DIV, DMV, DMV, 2 * DIV);
            // conv + silu (sliding window, bf16)
            conv_kernel<<<dim3(5, LSZ / TCONV, Bc), 256, 0, stream>>>(xz, cw, cb, xc);
            // xproj: (Mc x1280)@(64x1280)^T (padded W) -> dbc (bf16, ld 56)
            gemm_mfma_kernel<0, 64, 64, 64, unsigned short>
                <<<dim3(1, (unsigned)(Mc / 64)), 256, 0, stream>>>(
                xc, wxp + (long)i * 64 * DIV, nullptr, dbc,
                DTR + 2 * NST, DIV, DIV, DBLD);
            // delta = softplus(dbc[:, :20] @ dtw^T + b): K padded to 32, bf16 out
            gemm_mfma_kernel<4, 128, 128, 32, unsigned short>
                <<<dim3(10, (unsigned)(Mc / 128)), 256, 0, stream>>>(
                dbc, wdt + (long)i * DIV * 32, dpb, delta, DIV, 32, DBLD, DIV);
            // chunked scan (scan_local turns delta into cum in-place)
            scan_local_kernel<<<dim3(5, NCHUNK, Bc), 256, 0, stream>>>(
                xc, xz, dbc, delta, al, dd, hfin, sumd);
            scan_prefix_kernel<<<dim3(Bc * 80), 256, 0, stream>>>(hfin, sumd, al, Bc);
            scan_fix_kernel<<<dim3(5, NCHUNK, Bc), 256, 0, stream>>>(
                xz, dbc, delta, al, hfin);
            // outproj + elu: (Mc x1280)@(320x1280)^T -> u (bf16)
            gemm_mfma_kernel<3, 128, 64, 64, unsigned short>
                <<<dim3(5, (unsigned)(Mc / 128)), 256, 0, stream>>>(
                xz, wout + (long)i * DMV * DIV, nullptr, u, DMV, DIV, 2 * DIV, DMV);
        }

        // fused head on last token of each batch in chunk
        head_kernel<<<Bc, 512, 0, stream>>>(u, w1t, s1_b1, w2t, s1_b2,
                                            s1_w3, s1_b3, sm, (float*)d_out + b0);
    }
}

// Round 11
// 1233.993 us; speedup vs baseline: 13.7918x; 1.0332x over previous
//
#include <hip/hip_runtime.h>
#include <math.h>

// Problem constants
#define BSZ 8
#define LSZ 2048
#define DMV 320
#define DIV 1280
#define NST 16
#define DCV 8
#define DTR 20
#define NBLKV 4
#define MTOT (BSZ*LSZ)   // 16384
#define NCHUNK 64
#define CLEN 32          // NCHUNK*CLEN == LSZ
#define DBLD 56          // dbc leading dim (bf16), 16B-aligned rows

typedef __attribute__((ext_vector_type(8))) short short8;
typedef __attribute__((ext_vector_type(8))) unsigned short ushort8;
typedef __attribute__((ext_vector_type(4))) float floatx4;

__device__ inline unsigned short f2bf(float f) {
    union { float f; unsigned u; } v; v.f = f;
    unsigned r = v.u + 0x7FFFu + ((v.u >> 16) & 1u);
    return (unsigned short)(r >> 16);
}
__device__ inline float bf2f(unsigned short b) {
    union { unsigned u; float f; } v; v.u = ((unsigned)b) << 16;
    return v.f;
}

// async 16B global -> LDS (wave-uniform LDS base + lane*16) [m97 pattern]
__device__ __forceinline__ void gload_lds16(unsigned short* l, const unsigned short* g) {
    __builtin_amdgcn_global_load_lds(
        (const __attribute__((address_space(1))) unsigned int*)g,
        (__attribute__((address_space(3))) unsigned int*)l, 16, 0, 0);
}

// ---------------------------------------------------------------------------
// fp32 -> bf16 weight conversion (grid-stride, n % 4 == 0)
// ---------------------------------------------------------------------------
__global__ __launch_bounds__(256) void convert_kernel(
    const float* __restrict__ src, unsigned short* __restrict__ dst, long n4) {
    long i = (long)blockIdx.x * 256 + threadIdx.x;
    if (i >= n4) return;
    float4 v = *(const float4*)(src + i * 4);
    unsigned short o[4] = {f2bf(v.x), f2bf(v.y), f2bf(v.z), f2bf(v.w)};
    *(unsigned long long*)(dst + i * 4) = *(unsigned long long*)o;
}

// dtproj_w (NBLKV x 1280 x 20) -> bf16 padded (NBLKV x 1280 x 32), zero cols 20..31
__global__ __launch_bounds__(256) void convert_dtw_kernel(
    const float* __restrict__ src, unsigned short* __restrict__ dst) {
    int i = blockIdx.x * 256 + threadIdx.x;
    if (i >= NBLKV * DIV * 32) return;
    int l = i / (DIV * 32), rem = i % (DIV * 32);
    int d = rem >> 5, j = rem & 31;
    dst[i] = (j < DTR) ? f2bf(src[((long)l * DIV + d) * DTR + j]) : (unsigned short)0;
}

// xproj_w (NBLKV x 52 x 1280) -> bf16 padded (NBLKV x 64 x 1280), zero rows 52..63
__global__ __launch_bounds__(256) void convert_xp_kernel(
    const float* __restrict__ src, unsigned short* __restrict__ dst) {
    int i = blockIdx.x * 256 + threadIdx.x;
    if (i >= NBLKV * 64 * DIV) return;
    int l = i / (64 * DIV), rem = i % (64 * DIV);
    int n = rem / DIV, k = rem % DIV;
    dst[i] = (n < DTR + 2 * NST) ? f2bf(src[((long)l * (DTR + 2 * NST) + n) * DIV + k])
                                 : (unsigned short)0;
}

// head weight (N x K) fp32 -> pair-packed transposed bf16
__global__ __launch_bounds__(256) void convert_t2_kernel(
    const float* __restrict__ src, unsigned short* __restrict__ dst, int N, int K) {
    int i = blockIdx.x * 256 + threadIdx.x;
    if (i >= N * K) return;
    int n = i / K, k = i % K;
    dst[((k >> 1) * N + n) * 2 + (k & 1)] = f2bf(src[i]);
}

// ---------------------------------------------------------------------------
// start_max reduction (x[:,:,2] >= 0, so int-compare atomicMax is valid)
// ---------------------------------------------------------------------------
__global__ void init_sm_kernel(float* sm) {
    if (threadIdx.x == 0) ((int*)sm)[0] = 0;
}

__global__ void reduce_max_kernel(const float* __restrict__ x, float* sm) {
    int idx = blockIdx.x * blockDim.x + threadIdx.x;
    float v = 0.f;
    for (int i = idx; i < MTOT; i += gridDim.x * blockDim.x)
        v = fmaxf(v, x[i * 4 + 2]);
    #pragma unroll
    for (int off = 32; off > 0; off >>= 1)
        v = fmaxf(v, __shfl_xor(v, off, 64));
    if ((threadIdx.x & 63) == 0)
        atomicMax((int*)sm, __float_as_int(v));
}

// ---------------------------------------------------------------------------
// input normalize + fc (K=4) -> bf16 u
// ---------------------------------------------------------------------------
__global__ __launch_bounds__(256) void fc_kernel(
    const float* __restrict__ x, const float* __restrict__ fw,
    const float* __restrict__ fb, const float* __restrict__ sm,
    unsigned short* __restrict__ u) {
    int o = blockIdx.x * 64 + (threadIdx.x & 63);
    long m = (long)blockIdx.y * 4 + (threadIdx.x >> 6);
    float inv_sm = 1.0f / sm[0];
    float x0 = x[m * 4 + 0] * (1.0f / 255.0f);
    float x1 = x[m * 4 + 1] * (1.0f / 255.0f);
    float x2 = x[m * 4 + 2] * inv_sm;
    float x3 = x[m * 4 + 3];
    float acc = fb[o];
    acc = fmaf(x0, fw[o * 4 + 0], acc);
    acc = fmaf(x1, fw[o * 4 + 1], acc);
    acc = fmaf(x2, fw[o * 4 + 2], acc);
    acc = fmaf(x3, fw[o * 4 + 3], acc);
    u[m * DMV + o] = f2bf(acc);
}

// ---------------------------------------------------------------------------
// bf16 MFMA GEMM with async global->LDS staging + XOR chunk swizzle
// ---------------------------------------------------------------------------
template<int ACT, int BM, int BN, int KB, typename TOUT>
__global__ __launch_bounds__(256) void gemm_mfma_kernel(
    const unsigned short* __restrict__ X, const unsigned short* __restrict__ W,
    const float* __restrict__ bias, TOUT* __restrict__ Y,
    int N, int K, long ldx, long ldy)
{
    constexpr int WMT = (BM == 128 && BN == 128) ? 4 : 2;
    constexpr int WNT = (BM == 64 && BN == 64) ? 2 : 4;
    constexpr int CPR = KB / 8;                  // 16B chunks per row
    constexpr int CMSK = CPR - 1;
    constexpr int NCX = BM * CPR / 256;
    constexpr int NCW = BN * CPR / 256;
    __shared__ unsigned short Xs[BM * KB];
    __shared__ unsigned short Ws[BN * KB];

    int tid = threadIdx.x;
    int wave = tid >> 6, lane = tid & 63;
    int quad = lane >> 4, l15 = lane & 15;
    int wmbase, wnbase;
    if (BM == 128 && BN == 128)      { wmbase = (wave & 1) * 64; wnbase = (wave >> 1) * 64; }
    else if (BM == 128 && BN == 64)  { wmbase = wave * 32;       wnbase = 0; }
    else                             { wmbase = (wave & 1) * 32; wnbase = (wave >> 1) * 32; }
    long m0 = (long)blockIdx.y * BM;
    int n0 = blockIdx.x * BN;

    floatx4 acc[WMT][WNT];
    #pragma unroll
    for (int i = 0; i < WMT; i++)
        #pragma unroll
        for (int j = 0; j < WNT; j++)
            acc[i][j] = (floatx4){0.f, 0.f, 0.f, 0.f};

    const unsigned short* Xb = X + m0 * ldx;
    const unsigned short* Wb = W + (long)n0 * K;

    for (int k0 = 0; k0 < K; k0 += KB) {
        #pragma unroll
        for (int j = 0; j < NCX; j++) {
            int s = (wave * NCX + j) * 64 + lane;
            int r = s / CPR, c = s % CPR;
            int cg = c ^ (r & CMSK);
            gload_lds16(&Xs[(wave * NCX + j) * 512],
                        Xb + (long)r * ldx + k0 + cg * 8);
        }
        #pragma unroll
        for (int j = 0; j < NCW; j++) {
            int s = (wave * NCW + j) * 64 + lane;
            int r = s / CPR, c = s % CPR;
            int cg = c ^ (r & CMSK);
            gload_lds16(&Ws[(wave * NCW + j) * 512],
                        Wb + (long)r * K + k0 + cg * 8);
        }
        __syncthreads();
        #pragma unroll
        for (int kk = 0; kk < KB; kk += 32) {
            short8 af[WMT], bfr[WNT];
            #pragma unroll
            for (int i = 0; i < WMT; i++) {
                int R = wmbase + i * 16 + l15;
                int cp = (kk / 8 + quad) ^ (R & CMSK);
                af[i] = *(short8*)&Xs[R * KB + cp * 8];
            }
            #pragma unroll
            for (int j = 0; j < WNT; j++) {
                int R = wnbase + j * 16 + l15;
                int cp = (kk / 8 + quad) ^ (R & CMSK);
                bfr[j] = *(short8*)&Ws[R * KB + cp * 8];
            }
            #pragma unroll
            for (int i = 0; i < WMT; i++)
                #pragma unroll
                for (int j = 0; j < WNT; j++)
                    acc[i][j] = __builtin_amdgcn_mfma_f32_16x16x32_bf16(
                        af[i], bfr[j], acc[i][j], 0, 0, 0);
        }
        __syncthreads();
    }

    #pragma unroll
    for (int i = 0; i < WMT; i++) {
        long mb = m0 + wmbase + i * 16 + quad * 4;
        #pragma unroll
        for (int j = 0; j < WNT; j++) {
            int n = n0 + wnbase + j * 16 + l15;
            if (n >= N) continue;
            float bv = bias ? bias[n] : 0.f;
            #pragma unroll
            for (int r = 0; r < 4; r++) {
                float v = acc[i][j][r] + bv;
                if (ACT == 1) v = tanhf(v);
                else if (ACT == 3) v = (v > 0.f) ? v : expm1f(v);
                else if (ACT == 4) v = (v > 20.f) ? v : __logf(1.0f + __expf(v));
                if constexpr (sizeof(TOUT) == 2)
                    Y[(mb + r) * ldy + n] = f2bf(v);
                else
                    Y[(mb + r) * ldy + n] = v;
            }
        }
    }
}

// ---------------------------------------------------------------------------
// fused head, thread-per-output with pair-packed transposed bf16 weights.
// ---------------------------------------------------------------------------
__global__ __launch_bounds__(512) void head_kernel(
    const unsigned short* __restrict__ u,
    const unsigned short* __restrict__ w1t, const float* __restrict__ b1,
    const unsigned short* __restrict__ w2t, const float* __restrict__ b2,
    const float* __restrict__ w3, const float* __restrict__ b3,
    const float* __restrict__ sm, float* __restrict__ out)
{
    __shared__ float xs[DMV];
    __shared__ float h1s[512];
    __shared__ float red[8];
    int b = blockIdx.x;
    int tid = threadIdx.x;
    const unsigned short* xr = u + ((long)b * LSZ + (LSZ - 1)) * DMV;
    if (tid < DMV) xs[tid] = bf2f(xr[tid]);
    __syncthreads();

    float acc = 0.f;
    #pragma unroll 8
    for (int kk = 0; kk < DMV / 2; kk++) {
        unsigned wv = *(const unsigned*)&w1t[((long)kk * 512 + tid) * 2];
        acc = fmaf(xs[2 * kk],     bf2f((unsigned short)(wv & 0xffffu)), acc);
        acc = fmaf(xs[2 * kk + 1], bf2f((unsigned short)(wv >> 16)), acc);
    }
    h1s[tid] = fmaxf(acc + b1[tid], 0.f);
    __syncthreads();

    acc = 0.f;
    #pragma unroll 8
    for (int kk = 0; kk < 256; kk++) {
        unsigned wv = *(const unsigned*)&w2t[((long)kk * 512 + tid) * 2];
        acc = fmaf(h1s[2 * kk],     bf2f((unsigned short)(wv & 0xffffu)), acc);
        acc = fmaf(h1s[2 * kk + 1], bf2f((unsigned short)(wv >> 16)), acc);
    }
    float h2 = fmaxf(acc + b2[tid], 0.f);

    float part = h2 * w3[tid];
    #pragma unroll
    for (int off = 32; off > 0; off >>= 1) part += __shfl_xor(part, off, 64);
    if ((tid & 63) == 0) red[tid >> 6] = part;
    __syncthreads();
    if (tid == 0) {
        float s = b3[0];
        #pragma unroll
        for (int w = 0; w < 8; w++) s += red[w];
        float scale = sm[0] / 8.624618986159398f;   // 1 + ln(2048)
        out[b] = fmaxf(s * scale, 0.f);
    }
}

// ---------------------------------------------------------------------------
// depthwise causal conv (k=8) + bias + silu, sliding-window, bf16
// ---------------------------------------------------------------------------
#define TCONV 32
__global__ __launch_bounds__(256) void conv_kernel(
    const unsigned short* __restrict__ xz, const float* __restrict__ cw,
    const float* __restrict__ cb, unsigned short* __restrict__ xc)
{
    int d = blockIdx.x * 256 + threadIdx.x;
    int lb = blockIdx.z;
    int l0 = blockIdx.y * TCONV;
    long base = (long)lb * LSZ + l0;

    float w[8];
    #pragma unroll
    for (int k = 0; k < 8; k++) w[k] = cw[d * 8 + k];
    float bc = cb[d];

    float win[8];
    #pragma unroll
    for (int i = 0; i < 7; i++) {
        int l = l0 - 7 + i;
        win[i] = (l >= 0) ? bf2f(xz[(base - 7 + i) * 2560 + d]) : 0.f;
    }
    #pragma unroll
    for (int s = 0; s < TCONV; s++) {
        win[7] = bf2f(xz[(base + s) * 2560 + d]);
        float acc = bc;
        #pragma unroll
        for (int k = 0; k < 8; k++) acc = fmaf(win[k], w[k], acc);
        float sv = acc / (1.0f + __expf(-acc));
        xc[(base + s) * DIV + d] = f2bf(sv);
        #pragma unroll
        for (int k = 0; k < 7; k++) win[k] = win[k + 1];
    }
}

// power ladder: pw[n] = p^(n+1)
__device__ inline void pow_ladder(float p, float* pw) {
    pw[0] = p;
    pw[1] = pw[0] * pw[0];
    pw[2] = pw[1] * pw[0];
    pw[3] = pw[1] * pw[1];
    pw[4] = pw[3] * pw[0];
    pw[5] = pw[3] * pw[1];
    pw[6] = pw[3] * pw[2];
    pw[7] = pw[3] * pw[3];
    #pragma unroll
    for (int k = 8; k < 16; k++) pw[k] = pw[7] * pw[k - 8];
}

// ---------------------------------------------------------------------------
// Chunked scan phase 1: per-chunk local scan (h0=0), CLEN=32.
// delta is read-only; chunk-final state -> hfin (bf16), sum(delta) -> sumd.
// ---------------------------------------------------------------------------
__global__ __launch_bounds__(256) void scan_local_kernel(
    const unsigned short* __restrict__ xc, unsigned short* xz,
    const unsigned short* __restrict__ dbc, const unsigned short* __restrict__ delta,
    const float* __restrict__ A_log, const float* __restrict__ Dp,
    unsigned short* __restrict__ hfin, float* __restrict__ sumd)
{
    __shared__ float S[CLEN * 32];
    int lb = blockIdx.z;
    int ch = blockIdx.y;
    int d = blockIdx.x * 256 + threadIdx.x;
    int tid = threadIdx.x;

    float a[NST], h[NST];
    #pragma unroll
    for (int n = 0; n < NST; n++) {
        a[n] = -__expf(A_log[d * NST + n]);
        h[n] = 0.f;
    }
    float a0 = a[0];
    bool geo = true;
    #pragma unroll
    for (int n = 1; n < NST; n++)
        geo = geo && (fabsf(a[n] - (float)(n + 1) * a0) <= 1e-4f * (float)(n + 1));
    float Dd = Dp[d];

    long tok0 = (long)lb * LSZ + ch * CLEN;
    for (int i = tid; i < CLEN * 32; i += 256) {
        int r = i >> 5, c = i & 31;
        S[i] = bf2f(dbc[(tok0 + r) * DBLD + 20 + c]);
    }
    __syncthreads();

    float sd = 0.f;
    if (__all(geo)) {
        for (int l = 0; l < CLEN; l++) {
            long m = tok0 + l;
            const float* row = &S[l * 32];
            float dl = bf2f(delta[m * DIV + d]);
            sd += dl;
            float xv = bf2f(xc[m * DIV + d]);
            float db = dl * xv;
            float pw[NST];
            pow_ladder(__expf(dl * a0), pw);
            float y = 0.f;
            #pragma unroll
            for (int n = 0; n < NST; n++) {
                h[n] = fmaf(pw[n], h[n], db * row[n]);
                y = fmaf(h[n], row[16 + n], y);
            }
            y = fmaf(xv, Dd, y);
            xz[m * 2560 + d] = f2bf(y);
        }
    } else {
        for (int l = 0; l < CLEN; l++) {
            long m = tok0 + l;
            const float* row = &S[l * 32];
            float dl = bf2f(delta[m * DIV + d]);
            sd += dl;
            float xv = bf2f(xc[m * DIV + d]);
            float db = dl * xv;
            float y = 0.f;
            #pragma unroll
            for (int n = 0; n < NST; n++) {
                float dA = __expf(dl * a[n]);
                h[n] = fmaf(dA, h[n], db * row[n]);
                y = fmaf(h[n], row[16 + n], y);
            }
            y = fmaf(xv, Dd, y);
            xz[m * 2560 + d] = f2bf(y);
        }
    }

    long cidx = ((long)lb * NCHUNK + ch) * DIV + d;
    #pragma unroll
    for (int n = 0; n < NST; n++) hfin[cidx * NST + n] = f2bf(h[n]);
    sumd[cidx] = sd;
}

// ---------------------------------------------------------------------------
// Phase 2: sequential prefix over chunks (bf16 hfin). One thread per (b,d,n).
// ---------------------------------------------------------------------------
__global__ __launch_bounds__(256) void scan_prefix_kernel(
    unsigned short* __restrict__ hfin, const float* __restrict__ sumd,
    const float* __restrict__ A_log, int Bc)
{
    long g = (long)blockIdx.x * 256 + threadIdx.x;
    int n = (int)(g & (NST - 1));
    long t = g >> 4;
    int d = (int)(t % DIV);
    int lb = (int)(t / DIV);
    if (lb >= Bc) return;

    float a = -__expf(A_log[d * NST + n]);
    float s = 0.f;
    for (int c = 0; c < NCHUNK; c++) {
        long cidx = ((long)lb * NCHUNK + c) * DIV + d;
        float hl = bf2f(hfin[cidx * NST + n]);
        float P = __expf(a * sumd[cidx]);
        hfin[cidx * NST + n] = f2bf(s);
        s = fmaf(P, s, hl);
    }
}

// ---------------------------------------------------------------------------
// Phase 3 (parallel over tokens; cheap serial cum recompute):
// y = y_local + C . (hin * exp(a*cum)), out = y * silu(z).
// ---------------------------------------------------------------------------
__global__ __launch_bounds__(256) void scan_fix_kernel(
    unsigned short* xz, const unsigned short* __restrict__ dbc,
    const unsigned short* __restrict__ delta,
    const float* __restrict__ A_log, const unsigned short* __restrict__ hfin)
{
    __shared__ float S[CLEN * 16];
    int lb = blockIdx.z;
    int ch = blockIdx.y;
    int d = blockIdx.x * 256 + threadIdx.x;
    int tid = threadIdx.x;

    float a[NST], hin[NST];
    #pragma unroll
    for (int n = 0; n < NST; n++) a[n] = -__expf(A_log[d * NST + n]);
    float a0 = a[0];
    bool geo = true;
    #pragma unroll
    for (int n = 1; n < NST; n++)
        geo = geo && (fabsf(a[n] - (float)(n + 1) * a0) <= 1e-4f * (float)(n + 1));

    long cidx = ((long)lb * NCHUNK + ch) * DIV + d;
    #pragma unroll
    for (int n = 0; n < NST; n++) hin[n] = bf2f(hfin[cidx * NST + n]);

    long tok0 = (long)lb * LSZ + ch * CLEN;
    for (int i = tid; i < CLEN * 16; i += 256) {
        int r = i >> 4, c = i & 15;
        S[i] = bf2f(dbc[(tok0 + r) * DBLD + 36 + c]);
    }
    __syncthreads();

    float cum = 0.f;
    if (__all(geo)) {
        for (int l = 0; l < CLEN; l++) {
            long m = tok0 + l;
            const float* row = &S[l * 16];
            cum += bf2f(delta[m * DIV + d]);
            float pw[NST];
            pow_ladder(__expf(cum * a0), pw);
            float fix = 0.f;
            #pragma unroll
            for (int n = 0; n < NST; n++)
                fix = fmaf(hin[n] * pw[n], row[n], fix);
            float y = bf2f(xz[m * 2560 + d]) + fix;
            float zv = bf2f(xz[m * 2560 + 1280 + d]);
            float sz = zv / (1.0f + __expf(-zv));
            xz[m * 2560 + d] = f2bf(y * sz);
        }
    } else {
        for (int l = 0; l < CLEN; l++) {
            long m = tok0 + l;
            const float* row = &S[l * 16];
            cum += bf2f(delta[m * DIV + d]);
            float fix = 0.f;
            #pragma unroll
            for (int n = 0; n < NST; n++)
                fix = fmaf(hin[n] * __expf(cum * a[n]), row[n], fix);
            float y = bf2f(xz[m * 2560 + d]) + fix;
            float zv = bf2f(xz[m * 2560 + 1280 + d]);
            float sz = zv / (1.0f + __expf(-zv));
            xz[m * 2560 + d] = f2bf(y * sz);
        }
    }
}

// ---------------------------------------------------------------------------
extern "C" void kernel_launch(void* const* d_in, const int* in_sizes, int n_in,
                              void* d_out, int out_size, void* d_ws, size_t ws_size,
                              hipStream_t stream) {
    const float* x        = (const float*)d_in[0];
    const float* fc_w     = (const float*)d_in[1];
    const float* fc_b     = (const float*)d_in[2];
    const float* lin_w    = (const float*)d_in[3];
    const float* lin_b    = (const float*)d_in[4];
    const float* inproj_w = (const float*)d_in[5];
    const float* conv_w   = (const float*)d_in[6];
    const float* conv_b   = (const float*)d_in[7];
    const float* xproj_w  = (const float*)d_in[8];
    const float* dtproj_w = (const float*)d_in[9];
    const float* dtproj_b = (const float*)d_in[10];
    const float* A_log    = (const float*)d_in[11];
    const float* Dp       = (const float*)d_in[12];
    const float* outproj_w= (const float*)d_in[13];
    const float* s1_w1    = (const float*)d_in[14];
    const float* s1_b1    = (const float*)d_in[15];
    const float* s1_w2    = (const float*)d_in[16];
    const float* s1_b2    = (const float*)d_in[17];
    const float* s1_w3    = (const float*)d_in[18];
    const float* s1_b3    = (const float*)d_in[19];

    const long NLIN = (long)NBLKV * DMV * DMV;
    const long NINP = (long)NBLKV * 2 * DIV * DMV;
    const long NXPP = (long)NBLKV * 64 * DIV;
    const long NOUT = (long)NBLKV * DMV * DIV;
    const long NDTW = (long)NBLKV * DIV * 32;
    const long NHW1 = (long)512 * DMV;
    const long NHW2 = (long)512 * 512;

    // ---- workspace sizing ----
    const long FIXED = 256 +
                       (NLIN + NINP + NXPP + NOUT + NDTW + NHW1 + NHW2) * 2 + 256;
    const long PER_BATCH = (long)LSZ * (DMV + DMV + 2 * DIV + DIV) * 2   // bf16 acts
                         + (long)LSZ * DBLD * 2                          // dbc bf16
                         + (long)LSZ * DIV * 2                           // delta bf16
                         + (long)NCHUNK * DIV * NST * 2                  // hfin bf16
                         + (long)NCHUNK * DIV * 4;                       // sumd
    int Bc = 8;
    while (Bc > 1 && (size_t)(FIXED + (long)Bc * PER_BATCH) > ws_size)
        Bc >>= 1;
    int nchunk_b = BSZ / Bc;
    long Mc = (long)Bc * LSZ;

    char* p = (char*)d_ws;
    float* sm = (float*)p;           p += 256;
    unsigned short* wlin = (unsigned short*)p; p += NLIN * 2;
    unsigned short* winp = (unsigned short*)p; p += NINP * 2;
    unsigned short* wxp  = (unsigned short*)p; p += NXPP * 2;
    unsigned short* wout = (unsigned short*)p; p += NOUT * 2;
    unsigned short* wdt  = (unsigned short*)p; p += NDTW * 2;
    unsigned short* w1t  = (unsigned short*)p; p += NHW1 * 2;
    unsigned short* w2t  = (unsigned short*)p; p += NHW2 * 2;
    unsigned short* u  = (unsigned short*)p;   p += Mc * DMV * 2;
    unsigned short* t  = (unsigned short*)p;   p += Mc * DMV * 2;
    unsigned short* xz = (unsigned short*)p;   p += Mc * 2560 * 2;
    unsigned short* xc = (unsigned short*)p;   p += Mc * DIV * 2;
    unsigned short* dbc = (unsigned short*)p;  p += Mc * DBLD * 2;
    unsigned short* delta = (unsigned short*)p; p += Mc * DIV * 2;
    unsigned short* hfin = (unsigned short*)p; p += (long)Bc * NCHUNK * DIV * NST * 2;
    float* sumd = (float*)p;

    // one-time (per launch) weight conversion
    convert_kernel<<<(unsigned)((NLIN / 4 + 255) / 256), 256, 0, stream>>>(lin_w, wlin, NLIN / 4);
    convert_kernel<<<(unsigned)((NINP / 4 + 255) / 256), 256, 0, stream>>>(inproj_w, winp, NINP / 4);
    convert_kernel<<<(unsigned)((NOUT / 4 + 255) / 256), 256, 0, stream>>>(outproj_w, wout, NOUT / 4);
    convert_xp_kernel<<<(unsigned)((NXPP + 255) / 256), 256, 0, stream>>>(xproj_w, wxp);
    convert_dtw_kernel<<<(unsigned)((NDTW + 255) / 256), 256, 0, stream>>>(dtproj_w, wdt);
    convert_t2_kernel<<<(unsigned)((NHW1 + 255) / 256), 256, 0, stream>>>(s1_w1, w1t, 512, DMV);
    convert_t2_kernel<<<(unsigned)((NHW2 + 255) / 256), 256, 0, stream>>>(s1_w2, w2t, 512, 512);

    init_sm_kernel<<<1, 64, 0, stream>>>(sm);
    reduce_max_kernel<<<32, 256, 0, stream>>>(x, sm);

    for (int c = 0; c < nchunk_b; c++) {
        int b0 = c * Bc;
        fc_kernel<<<dim3(5, (unsigned)(Mc / 4)), 256, 0, stream>>>(
            x + (long)b0 * LSZ * 4, fc_w, fc_b, sm, u);

        for (int i = 0; i < NBLKV; i++) {
            const float* lb  = lin_b    + (long)i * DMV;
            const float* cw  = conv_w   + (long)i * DIV * DCV;
            const float* cb  = conv_b   + (long)i * DIV;
            const float* dpb = dtproj_b + (long)i * DIV;
            const float* al  = A_log    + (long)i * DIV * NST;
            const float* dd  = Dp       + (long)i * DIV;

            // lin + tanh: (Mc x320)@(320x320)^T -> t (bf16)
            gemm_mfma_kernel<1, 128, 64, 64, unsigned short>
                <<<dim3(5, (unsigned)(Mc / 128)), 256, 0, stream>>>(
                u, wlin + (long)i * DMV * DMV, lb, t, DMV, DMV, DMV, DMV);
            // inproj: (Mc x320)@(2560x320)^T -> xz (bf16)
            gemm_mfma_kernel<0, 128, 128, 64, unsigned short>
                <<<dim3(20, (unsigned)(Mc / 128)), 256, 0, stream>>>(
                t, winp + (long)i * 2 * DIV * DMV, nullptr, xz, 2 * DIV, DMV, DMV, 2 * DIV);
            // conv + silu (sliding window, bf16)
            conv_kernel<<<dim3(5, LSZ / TCONV, Bc), 256, 0, stream>>>(xz, cw, cb, xc);
            // xproj: (Mc x1280)@(64x1280)^T (padded W) -> dbc (bf16, ld 56)
            gemm_mfma_kernel<0, 64, 64, 64, unsigned short>
                <<<dim3(1, (unsigned)(Mc / 64)), 256, 0, stream>>>(
                xc, wxp + (long)i * 64 * DIV, nullptr, dbc,
                DTR + 2 * NST, DIV, DIV, DBLD);
            // delta = softplus(dbc[:, :20] @ dtw^T + b): K padded to 32, bf16 out
            gemm_mfma_kernel<4, 128, 128, 32, unsigned short>
                <<<dim3(10, (unsigned)(Mc / 128)), 256, 0, stream>>>(
                dbc, wdt + (long)i * DIV * 32, dpb, delta, DIV, 32, DBLD, DIV);
            // chunked scan (CLEN=32, NCHUNK=64)
            scan_local_kernel<<<dim3(5, NCHUNK, Bc), 256, 0, stream>>>(
                xc, xz, dbc, delta, al, dd, hfin, sumd);
            scan_prefix_kernel<<<dim3(Bc * 80), 256, 0, stream>>>(hfin, sumd, al, Bc);
            scan_fix_kernel<<<dim3(5, NCHUNK, Bc), 256, 0, stream>>>(
                xz, dbc, delta, al, hfin);
            // outproj + elu: (Mc x1280)@(320x1280)^T -> u (bf16)
            gemm_mfma_kernel<3, 128, 64, 64, unsigned short>
                <<<dim3(5, (unsigned)(Mc / 128)), 256, 0, stream>>>(
                xz, wout + (long)i * DMV * DIV, nullptr, u, DMV, DIV, 2 * DIV, DMV);
        }

        // fused head on last token of each batch in chunk
        head_kernel<<<Bc, 512, 0, stream>>>(u, w1t, s1_b1, w2t, s1_b2,
                                            s1_w3, s1_b3, sm, (float*)d_out + b0);
    }
}